// Round 1
// baseline (1740.909 us; speedup 1.0000x reference)
//
#include <hip/hip_runtime.h>

#define DM 1024
#define NH 16
#define DH 64
#define QL 1024
#define KL 2048

__device__ __forceinline__ float dot4(const float4 a, const float4 b) {
  return a.x*b.x + a.y*b.y + a.z*b.z + a.w*b.w;
}

// ---------------- fp32 tiled GEMM: C(64x64 tile) = A(Mx1024) @ W(1024x1024) ----------
// mode 0: plain row-major out[M][1024]
// mode 1: head-scatter: out[((b*16+head)*S + t + toff)*64 + dh], b=gm>>rpbs, t=gm&((1<<rpbs)-1)
__global__ __launch_bounds__(256) void gemm_proj(
    const float* __restrict__ A, const float* __restrict__ W,
    float* __restrict__ out, int mode, int S, int toff, int rpbs)
{
  __shared__ float As[16][68];   // As[k][m] (transposed A tile)
  __shared__ float Bs[16][68];   // Bs[k][n]
  const int tid = threadIdx.x;
  const int m0 = blockIdx.x * 64;
  const int n0 = blockIdx.y * 64;
  const int arow = tid >> 2;
  const int akq  = tid & 3;
  const int bkr  = tid >> 4;
  const int bnq  = tid & 15;
  const int ty   = tid >> 4;
  const int tx   = tid & 15;
  float acc[4][4] = {{0.f,0.f,0.f,0.f},{0.f,0.f,0.f,0.f},{0.f,0.f,0.f,0.f},{0.f,0.f,0.f,0.f}};

  for (int k0 = 0; k0 < DM; k0 += 16) {
    const float4 a4 = *(const float4*)&A[(size_t)(m0+arow)*DM + k0 + akq*4];
    const float4 b4 = *(const float4*)&W[(size_t)(k0+bkr)*DM + n0 + bnq*4];
    __syncthreads();
    As[akq*4+0][arow] = a4.x;
    As[akq*4+1][arow] = a4.y;
    As[akq*4+2][arow] = a4.z;
    As[akq*4+3][arow] = a4.w;
    *(float4*)&Bs[bkr][bnq*4] = b4;
    __syncthreads();
#pragma unroll
    for (int kk = 0; kk < 16; kk++) {
      const float4 a = *(const float4*)&As[kk][ty*4];
      const float4 b = *(const float4*)&Bs[kk][tx*4];
      acc[0][0] += a.x*b.x; acc[0][1] += a.x*b.y; acc[0][2] += a.x*b.z; acc[0][3] += a.x*b.w;
      acc[1][0] += a.y*b.x; acc[1][1] += a.y*b.y; acc[1][2] += a.y*b.z; acc[1][3] += a.y*b.w;
      acc[2][0] += a.z*b.x; acc[2][1] += a.z*b.y; acc[2][2] += a.z*b.z; acc[2][3] += a.z*b.w;
      acc[3][0] += a.w*b.x; acc[3][1] += a.w*b.y; acc[3][2] += a.w*b.z; acc[3][3] += a.w*b.w;
    }
  }
#pragma unroll
  for (int rr = 0; rr < 4; rr++) {
    const int gm = m0 + ty*4 + rr;
    const int gn = n0 + tx*4;
    float4 o; o.x = acc[rr][0]; o.y = acc[rr][1]; o.z = acc[rr][2]; o.w = acc[rr][3];
    if (mode == 0) {
      *(float4*)&out[(size_t)gm*DM + gn] = o;
    } else {
      const int bb = gm >> rpbs;
      const int t  = gm & ((1 << rpbs) - 1);
      const int hd = gn >> 6;
      const int dh = gn & 63;
      *(float4*)&out[(((size_t)bb*NH + hd)*S + t + toff)*DH + dh] = o;
    }
  }
}

// ---------------- fused flash attention with rel-shift ----------------
// q: (B,H,1024,64)  k,v: (B,H,2048,64)  rh: (H,2048,64)
// per block: (b, h, q-tile of 32 rows); iterate 64 k-tiles of 32 cols.
// rel-shift closed form (d = j - i):
//   d <= 1024 : bd = qr[i]   . rh[d+1023]
//   d == 1025 : bd = 0                      (handled via zero-filled wrap buffer)
//   d >= 1026 : bd = qr[i+1] . rh[d-1026]
__global__ __launch_bounds__(256) void attn_fused(
    const float* __restrict__ q, const float* __restrict__ k,
    const float* __restrict__ v, const float* __restrict__ rh,
    const float* __restrict__ rwb, const float* __restrict__ rrb,
    float* __restrict__ av)
{
  __shared__ float qw[32][68];   // q + r_w_bias
  __shared__ float qr[33][68];   // q + r_r_bias (extra row for wrap)
  __shared__ float kv[32][68];   // k tile, later v tile
  __shared__ float rm[63][68];   // r window, main region
  __shared__ float rw[63][68];   // r window, wrap region (zero-filled OOB)
  __shared__ float sc[32][33];   // softmax probs (written/read by same 8-lane group)

  const int tid = threadIdx.x;
  const int blk = blockIdx.x;
  const int qi = blk & 31;
  const int h  = (blk >> 5) & 15;
  const int b  = blk >> 9;
  const int i0 = qi * 32;

  const float* qbh = q + (((size_t)b*NH + h)*QL + i0)*DH;
  const float* kbh = k + ((size_t)b*NH + h)*KL*DH;
  const float* vbh = v + ((size_t)b*NH + h)*KL*DH;
  const float* rhh = rh + (size_t)h*KL*DH;

  // load q tiles (+biases)
#pragma unroll
  for (int s = 0; s < 2; s++) {
    const int fi = tid + 256*s;          // 0..511
    const int row = fi >> 4, c4 = (fi & 15) * 4;
    const float4 qv = *(const float4*)&qbh[row*DH + c4];
    const float4 bw = *(const float4*)&rwb[h*DH + c4];
    qw[row][c4+0] = qv.x + bw.x;
    qw[row][c4+1] = qv.y + bw.y;
    qw[row][c4+2] = qv.z + bw.z;
    qw[row][c4+3] = qv.w + bw.w;
  }
#pragma unroll
  for (int s = 0; s < 3; s++) {
    const int fi = tid + 256*s;
    if (fi < 528) {                       // 33 rows * 16
      const int row = fi >> 4, c4 = (fi & 15) * 4;
      const int gi = i0 + row;
      float4 qv = make_float4(0.f,0.f,0.f,0.f);
      if (gi < QL) qv = *(const float4*)&qbh[row*DH + c4];
      const float4 br = *(const float4*)&rrb[h*DH + c4];
      qr[row][c4+0] = qv.x + br.x;
      qr[row][c4+1] = qv.y + br.y;
      qr[row][c4+2] = qv.z + br.z;
      qr[row][c4+3] = qv.w + br.w;
    }
  }

  float O[8];
#pragma unroll
  for (int r = 0; r < 8; r++) O[r] = 0.f;
  float m_old = -1e30f, l = 0.f;

  const int ri = tid >> 3;        // q row within tile, 0..31
  const int t8 = tid & 7;
  const int d0 = t8 * 8;          // O column base

  for (int kt = 0; kt < 64; kt++) {
    const int k0 = kt * 32;
    __syncthreads();              // previous phase C done: kv/sc free
    // k tile
#pragma unroll
    for (int s = 0; s < 2; s++) {
      const int fi = tid + 256*s;
      const int row = fi >> 4, c4 = (fi & 15) * 4;
      *(float4*)&kv[row][c4] = *(const float4*)&kbh[(size_t)(k0+row)*DH + c4];
    }
    // r main window: x = (k0 - i0 + 992) + row
    const int xm0 = k0 - i0 + 992;
#pragma unroll
    for (int s = 0; s < 4; s++) {
      const int fi = tid + 256*s;
      if (fi < 1008) {                    // 63 rows * 16
        const int row = fi >> 4, c4 = (fi & 15) * 4;
        const int x = xm0 + row;
        float4 val = make_float4(0.f,0.f,0.f,0.f);
        if (x >= 0 && x < KL) val = *(const float4*)&rhh[(size_t)x*DH + c4];
        *(float4*)&rm[row][c4] = val;
      }
    }
    // r wrap window: x = (k0 - i0 - 1057) + row (zero-filled OOB -> d==1025 gives bd=0)
    const bool need_rw = (k0 - i0) >= 994;
    if (need_rw) {
      const int xw0 = k0 - i0 - 1057;
#pragma unroll
      for (int s = 0; s < 4; s++) {
        const int fi = tid + 256*s;
        if (fi < 1008) {
          const int row = fi >> 4, c4 = (fi & 15) * 4;
          const int x = xw0 + row;
          float4 val = make_float4(0.f,0.f,0.f,0.f);
          if (x >= 0 && x < KL) val = *(const float4*)&rhh[(size_t)x*DH + c4];
          *(float4*)&rw[row][c4] = val;
        }
      }
    }
    __syncthreads();

    // ---- phase A: scores for (ri, j = t8 + 8*jj) ----
    int jv[4];
    const float* rp[4];
    const float* qp[4];
    float accA[4] = {0.f,0.f,0.f,0.f};   // ac part
    float accB[4] = {0.f,0.f,0.f,0.f};   // bd part
#pragma unroll
    for (int jj = 0; jj < 4; jj++) {
      const int j = t8 + 8*jj;
      jv[jj] = j;
      const int d = (k0 + j) - (i0 + ri);
      const int row = j - ri + 31;       // 0..62, same row formula for both buffers
      const bool mn = (d <= 1024);
      rp[jj] = mn ? &rm[row][0] : &rw[row][0];
      qp[jj] = mn ? &qr[ri][0]  : &qr[ri+1][0];
    }
#pragma unroll 2
    for (int dd = 0; dd < 64; dd += 4) {
      const float4 qw4 = *(const float4*)&qw[ri][dd];
#pragma unroll
      for (int jj = 0; jj < 4; jj++) {
        const float4 k4 = *(const float4*)&kv[jv[jj]][dd];
        const float4 q4 = *(const float4*)(qp[jj] + dd);
        const float4 r4 = *(const float4*)(rp[jj] + dd);
        accA[jj] += dot4(qw4, k4);
        accB[jj] += dot4(q4, r4);
      }
    }
    float accS[4];
#pragma unroll
    for (int jj = 0; jj < 4; jj++) accS[jj] = (accA[jj] + accB[jj]) * 0.125f;

    // ---- phase B: online softmax (register + intra-wave shuffles only) ----
    float mnew = fmaxf(fmaxf(accS[0], accS[1]), fmaxf(accS[2], accS[3]));
    mnew = fmaxf(mnew, __shfl_xor(mnew, 1));
    mnew = fmaxf(mnew, __shfl_xor(mnew, 2));
    mnew = fmaxf(mnew, __shfl_xor(mnew, 4));
    mnew = fmaxf(m_old, mnew);
    const float alpha = __expf(m_old - mnew);
    float psum = 0.f;
#pragma unroll
    for (int jj = 0; jj < 4; jj++) {
      const float p = __expf(accS[jj] - mnew);
      sc[ri][jv[jj]] = p;
      psum += p;
    }
    psum += __shfl_xor(psum, 1);
    psum += __shfl_xor(psum, 2);
    psum += __shfl_xor(psum, 4);
    l = l * alpha + psum;
    m_old = mnew;
#pragma unroll
    for (int r = 0; r < 8; r++) O[r] *= alpha;

    __syncthreads();              // phase A done reading kv -> load v over it
#pragma unroll
    for (int s = 0; s < 2; s++) {
      const int fi = tid + 256*s;
      const int row = fi >> 4, c4 = (fi & 15) * 4;
      *(float4*)&kv[row][c4] = *(const float4*)&vbh[(size_t)(k0+row)*DH + c4];
    }
    __syncthreads();

    // ---- phase C: O[ri][d0..d0+7] += p * v ----
#pragma unroll 8
    for (int j = 0; j < 32; j++) {
      const float p = sc[ri][j];
      const float4 v0 = *(const float4*)&kv[j][d0];
      const float4 v1 = *(const float4*)&kv[j][d0+4];
      O[0] += p*v0.x; O[1] += p*v0.y; O[2] += p*v0.z; O[3] += p*v0.w;
      O[4] += p*v1.x; O[5] += p*v1.y; O[6] += p*v1.z; O[7] += p*v1.w;
    }
  }

  const float inv = 1.f / l;
  float4 o0, o1;
  o0.x = O[0]*inv; o0.y = O[1]*inv; o0.z = O[2]*inv; o0.w = O[3]*inv;
  o1.x = O[4]*inv; o1.y = O[5]*inv; o1.z = O[6]*inv; o1.w = O[7]*inv;
  float* dst = av + ((size_t)b*QL + (i0 + ri))*DM + h*DH + d0;
  *(float4*)&dst[0] = o0;
  *(float4*)&dst[4] = o1;
}

extern "C" void kernel_launch(void* const* d_in, const int* in_sizes, int n_in,
                              void* d_out, int out_size, void* d_ws, size_t ws_size,
                              hipStream_t stream) {
  (void)in_sizes; (void)n_in; (void)out_size; (void)ws_size;
  const float* h   = (const float*)d_in[0];
  const float* mem = (const float*)d_in[1];
  const float* r   = (const float*)d_in[2];
  const float* Wq  = (const float*)d_in[3];
  const float* Wk  = (const float*)d_in[4];
  const float* Wv  = (const float*)d_in[5];
  const float* Wr  = (const float*)d_in[6];
  const float* Wo  = (const float*)d_in[7];
  const float* rwb = (const float*)d_in[8];
  const float* rrb = (const float*)d_in[9];
  float* out = (float*)d_out;

  // workspace layout (floats): q 2M | k 4M | v 4M | rh 2M | av 2M  = 56 MB
  float* qb = (float*)d_ws;
  float* kb = qb + (size_t)2*NH*QL*DH;
  float* vb = kb + (size_t)2*NH*KL*DH;
  float* rh = vb + (size_t)2*NH*KL*DH;
  float* av = rh + (size_t)NH*KL*DH;

  const dim3 g(32, 16), blk(256);
  // projections (M = 2048 rows each)
  gemm_proj<<<g, blk, 0, stream>>>(h,   Wq, qb, 1, QL, 0,    10);
  gemm_proj<<<g, blk, 0, stream>>>(mem, Wk, kb, 1, KL, 0,    10);
  gemm_proj<<<g, blk, 0, stream>>>(h,   Wk, kb, 1, KL, 1024, 10);
  gemm_proj<<<g, blk, 0, stream>>>(mem, Wv, vb, 1, KL, 0,    10);
  gemm_proj<<<g, blk, 0, stream>>>(h,   Wv, vb, 1, KL, 1024, 10);
  gemm_proj<<<g, blk, 0, stream>>>(r,   Wr, rh, 1, KL, 0,    11);
  // fused attention
  attn_fused<<<dim3(1024), blk, 0, stream>>>(qb, kb, vb, rh, rwb, rrb, av);
  // output projection
  gemm_proj<<<g, blk, 0, stream>>>(av, Wo, out, 0, 0, 0, 0);
}

// Round 2
// 429.853 us; speedup vs baseline: 4.0500x; 4.0500x over previous
//
#include <hip/hip_runtime.h>

#define DM 1024
#define NH 16
#define DH 64
#define QL 1024
#define KL 2048

typedef short s16x8 __attribute__((ext_vector_type(8)));
typedef float f32x4 __attribute__((ext_vector_type(4)));

__device__ __forceinline__ unsigned short f2bf(float f) {
  unsigned int u = __builtin_bit_cast(unsigned int, f);
  u += 0x7fffu + ((u >> 16) & 1u);
  return (unsigned short)(u >> 16);
}
__device__ __forceinline__ float bf2f(unsigned short b) {
  unsigned int u = ((unsigned int)b) << 16;
  return __builtin_bit_cast(float, u);
}
__device__ __forceinline__ f32x4 mfma16(s16x8 a, s16x8 b, f32x4 c) {
  return __builtin_amdgcn_mfma_f32_16x16x32_bf16(a, b, c, 0, 0, 0);
}

// ---------------- input conversion: catb (B*2048 x 1024 bf16), rb (2048x1024 bf16) ----
__global__ __launch_bounds__(256) void build_inputs(
    const float* __restrict__ h, const float* __restrict__ mem, const float* __restrict__ r,
    unsigned short* __restrict__ catb, unsigned short* __restrict__ rb)
{
  int idx = blockIdx.x * 256 + threadIdx.x;           // 0 .. 1.5M-1
  if (idx < 1048576) {                                // catb: 4M u16, 4 per thread
    int e = idx * 4;
    int row = e >> 10, col = e & 1023;
    int b = row >> 11, t = row & 2047;
    const float* s = (t < 1024) ? &mem[((size_t)(b * 1024 + t)) * 1024 + col]
                                : &h[((size_t)(b * 1024 + t - 1024)) * 1024 + col];
    float4 v = *(const float4*)s;
    *(ushort4*)&catb[e] = make_ushort4(f2bf(v.x), f2bf(v.y), f2bf(v.z), f2bf(v.w));
  } else {
    int e = (idx - 1048576) * 4;                      // rb: 2M elements
    float4 v = *(const float4*)&r[e];
    *(ushort4*)&rb[e] = make_ushort4(f2bf(v.x), f2bf(v.y), f2bf(v.z), f2bf(v.w));
  }
}

// ---------------- W (1024x1024 f32) -> Wt (1024x1024 bf16, transposed) ----------------
__global__ __launch_bounds__(256) void transp_conv(
    const float* __restrict__ src, unsigned short* __restrict__ dst)
{
  __shared__ unsigned short tS[64][72];
  int tid = threadIdx.x;
  int sr0 = blockIdx.x * 64, sc0 = blockIdx.y * 64;
  int rr = tid >> 4, c4 = (tid & 15) * 4;
#pragma unroll
  for (int i = 0; i < 4; ++i) {
    int row = rr + i * 16;
    float4 v = *(const float4*)&src[(size_t)(sr0 + row) * 1024 + sc0 + c4];
    tS[c4 + 0][row] = f2bf(v.x); tS[c4 + 1][row] = f2bf(v.y);
    tS[c4 + 2][row] = f2bf(v.z); tS[c4 + 3][row] = f2bf(v.w);
  }
  __syncthreads();
#pragma unroll
  for (int i = 0; i < 4; ++i) {
    int row = rr + i * 16;
    ushort4 o = make_ushort4(tS[row][c4], tS[row][c4 + 1], tS[row][c4 + 2], tS[row][c4 + 3]);
    *(ushort4*)&dst[(size_t)(sc0 + row) * 1024 + sr0 + c4] = o;
  }
}

// Wo -> transposed hi/lo bf16 split
__global__ __launch_bounds__(256) void transp_conv_hilo(
    const float* __restrict__ src, unsigned short* __restrict__ dhi, unsigned short* __restrict__ dlo)
{
  __shared__ unsigned short tH[64][72];
  __shared__ unsigned short tL[64][72];
  int tid = threadIdx.x;
  int sr0 = blockIdx.x * 64, sc0 = blockIdx.y * 64;
  int rr = tid >> 4, c4 = (tid & 15) * 4;
#pragma unroll
  for (int i = 0; i < 4; ++i) {
    int row = rr + i * 16;
    float4 v = *(const float4*)&src[(size_t)(sr0 + row) * 1024 + sc0 + c4];
    float vv[4] = {v.x, v.y, v.z, v.w};
#pragma unroll
    for (int j = 0; j < 4; ++j) {
      unsigned short hi = f2bf(vv[j]);
      tH[c4 + j][row] = hi;
      tL[c4 + j][row] = f2bf(vv[j] - bf2f(hi));
    }
  }
  __syncthreads();
#pragma unroll
  for (int i = 0; i < 4; ++i) {
    int row = rr + i * 16;
    size_t o = (size_t)(sc0 + row) * 1024 + sr0 + c4;
    *(ushort4*)&dhi[o] = make_ushort4(tH[row][c4], tH[row][c4 + 1], tH[row][c4 + 2], tH[row][c4 + 3]);
    *(ushort4*)&dlo[o] = make_ushort4(tL[row][c4], tL[row][c4 + 1], tL[row][c4 + 2], tL[row][c4 + 3]);
  }
}

// ---------------- projection GEMMs (bf16 MFMA, 128x128 tile, BK=32) -------------------
// blocks 0..127   : Q   : A=catb(h rows),  Bt=wqt,  M=2048, N=1024 -> qwb,qrb (head layout + bias)
// blocks 128..639 : K|V : A=catb,          Bt=wkvt, M=4096, N=2048 -> kbuf (head) / vT (transposed)
// blocks 640..767 : R   : A=rb,            Bt=wrt,  M=2048, N=1024 -> rhb (head layout)
__global__ __launch_bounds__(256) void gemm_all(
    const unsigned short* __restrict__ catb, const unsigned short* __restrict__ rb,
    const unsigned short* __restrict__ wqt, const unsigned short* __restrict__ wkvt,
    const unsigned short* __restrict__ wrt,
    const float* __restrict__ rwb, const float* __restrict__ rrb,
    unsigned short* __restrict__ qwb, unsigned short* __restrict__ qrb,
    unsigned short* __restrict__ kbuf, unsigned short* __restrict__ vT,
    unsigned short* __restrict__ rhb)
{
  __shared__ __align__(16) unsigned short As[128 * 32];
  __shared__ __align__(16) unsigned short Bs[128 * 32];
  int blk = blockIdx.x, tid = threadIdx.x;
  int job, mb, nb;
  const unsigned short *A, *Bt;
  if (blk < 128)      { job = 0; A = catb; Bt = wqt;  mb = blk >> 3; nb = blk & 7; }
  else if (blk < 640) { job = 1; A = catb; Bt = wkvt; int q = blk - 128; mb = q >> 4; nb = q & 15; }
  else                { job = 2; A = rb;   Bt = wrt;  int q = blk - 640; mb = q >> 3; nb = q & 7; }

  int srow = tid >> 1;                 // 0..127
  int scol = (tid & 1) * 16;           // u16 offset within 32-wide k-slab
  int ga_row = mb * 128 + srow;
  if (job == 0) ga_row = ((ga_row >> 10) << 11) + 1024 + (ga_row & 1023);  // h rows inside catb
  const unsigned short* ga = A + (size_t)ga_row * 1024 + scol;
  const unsigned short* gb = Bt + (size_t)(nb * 128 + srow) * 1024 + scol;
  unsigned short* la = &As[srow * 32 + scol];
  unsigned short* lb = &Bs[srow * 32 + scol];

  int lane = tid & 63, w = tid >> 6;
  int lc = lane & 15, quad = lane >> 4;
  int wm = (w & 1) * 64, wn = (w >> 1) * 64;

  f32x4 acc[4][4];
#pragma unroll
  for (int mt = 0; mt < 4; ++mt)
#pragma unroll
    for (int nt = 0; nt < 4; ++nt) { acc[mt][nt][0] = 0.f; acc[mt][nt][1] = 0.f; acc[mt][nt][2] = 0.f; acc[mt][nt][3] = 0.f; }

  s16x8 pa0 = *(const s16x8*)ga,       pa1 = *(const s16x8*)(ga + 8);
  s16x8 pb0 = *(const s16x8*)gb,       pb1 = *(const s16x8*)(gb + 8);

  for (int k0 = 0; k0 < 1024; k0 += 32) {
    __syncthreads();
    *(s16x8*)la = pa0; *(s16x8*)(la + 8) = pa1;
    *(s16x8*)lb = pb0; *(s16x8*)(lb + 8) = pb1;
    __syncthreads();
    if (k0 + 32 < 1024) {
      pa0 = *(const s16x8*)(ga + k0 + 32); pa1 = *(const s16x8*)(ga + k0 + 40);
      pb0 = *(const s16x8*)(gb + k0 + 32); pb1 = *(const s16x8*)(gb + k0 + 40);
    }
    s16x8 af[4], bf[4];
#pragma unroll
    for (int mt = 0; mt < 4; ++mt) af[mt] = *(const s16x8*)&As[(wm + mt * 16 + lc) * 32 + quad * 8];
#pragma unroll
    for (int nt = 0; nt < 4; ++nt) bf[nt] = *(const s16x8*)&Bs[(wn + nt * 16 + lc) * 32 + quad * 8];
#pragma unroll
    for (int mt = 0; mt < 4; ++mt)
#pragma unroll
      for (int nt = 0; nt < 4; ++nt) acc[mt][nt] = mfma16(af[mt], bf[nt], acc[mt][nt]);
  }

  // epilogue: C row m = mb*128+wm+mt*16+quad*4+rr ; col n = nb*128+wn+nt*16+lc
#pragma unroll
  for (int mt = 0; mt < 4; ++mt) {
    int t4 = mb * 128 + wm + mt * 16 + quad * 4;
#pragma unroll
    for (int nt = 0; nt < 4; ++nt) {
      int n = nb * 128 + wn + nt * 16 + lc;
      if (job == 0) {
        int hh = n >> 6, dh = n & 63;
        float bw = rwb[n], br = rrb[n];
#pragma unroll
        for (int rr = 0; rr < 4; ++rr) {
          int m = t4 + rr; int bb = m >> 10, t = m & 1023;
          size_t idx = (((size_t)bb * NH + hh) * QL + t) * DH + dh;
          qwb[idx] = f2bf(acc[mt][nt][rr] + bw);
          qrb[idx] = f2bf(acc[mt][nt][rr] + br);
        }
      } else if (job == 1) {
        int bb = t4 >> 11, t = t4 & 2047;
        if (n < 1024) {
          int hh = n >> 6, dh = n & 63;
#pragma unroll
          for (int rr = 0; rr < 4; ++rr)
            kbuf[(((size_t)bb * NH + hh) * KL + t + rr) * DH + dh] = f2bf(acc[mt][nt][rr]);
        } else {
          int n2 = n - 1024, hh = n2 >> 6, dh = n2 & 63;
          ushort4 pk = make_ushort4(f2bf(acc[mt][nt][0]), f2bf(acc[mt][nt][1]),
                                    f2bf(acc[mt][nt][2]), f2bf(acc[mt][nt][3]));
          *(ushort4*)&vT[(((size_t)bb * NH + hh) * DH + dh) * KL + t] = pk;
        }
      } else {
        int hh = n >> 6, dh = n & 63;
#pragma unroll
        for (int rr = 0; rr < 4; ++rr)
          rhb[((size_t)hh * KL + t4 + rr) * DH + dh] = f2bf(acc[mt][nt][rr]);
      }
    }
  }
}

// ---------------- fused flash attention with rel-shift (bf16 MFMA) --------------------
// block: (b, h, 16 q-rows). Phase 0: raw BD strip (17 x 2048 bf16) in LDS via MFMA.
// Main: 4 waves split-K (512 keys each), no barriers. Epilogue: split-K merge in LDS.
#define BDSTR 2056
__global__ __launch_bounds__(256) void attn(
    const unsigned short* __restrict__ qwb, const unsigned short* __restrict__ qrb,
    const unsigned short* __restrict__ kbuf, const unsigned short* __restrict__ vT,
    const unsigned short* __restrict__ rhb,
    unsigned short* __restrict__ avhi, unsigned short* __restrict__ avlo)
{
  __shared__ __align__(16) unsigned short bdS[17 * BDSTR];   // 69904 B
  __shared__ __align__(16) unsigned short pS[4 * 16 * 40];   // 5120 B
  float* oS  = (float*)bdS;            // merge overlay: [4][16][64] f32
  float* mlS = (float*)bdS + 4096;     // [4][16][2] f32

  const int tid = threadIdx.x;
  const int w = tid >> 6, lane = tid & 63;
  const int lc = lane & 15, quad = lane >> 4;
  const int is = blockIdx.x & 63, h = (blockIdx.x >> 6) & 15, b = blockIdx.x >> 10;
  const int i0 = is * 16;
  const size_t bh = (size_t)b * NH + h;

  const unsigned short* qw_p = qwb + bh * QL * DH;
  const unsigned short* qr_p = qrb + bh * QL * DH;
  const unsigned short* kb_p = kbuf + bh * KL * DH;
  const unsigned short* vT_p = vT + bh * DH * KL;
  const unsigned short* rh_p = rhb + (size_t)h * KL * DH;

  // ---- phase 0: raw BD strip rows i0..i0+16 (17), cols 0..2047 ----
  {
    int r0 = i0 + lc;
    int r1 = i0 + 16 + lc; if (r1 > 1023) r1 = 1023;   // clamp; clamped rows unused
    s16x8 qa00 = *(const s16x8*)(qr_p + (size_t)r0 * DH + quad * 8);
    s16x8 qa01 = *(const s16x8*)(qr_p + (size_t)r0 * DH + 32 + quad * 8);
    s16x8 qa10 = *(const s16x8*)(qr_p + (size_t)r1 * DH + quad * 8);
    s16x8 qa11 = *(const s16x8*)(qr_p + (size_t)r1 * DH + 32 + quad * 8);
    for (int xt = w * 32; xt < w * 32 + 32; ++xt) {
      const unsigned short* rp = rh_p + (size_t)(xt * 16 + lc) * DH + quad * 8;
      s16x8 rf0 = *(const s16x8*)rp;
      s16x8 rf1 = *(const s16x8*)(rp + 32);
      f32x4 c0; c0[0] = 0.f; c0[1] = 0.f; c0[2] = 0.f; c0[3] = 0.f;
      f32x4 c1 = c0;
      c0 = mfma16(qa00, rf0, c0); c0 = mfma16(qa01, rf1, c0);
      c1 = mfma16(qa10, rf0, c1); c1 = mfma16(qa11, rf1, c1);
      int col = xt * 16 + lc;
#pragma unroll
      for (int rr = 0; rr < 4; ++rr) bdS[(quad * 4 + rr) * BDSTR + col] = f2bf(c0[rr]);
      if (lane < 16) bdS[16 * BDSTR + col] = f2bf(c1[0]);
    }
  }
  __syncthreads();

  // ---- main split-K loop: wave w handles k in [w*512, w*512+512) ----
  s16x8 qwf0 = *(const s16x8*)(qw_p + (size_t)(i0 + lc) * DH + quad * 8);
  s16x8 qwf1 = *(const s16x8*)(qw_p + (size_t)(i0 + lc) * DH + 32 + quad * 8);

  f32x4 O[4];
#pragma unroll
  for (int nt = 0; nt < 4; ++nt) { O[nt][0] = 0.f; O[nt][1] = 0.f; O[nt][2] = 0.f; O[nt][3] = 0.f; }
  float mcur[4] = {-1e30f, -1e30f, -1e30f, -1e30f};
  float lsum[4] = {0.f, 0.f, 0.f, 0.f};
  unsigned short* pw = pS + w * 16 * 40;
  int ebase[4];
#pragma unroll
  for (int rr = 0; rr < 4; ++rr) ebase[rr] = lc - (quad * 4 + rr) - i0;

  for (int it = 0; it < 16; ++it) {
    const int k0 = w * 512 + it * 32;
    float s[2][4];
#pragma unroll
    for (int jh = 0; jh < 2; ++jh) {
      const unsigned short* kp = kb_p + (size_t)(k0 + jh * 16 + lc) * DH + quad * 8;
      s16x8 kf0 = *(const s16x8*)kp;
      s16x8 kf1 = *(const s16x8*)(kp + 32);
      f32x4 c; c[0] = 0.f; c[1] = 0.f; c[2] = 0.f; c[3] = 0.f;
      c = mfma16(qwf0, kf0, c);
      c = mfma16(qwf1, kf1, c);
#pragma unroll
      for (int rr = 0; rr < 4; ++rr) {
        int row = quad * 4 + rr;
        int d = k0 + jh * 16 + ebase[rr];
        int am = row * BDSTR + (d + 1023);
        int aw = (row + 1) * BDSTR + (d - 1026);
        unsigned short vb = bdS[(d <= 1024) ? am : aw];
        float bd = (d == 1025) ? 0.0f : bf2f(vb);
        s[jh][rr] = (c[rr] + bd) * 0.125f;
      }
    }
    // online softmax (rows live in 16-lane groups)
    float mx[4];
#pragma unroll
    for (int rr = 0; rr < 4; ++rr) mx[rr] = fmaxf(s[0][rr], s[1][rr]);
#pragma unroll
    for (int msk = 1; msk <= 8; msk <<= 1)
#pragma unroll
      for (int rr = 0; rr < 4; ++rr) mx[rr] = fmaxf(mx[rr], __shfl_xor(mx[rr], msk));
    float al[4], p0[4], p1[4], ps[4];
#pragma unroll
    for (int rr = 0; rr < 4; ++rr) {
      float mn = fmaxf(mcur[rr], mx[rr]);
      al[rr] = __expf(mcur[rr] - mn);
      mcur[rr] = mn;
      p0[rr] = __expf(s[0][rr] - mn);
      p1[rr] = __expf(s[1][rr] - mn);
      ps[rr] = p0[rr] + p1[rr];
    }
#pragma unroll
    for (int msk = 1; msk <= 8; msk <<= 1)
#pragma unroll
      for (int rr = 0; rr < 4; ++rr) ps[rr] += __shfl_xor(ps[rr], msk);
#pragma unroll
    for (int rr = 0; rr < 4; ++rr) lsum[rr] = lsum[rr] * al[rr] + ps[rr];
#pragma unroll
    for (int nt = 0; nt < 4; ++nt)
#pragma unroll
      for (int rr = 0; rr < 4; ++rr) O[nt][rr] *= al[rr];
    // P -> LDS (A-operand layout source)
#pragma unroll
    for (int rr = 0; rr < 4; ++rr) {
      int row = quad * 4 + rr;
      pw[row * 40 + lc] = f2bf(p0[rr]);
      pw[row * 40 + 16 + lc] = f2bf(p1[rr]);
    }
    asm volatile("s_waitcnt lgkmcnt(0)" ::: "memory");
    s16x8 pf = *(const s16x8*)(pw + lc * 40 + quad * 8);
#pragma unroll
    for (int nt = 0; nt < 4; ++nt) {
      const unsigned short* vp = vT_p + (size_t)(nt * 16 + lc) * KL + k0 + quad * 8;
      s16x8 vf = *(const s16x8*)vp;
      O[nt] = mfma16(pf, vf, O[nt]);
    }
  }

  // ---- split-K merge ----
  __syncthreads();               // all waves done with bdS reads
#pragma unroll
  for (int nt = 0; nt < 4; ++nt)
#pragma unroll
    for (int rr = 0; rr < 4; ++rr)
      oS[(w * 16 + quad * 4 + rr) * 64 + nt * 16 + lc] = O[nt][rr];
  if (lc == 0) {
#pragma unroll
    for (int rr = 0; rr < 4; ++rr) {
      mlS[(w * 16 + quad * 4 + rr) * 2]     = mcur[rr];
      mlS[(w * 16 + quad * 4 + rr) * 2 + 1] = lsum[rr];
    }
  }
  __syncthreads();

  {
    int r = tid >> 4, c0 = (tid & 15) * 4;
    float M = -1e30f;
#pragma unroll
    for (int wv = 0; wv < 4; ++wv) M = fmaxf(M, mlS[(wv * 16 + r) * 2]);
    float L = 0.f, a0 = 0.f, a1 = 0.f, a2 = 0.f, a3 = 0.f;
#pragma unroll
    for (int wv = 0; wv < 4; ++wv) {
      float scl = __expf(mlS[(wv * 16 + r) * 2] - M);
      L += scl * mlS[(wv * 16 + r) * 2 + 1];
      const float* op = oS + (wv * 16 + r) * 64 + c0;
      a0 += scl * op[0]; a1 += scl * op[1]; a2 += scl * op[2]; a3 += scl * op[3];
    }
    float inv = 1.0f / L;
    float v[4] = {a0 * inv, a1 * inv, a2 * inv, a3 * inv};
    unsigned short hi[4], lo[4];
#pragma unroll
    for (int j = 0; j < 4; ++j) {
      hi[j] = f2bf(v[j]);
      lo[j] = f2bf(v[j] - bf2f(hi[j]));
    }
    size_t oidx = ((size_t)(b * QL + i0 + r)) * DM + h * DH + c0;
    *(ushort4*)&avhi[oidx] = make_ushort4(hi[0], hi[1], hi[2], hi[3]);
    *(ushort4*)&avlo[oidx] = make_ushort4(lo[0], lo[1], lo[2], lo[3]);
  }
}

// ---------------- final GEMM: out = av @ Wo, split bf16 (hi*hi + hi*lo + lo*hi) -------
__global__ __launch_bounds__(256) void gemm_final(
    const unsigned short* __restrict__ avhi, const unsigned short* __restrict__ avlo,
    const unsigned short* __restrict__ wohi, const unsigned short* __restrict__ wolo,
    float* __restrict__ out)
{
  __shared__ __align__(16) unsigned short As[128 * 32];
  __shared__ __align__(16) unsigned short Bs[128 * 32];
  int blk = blockIdx.x, tid = threadIdx.x;
  int mb = blk >> 3, nb = blk & 7;

  int srow = tid >> 1;
  int scol = (tid & 1) * 16;
  int lane = tid & 63, w = tid >> 6;
  int lc = lane & 15, quad = lane >> 4;
  int wm = (w & 1) * 64, wn = (w >> 1) * 64;
  unsigned short* la = &As[srow * 32 + scol];
  unsigned short* lb = &Bs[srow * 32 + scol];

  f32x4 acc[4][4];
#pragma unroll
  for (int mt = 0; mt < 4; ++mt)
#pragma unroll
    for (int nt = 0; nt < 4; ++nt) { acc[mt][nt][0] = 0.f; acc[mt][nt][1] = 0.f; acc[mt][nt][2] = 0.f; acc[mt][nt][3] = 0.f; }

  for (int k0 = 0; k0 < 3072; k0 += 32) {
    int seg = k0 >> 10, kk = k0 & 1023;
    const unsigned short* Ap = ((seg < 2) ? avhi : avlo) + (size_t)(mb * 128 + srow) * 1024 + kk + scol;
    const unsigned short* Bp = ((seg == 1) ? wolo : wohi) + (size_t)(nb * 128 + srow) * 1024 + kk + scol;
    s16x8 a0 = *(const s16x8*)Ap, a1 = *(const s16x8*)(Ap + 8);
    s16x8 b0 = *(const s16x8*)Bp, b1 = *(const s16x8*)(Bp + 8);
    __syncthreads();
    *(s16x8*)la = a0; *(s16x8*)(la + 8) = a1;
    *(s16x8*)lb = b0; *(s16x8*)(lb + 8) = b1;
    __syncthreads();
    s16x8 af[4], bf[4];
#pragma unroll
    for (int mt = 0; mt < 4; ++mt) af[mt] = *(const s16x8*)&As[(wm + mt * 16 + lc) * 32 + quad * 8];
#pragma unroll
    for (int nt = 0; nt < 4; ++nt) bf[nt] = *(const s16x8*)&Bs[(wn + nt * 16 + lc) * 32 + quad * 8];
#pragma unroll
    for (int mt = 0; mt < 4; ++mt)
#pragma unroll
      for (int nt = 0; nt < 4; ++nt) acc[mt][nt] = mfma16(af[mt], bf[nt], acc[mt][nt]);
  }

#pragma unroll
  for (int mt = 0; mt < 4; ++mt)
#pragma unroll
    for (int nt = 0; nt < 4; ++nt) {
      int n = nb * 128 + wn + nt * 16 + lc;
#pragma unroll
      for (int rr = 0; rr < 4; ++rr) {
        int m = mb * 128 + wm + mt * 16 + quad * 4 + rr;
        out[(size_t)m * 1024 + n] = acc[mt][nt][rr];
      }
    }
}

extern "C" void kernel_launch(void* const* d_in, const int* in_sizes, int n_in,
                              void* d_out, int out_size, void* d_ws, size_t ws_size,
                              hipStream_t stream) {
  (void)in_sizes; (void)n_in; (void)out_size; (void)ws_size;
  const float* h   = (const float*)d_in[0];
  const float* mem = (const float*)d_in[1];
  const float* r   = (const float*)d_in[2];
  const float* Wq  = (const float*)d_in[3];
  const float* Wk  = (const float*)d_in[4];
  const float* Wv  = (const float*)d_in[5];
  const float* Wr  = (const float*)d_in[6];
  const float* Wo  = (const float*)d_in[7];
  const float* rwb = (const float*)d_in[8];
  const float* rrb = (const float*)d_in[9];
  float* out = (float*)d_out;

  char* ws = (char*)d_ws;
  unsigned short* catb = (unsigned short*)(ws + 0);          // 8 MB
  unsigned short* rb   = (unsigned short*)(ws + 8388608);    // 4 MB
  unsigned short* wqt  = (unsigned short*)(ws + 12582912);   // 2 MB
  unsigned short* wkvt = (unsigned short*)(ws + 14680064);   // 4 MB
  unsigned short* wrt  = (unsigned short*)(ws + 18874368);   // 2 MB
  unsigned short* wohi = (unsigned short*)(ws + 20971520);   // 2 MB
  unsigned short* wolo = (unsigned short*)(ws + 23068672);   // 2 MB
  unsigned short* qwb  = (unsigned short*)(ws + 25165824);   // 4 MB
  unsigned short* qrb  = (unsigned short*)(ws + 29360128);   // 4 MB
  unsigned short* kbuf = (unsigned short*)(ws + 33554432);   // 8 MB
  unsigned short* vTb  = (unsigned short*)(ws + 41943040);   // 8 MB
  unsigned short* rhb  = (unsigned short*)(ws + 50331648);   // 4 MB
  unsigned short* avhi = (unsigned short*)(ws + 54525952);   // 4 MB
  unsigned short* avlo = (unsigned short*)(ws + 58720256);   // 4 MB

  build_inputs<<<6144, 256, 0, stream>>>(h, mem, r, catb, rb);
  transp_conv<<<dim3(16, 16), 256, 0, stream>>>(Wq, wqt);
  transp_conv<<<dim3(16, 16), 256, 0, stream>>>(Wk, wkvt);
  transp_conv<<<dim3(16, 16), 256, 0, stream>>>(Wv, wkvt + (size_t)1024 * 1024);
  transp_conv<<<dim3(16, 16), 256, 0, stream>>>(Wr, wrt);
  transp_conv_hilo<<<dim3(16, 16), 256, 0, stream>>>(Wo, wohi, wolo);
  gemm_all<<<768, 256, 0, stream>>>(catb, rb, wqt, wkvt, wrt, rwb, rrb,
                                    qwb, qrb, kbuf, vTb, rhb);
  attn<<<2048, 256, 0, stream>>>(qwb, qrb, kbuf, vTb, rhb, avhi, avlo);
  gemm_final<<<128, 256, 0, stream>>>(avhi, avlo, wohi, wolo, out);
}

// Round 3
// 411.604 us; speedup vs baseline: 4.2296x; 1.0443x over previous
//
#include <hip/hip_runtime.h>

#define DM 1024
#define NH 16
#define DH 64
#define QL 1024
#define KL 2048

typedef short s16x8 __attribute__((ext_vector_type(8)));
typedef float f32x4 __attribute__((ext_vector_type(4)));

__device__ __forceinline__ unsigned short f2bf(float f) {
  unsigned int u = __builtin_bit_cast(unsigned int, f);
  u += 0x7fffu + ((u >> 16) & 1u);
  return (unsigned short)(u >> 16);
}
__device__ __forceinline__ float bf2f(unsigned short b) {
  unsigned int u = ((unsigned int)b) << 16;
  return __builtin_bit_cast(float, u);
}
__device__ __forceinline__ f32x4 mfma16(s16x8 a, s16x8 b, f32x4 c) {
  return __builtin_amdgcn_mfma_f32_16x16x32_bf16(a, b, c, 0, 0, 0);
}
// async global->LDS, 16B per lane; LDS dest = wave-uniform base + lane*16
__device__ __forceinline__ void gl2lds16(const void* g, void* l) {
  __builtin_amdgcn_global_load_lds(
      (const __attribute__((address_space(1))) unsigned int*)g,
      (__attribute__((address_space(3))) unsigned int*)l, 16, 0, 0);
}

// ---------------- input conversion: catb (B*2048 x 1024 bf16), rb (2048x1024 bf16) ----
__global__ __launch_bounds__(256) void build_inputs(
    const float* __restrict__ h, const float* __restrict__ mem, const float* __restrict__ r,
    unsigned short* __restrict__ catb, unsigned short* __restrict__ rb)
{
  int idx = blockIdx.x * 256 + threadIdx.x;           // 0 .. 1.5M-1
  if (idx < 1048576) {                                // catb: 4M u16, 4 per thread
    int e = idx * 4;
    int row = e >> 10, col = e & 1023;
    int b = row >> 11, t = row & 2047;
    const float* s = (t < 1024) ? &mem[((size_t)(b * 1024 + t)) * 1024 + col]
                                : &h[((size_t)(b * 1024 + t - 1024)) * 1024 + col];
    float4 v = *(const float4*)s;
    *(ushort4*)&catb[e] = make_ushort4(f2bf(v.x), f2bf(v.y), f2bf(v.z), f2bf(v.w));
  } else {
    int e = (idx - 1048576) * 4;                      // rb: 2M elements
    float4 v = *(const float4*)&r[e];
    *(ushort4*)&rb[e] = make_ushort4(f2bf(v.x), f2bf(v.y), f2bf(v.z), f2bf(v.w));
  }
}

// ---------------- W (1024x1024 f32) -> Wt (1024x1024 bf16, transposed) ----------------
__global__ __launch_bounds__(256) void transp_conv(
    const float* __restrict__ src, unsigned short* __restrict__ dst)
{
  __shared__ unsigned short tS[64][72];
  int tid = threadIdx.x;
  int sr0 = blockIdx.x * 64, sc0 = blockIdx.y * 64;
  int rr = tid >> 4, c4 = (tid & 15) * 4;
#pragma unroll
  for (int i = 0; i < 4; ++i) {
    int row = rr + i * 16;
    float4 v = *(const float4*)&src[(size_t)(sr0 + row) * 1024 + sc0 + c4];
    tS[c4 + 0][row] = f2bf(v.x); tS[c4 + 1][row] = f2bf(v.y);
    tS[c4 + 2][row] = f2bf(v.z); tS[c4 + 3][row] = f2bf(v.w);
  }
  __syncthreads();
#pragma unroll
  for (int i = 0; i < 4; ++i) {
    int row = rr + i * 16;
    ushort4 o = make_ushort4(tS[row][c4], tS[row][c4 + 1], tS[row][c4 + 2], tS[row][c4 + 3]);
    *(ushort4*)&dst[(size_t)(sc0 + row) * 1024 + sr0 + c4] = o;
  }
}

// Wo -> transposed hi/lo bf16 split
__global__ __launch_bounds__(256) void transp_conv_hilo(
    const float* __restrict__ src, unsigned short* __restrict__ dhi, unsigned short* __restrict__ dlo)
{
  __shared__ unsigned short tH[64][72];
  __shared__ unsigned short tL[64][72];
  int tid = threadIdx.x;
  int sr0 = blockIdx.x * 64, sc0 = blockIdx.y * 64;
  int rr = tid >> 4, c4 = (tid & 15) * 4;
#pragma unroll
  for (int i = 0; i < 4; ++i) {
    int row = rr + i * 16;
    float4 v = *(const float4*)&src[(size_t)(sr0 + row) * 1024 + sc0 + c4];
    float vv[4] = {v.x, v.y, v.z, v.w};
#pragma unroll
    for (int j = 0; j < 4; ++j) {
      unsigned short hi = f2bf(vv[j]);
      tH[c4 + j][row] = hi;
      tL[c4 + j][row] = f2bf(vv[j] - bf2f(hi));
    }
  }
  __syncthreads();
#pragma unroll
  for (int i = 0; i < 4; ++i) {
    int row = rr + i * 16;
    size_t o = (size_t)(sc0 + row) * 1024 + sr0 + c4;
    *(ushort4*)&dhi[o] = make_ushort4(tH[row][c4], tH[row][c4 + 1], tH[row][c4 + 2], tH[row][c4 + 3]);
    *(ushort4*)&dlo[o] = make_ushort4(tL[row][c4], tL[row][c4 + 1], tL[row][c4 + 2], tL[row][c4 + 3]);
  }
}

// ---------------- projection GEMMs (bf16 MFMA, 128x128 tile, BK=32, async staging) ----
__global__ __launch_bounds__(256) void gemm_all(
    const unsigned short* __restrict__ catb, const unsigned short* __restrict__ rb,
    const unsigned short* __restrict__ wqt, const unsigned short* __restrict__ wkvt,
    const unsigned short* __restrict__ wrt,
    const float* __restrict__ rwb, const float* __restrict__ rrb,
    unsigned short* __restrict__ qwb, unsigned short* __restrict__ qrb,
    unsigned short* __restrict__ kbuf, unsigned short* __restrict__ vT,
    unsigned short* __restrict__ rhb)
{
  __shared__ __align__(16) unsigned short As[128 * 32];
  __shared__ __align__(16) unsigned short Bs[128 * 32];
  int blk = blockIdx.x, tid = threadIdx.x;
  int job, mb, nb;
  const unsigned short *A, *Bt;
  if (blk < 128)      { job = 0; A = catb; Bt = wqt;  mb = blk >> 3; nb = blk & 7; }
  else if (blk < 640) { job = 1; A = catb; Bt = wkvt; int q = blk - 128; mb = q >> 4; nb = q & 15; }
  else                { job = 2; A = rb;   Bt = wrt;  int q = blk - 640; mb = q >> 3; nb = q & 7; }

  const int w = tid >> 6;
  // chunk scheme: thread tid stages 16B chunks tid and 256+tid of each slab
  const int r0 = tid >> 2;                 // chunk0 row (0..63)
  const int c0u = (tid & 3) * 8;           // u16 col offset within 32-wide slab
  int ga_r0 = mb * 128 + r0, ga_r1 = mb * 128 + 64 + r0;
  if (job == 0) {
    ga_r0 = ((ga_r0 >> 10) << 11) + 1024 + (ga_r0 & 1023);
    ga_r1 = ((ga_r1 >> 10) << 11) + 1024 + (ga_r1 & 1023);
  }
  const unsigned short* gA0 = A + (size_t)ga_r0 * 1024 + c0u;
  const unsigned short* gA1 = A + (size_t)ga_r1 * 1024 + c0u;
  const unsigned short* gB0 = Bt + (size_t)(nb * 128 + r0) * 1024 + c0u;
  const unsigned short* gB1 = Bt + (size_t)(nb * 128 + 64 + r0) * 1024 + c0u;
  char* lA0 = (char*)As + w * 1024;  char* lA1 = (char*)As + 4096 + w * 1024;
  char* lB0 = (char*)Bs + w * 1024;  char* lB1 = (char*)Bs + 4096 + w * 1024;

  const int lane = tid & 63;
  const int lc = lane & 15, quad = lane >> 4;
  const int wm = (w & 1) * 64, wn = (w >> 1) * 64;

  f32x4 acc[4][4];
#pragma unroll
  for (int mt = 0; mt < 4; ++mt)
#pragma unroll
    for (int nt = 0; nt < 4; ++nt) { acc[mt][nt][0] = 0.f; acc[mt][nt][1] = 0.f; acc[mt][nt][2] = 0.f; acc[mt][nt][3] = 0.f; }

  for (int k0 = 0; k0 < 1024; k0 += 32) {
    __syncthreads();
    gl2lds16(gA0 + k0, lA0);
    gl2lds16(gA1 + k0, lA1);
    gl2lds16(gB0 + k0, lB0);
    gl2lds16(gB1 + k0, lB1);
    __syncthreads();
    s16x8 af[4], bf[4];
#pragma unroll
    for (int mt = 0; mt < 4; ++mt) af[mt] = *(const s16x8*)&As[(wm + mt * 16 + lc) * 32 + quad * 8];
#pragma unroll
    for (int nt = 0; nt < 4; ++nt) bf[nt] = *(const s16x8*)&Bs[(wn + nt * 16 + lc) * 32 + quad * 8];
#pragma unroll
    for (int mt = 0; mt < 4; ++mt)
#pragma unroll
      for (int nt = 0; nt < 4; ++nt) acc[mt][nt] = mfma16(af[mt], bf[nt], acc[mt][nt]);
  }

  // epilogue: C row m = mb*128+wm+mt*16+quad*4+rr ; col n = nb*128+wn+nt*16+lc
#pragma unroll
  for (int mt = 0; mt < 4; ++mt) {
    int t4 = mb * 128 + wm + mt * 16 + quad * 4;
#pragma unroll
    for (int nt = 0; nt < 4; ++nt) {
      int n = nb * 128 + wn + nt * 16 + lc;
      if (job == 0) {
        int hh = n >> 6, dh = n & 63;
        float bw = rwb[n], br = rrb[n];
#pragma unroll
        for (int rr = 0; rr < 4; ++rr) {
          int m = t4 + rr; int bb = m >> 10, t = m & 1023;
          size_t idx = (((size_t)bb * NH + hh) * QL + t) * DH + dh;
          qwb[idx] = f2bf(acc[mt][nt][rr] + bw);
          qrb[idx] = f2bf(acc[mt][nt][rr] + br);
        }
      } else if (job == 1) {
        int bb = t4 >> 11, t = t4 & 2047;
        if (n < 1024) {
          int hh = n >> 6, dh = n & 63;
#pragma unroll
          for (int rr = 0; rr < 4; ++rr)
            kbuf[(((size_t)bb * NH + hh) * KL + t + rr) * DH + dh] = f2bf(acc[mt][nt][rr]);
        } else {
          int n2 = n - 1024, hh = n2 >> 6, dh = n2 & 63;
          ushort4 pk = make_ushort4(f2bf(acc[mt][nt][0]), f2bf(acc[mt][nt][1]),
                                    f2bf(acc[mt][nt][2]), f2bf(acc[mt][nt][3]));
          *(ushort4*)&vT[(((size_t)bb * NH + hh) * DH + dh) * KL + t] = pk;
        }
      } else {
        int hh = n >> 6, dh = n & 63;
#pragma unroll
        for (int rr = 0; rr < 4; ++rr)
          rhb[((size_t)hh * KL + t4 + rr) * DH + dh] = f2bf(acc[mt][nt][rr]);
      }
    }
  }
}

// ---------------- fused flash attention with rel-shift (bf16 MFMA) --------------------
// block: (b, h, 16 q-rows). Phase 0: raw BD strip (17 x 2048 bf16) in LDS via MFMA.
// Main: 4 waves split-K (512 keys each), 4 iterations x 128 keys, no barriers.
#define BDSTR 2056
__global__ __launch_bounds__(256, 2) void attn(
    const unsigned short* __restrict__ qwb, const unsigned short* __restrict__ qrb,
    const unsigned short* __restrict__ kbuf, const unsigned short* __restrict__ vT,
    const unsigned short* __restrict__ rhb,
    unsigned short* __restrict__ avhi, unsigned short* __restrict__ avlo)
{
  __shared__ __align__(16) unsigned short bdS[17 * BDSTR];   // 69904 B
  __shared__ __align__(16) unsigned short pS[4 * 16 * 72];   // 9216 B
  float* oS  = (float*)bdS;            // merge overlay: [4][16][64] f32
  float* mlS = (float*)bdS + 4096;     // [4][16][2] f32

  const int tid = threadIdx.x;
  const int w = tid >> 6, lane = tid & 63;
  const int lc = lane & 15, quad = lane >> 4;
  const int is = blockIdx.x & 63, h = (blockIdx.x >> 6) & 15, b = blockIdx.x >> 10;
  const int i0 = is * 16;
  const size_t bh = (size_t)b * NH + h;

  const unsigned short* qw_p = qwb + bh * QL * DH;
  const unsigned short* qr_p = qrb + bh * QL * DH;
  const unsigned short* kb_p = kbuf + bh * KL * DH;
  const unsigned short* vT_p = vT + bh * DH * KL;
  const unsigned short* rh_p = rhb + (size_t)h * KL * DH;

  // ---- phase 0: raw BD strip rows i0..i0+16 (17), cols 0..2047; 1-deep R prefetch ----
  {
    int r0 = i0 + lc;
    int r1 = i0 + 16 + lc; if (r1 > 1023) r1 = 1023;   // clamp; clamped rows unused
    s16x8 qa00 = *(const s16x8*)(qr_p + (size_t)r0 * DH + quad * 8);
    s16x8 qa01 = *(const s16x8*)(qr_p + (size_t)r0 * DH + 32 + quad * 8);
    s16x8 qa10 = *(const s16x8*)(qr_p + (size_t)r1 * DH + quad * 8);
    s16x8 qa11 = *(const s16x8*)(qr_p + (size_t)r1 * DH + 32 + quad * 8);
    const unsigned short* rp = rh_p + (size_t)(w * 32 * 16 + lc) * DH + quad * 8;
    s16x8 rf0 = *(const s16x8*)rp;
    s16x8 rf1 = *(const s16x8*)(rp + 32);
    for (int xt = w * 32; xt < w * 32 + 32; ++xt) {
      s16x8 cf0 = rf0, cf1 = rf1;
      if (xt + 1 < w * 32 + 32) {
        const unsigned short* rpn = rh_p + (size_t)((xt + 1) * 16 + lc) * DH + quad * 8;
        rf0 = *(const s16x8*)rpn;
        rf1 = *(const s16x8*)(rpn + 32);
      }
      f32x4 c0; c0[0] = 0.f; c0[1] = 0.f; c0[2] = 0.f; c0[3] = 0.f;
      f32x4 c1 = c0;
      c0 = mfma16(qa00, cf0, c0); c0 = mfma16(qa01, cf1, c0);
      c1 = mfma16(qa10, cf0, c1); c1 = mfma16(qa11, cf1, c1);
      int col = xt * 16 + lc;
#pragma unroll
      for (int rr = 0; rr < 4; ++rr) bdS[(quad * 4 + rr) * BDSTR + col] = f2bf(c0[rr]);
      if (lane < 16) bdS[16 * BDSTR + col] = f2bf(c1[0]);
    }
  }
  __syncthreads();

  // ---- main split-K loop: wave w handles k in [w*512, w*512+512), 4 x 128 keys ----
  s16x8 qwf0 = *(const s16x8*)(qw_p + (size_t)(i0 + lc) * DH + quad * 8);
  s16x8 qwf1 = *(const s16x8*)(qw_p + (size_t)(i0 + lc) * DH + 32 + quad * 8);

  f32x4 O[4];
#pragma unroll
  for (int nt = 0; nt < 4; ++nt) { O[nt][0] = 0.f; O[nt][1] = 0.f; O[nt][2] = 0.f; O[nt][3] = 0.f; }
  float mcur[4] = {-1e30f, -1e30f, -1e30f, -1e30f};
  float lsum[4] = {0.f, 0.f, 0.f, 0.f};
  unsigned short* pw = pS + w * 16 * 72;
  int ebase[4];
#pragma unroll
  for (int rr = 0; rr < 4; ++rr) ebase[rr] = lc - (quad * 4 + rr) - i0;

  for (int it = 0; it < 4; ++it) {
    const int k0 = w * 512 + it * 128;
    // K fragments for 8 16-key tiles (batched; compiler pipelines the loads)
    s16x8 kf[8][2];
#pragma unroll
    for (int t = 0; t < 8; ++t) {
      const unsigned short* kp = kb_p + (size_t)(k0 + t * 16 + lc) * DH + quad * 8;
      kf[t][0] = *(const s16x8*)kp;
      kf[t][1] = *(const s16x8*)(kp + 32);
    }
    // QK^T
    float sc[8][4];
#pragma unroll
    for (int t = 0; t < 8; ++t) {
      f32x4 c; c[0] = 0.f; c[1] = 0.f; c[2] = 0.f; c[3] = 0.f;
      c = mfma16(qwf0, kf[t][0], c);
      c = mfma16(qwf1, kf[t][1], c);
#pragma unroll
      for (int rr = 0; rr < 4; ++rr) {
        int row = quad * 4 + rr;
        int d = k0 + t * 16 + ebase[rr];
        int am = row * BDSTR + (d + 1023);
        int aw = (row + 1) * BDSTR + (d - 1026);
        unsigned short vb = bdS[(d <= 1024) ? am : aw];
        float bd = (d == 1025) ? 0.0f : bf2f(vb);
        sc[t][rr] = (c[rr] + bd) * 0.125f;
      }
    }
    // one online-softmax round per 128 keys
    float mx[4];
#pragma unroll
    for (int rr = 0; rr < 4; ++rr) {
      mx[rr] = sc[0][rr];
#pragma unroll
      for (int t = 1; t < 8; ++t) mx[rr] = fmaxf(mx[rr], sc[t][rr]);
    }
#pragma unroll
    for (int msk = 1; msk <= 8; msk <<= 1)
#pragma unroll
      for (int rr = 0; rr < 4; ++rr) mx[rr] = fmaxf(mx[rr], __shfl_xor(mx[rr], msk));
    float al[4], ps[4];
    float p[8][4];
#pragma unroll
    for (int rr = 0; rr < 4; ++rr) {
      float mn = fmaxf(mcur[rr], mx[rr]);
      al[rr] = __expf(mcur[rr] - mn);
      mcur[rr] = mn;
      ps[rr] = 0.f;
#pragma unroll
      for (int t = 0; t < 8; ++t) { p[t][rr] = __expf(sc[t][rr] - mn); ps[rr] += p[t][rr]; }
    }
#pragma unroll
    for (int msk = 1; msk <= 8; msk <<= 1)
#pragma unroll
      for (int rr = 0; rr < 4; ++rr) ps[rr] += __shfl_xor(ps[rr], msk);
#pragma unroll
    for (int rr = 0; rr < 4; ++rr) lsum[rr] = lsum[rr] * al[rr] + ps[rr];
#pragma unroll
    for (int nt = 0; nt < 4; ++nt)
#pragma unroll
      for (int rr = 0; rr < 4; ++rr) O[nt][rr] *= al[rr];

    // PV in two 64-key halves (P via LDS round trip, wave-local ordering)
#pragma unroll
    for (int hb = 0; hb < 2; ++hb) {
#pragma unroll
      for (int tt = 0; tt < 4; ++tt)
#pragma unroll
        for (int rr = 0; rr < 4; ++rr)
          pw[(quad * 4 + rr) * 72 + tt * 16 + lc] = f2bf(p[hb * 4 + tt][rr]);
      asm volatile("s_waitcnt lgkmcnt(0)" ::: "memory");
      s16x8 pf0 = *(const s16x8*)(pw + lc * 72 + quad * 8);
      s16x8 pf1 = *(const s16x8*)(pw + lc * 72 + 32 + quad * 8);
#pragma unroll
      for (int nt = 0; nt < 4; ++nt) {
        const unsigned short* vp = vT_p + (size_t)(nt * 16 + lc) * KL + k0 + hb * 64 + quad * 8;
        s16x8 vf0 = *(const s16x8*)vp;
        s16x8 vf1 = *(const s16x8*)(vp + 32);
        O[nt] = mfma16(pf0, vf0, O[nt]);
        O[nt] = mfma16(pf1, vf1, O[nt]);
      }
      if (hb == 0) { asm volatile("s_waitcnt lgkmcnt(0)" ::: "memory"); }  // pf reads done before overwrite
    }
  }

  // ---- split-K merge ----
  __syncthreads();               // all waves done with bdS reads
#pragma unroll
  for (int nt = 0; nt < 4; ++nt)
#pragma unroll
    for (int rr = 0; rr < 4; ++rr)
      oS[(w * 16 + quad * 4 + rr) * 64 + nt * 16 + lc] = O[nt][rr];
  if (lc == 0) {
#pragma unroll
    for (int rr = 0; rr < 4; ++rr) {
      mlS[(w * 16 + quad * 4 + rr) * 2]     = mcur[rr];
      mlS[(w * 16 + quad * 4 + rr) * 2 + 1] = lsum[rr];
    }
  }
  __syncthreads();

  {
    int r = tid >> 4, c0 = (tid & 15) * 4;
    float M = -1e30f;
#pragma unroll
    for (int wv = 0; wv < 4; ++wv) M = fmaxf(M, mlS[(wv * 16 + r) * 2]);
    float L = 0.f, a0 = 0.f, a1 = 0.f, a2 = 0.f, a3 = 0.f;
#pragma unroll
    for (int wv = 0; wv < 4; ++wv) {
      float scl = __expf(mlS[(wv * 16 + r) * 2] - M);
      L += scl * mlS[(wv * 16 + r) * 2 + 1];
      const float* op = oS + (wv * 16 + r) * 64 + c0;
      a0 += scl * op[0]; a1 += scl * op[1]; a2 += scl * op[2]; a3 += scl * op[3];
    }
    float inv = 1.0f / L;
    float v[4] = {a0 * inv, a1 * inv, a2 * inv, a3 * inv};
    unsigned short hi[4], lo[4];
#pragma unroll
    for (int j = 0; j < 4; ++j) {
      hi[j] = f2bf(v[j]);
      lo[j] = f2bf(v[j] - bf2f(hi[j]));
    }
    size_t oidx = ((size_t)(b * QL + i0 + r)) * DM + h * DH + c0;
    *(ushort4*)&avhi[oidx] = make_ushort4(hi[0], hi[1], hi[2], hi[3]);
    *(ushort4*)&avlo[oidx] = make_ushort4(lo[0], lo[1], lo[2], lo[3]);
  }
}

// ---------------- final GEMM: out = av @ Wo, split bf16 (hi*hi + hi*lo + lo*hi) -------
__global__ __launch_bounds__(256) void gemm_final(
    const unsigned short* __restrict__ avhi, const unsigned short* __restrict__ avlo,
    const unsigned short* __restrict__ wohi, const unsigned short* __restrict__ wolo,
    float* __restrict__ out)
{
  __shared__ __align__(16) unsigned short As[128 * 32];
  __shared__ __align__(16) unsigned short Bs[128 * 32];
  int blk = blockIdx.x, tid = threadIdx.x;
  int mb = blk >> 3, nb = blk & 7;

  const int w = tid >> 6;
  const int r0 = tid >> 2;
  const int c0u = (tid & 3) * 8;
  const size_t arow0 = (size_t)(mb * 128 + r0) * 1024;
  const size_t arow1 = (size_t)(mb * 128 + 64 + r0) * 1024;
  const size_t brow0 = (size_t)(nb * 128 + r0) * 1024;
  const size_t brow1 = (size_t)(nb * 128 + 64 + r0) * 1024;
  char* lA0 = (char*)As + w * 1024;  char* lA1 = (char*)As + 4096 + w * 1024;
  char* lB0 = (char*)Bs + w * 1024;  char* lB1 = (char*)Bs + 4096 + w * 1024;

  const int lane = tid & 63;
  const int lc = lane & 15, quad = lane >> 4;
  const int wm = (w & 1) * 64, wn = (w >> 1) * 64;

  f32x4 acc[4][4];
#pragma unroll
  for (int mt = 0; mt < 4; ++mt)
#pragma unroll
    for (int nt = 0; nt < 4; ++nt) { acc[mt][nt][0] = 0.f; acc[mt][nt][1] = 0.f; acc[mt][nt][2] = 0.f; acc[mt][nt][3] = 0.f; }

  for (int k0 = 0; k0 < 3072; k0 += 32) {
    int seg = k0 >> 10, kk = k0 & 1023;
    const unsigned short* Ab = ((seg < 2) ? avhi : avlo);
    const unsigned short* Bb = ((seg == 1) ? wolo : wohi);
    __syncthreads();
    gl2lds16(Ab + arow0 + kk + c0u, lA0);
    gl2lds16(Ab + arow1 + kk + c0u, lA1);
    gl2lds16(Bb + brow0 + kk + c0u, lB0);
    gl2lds16(Bb + brow1 + kk + c0u, lB1);
    __syncthreads();
    s16x8 af[4], bf[4];
#pragma unroll
    for (int mt = 0; mt < 4; ++mt) af[mt] = *(const s16x8*)&As[(wm + mt * 16 + lc) * 32 + quad * 8];
#pragma unroll
    for (int nt = 0; nt < 4; ++nt) bf[nt] = *(const s16x8*)&Bs[(wn + nt * 16 + lc) * 32 + quad * 8];
#pragma unroll
    for (int mt = 0; mt < 4; ++mt)
#pragma unroll
      for (int nt = 0; nt < 4; ++nt) acc[mt][nt] = mfma16(af[mt], bf[nt], acc[mt][nt]);
  }

#pragma unroll
  for (int mt = 0; mt < 4; ++mt)
#pragma unroll
    for (int nt = 0; nt < 4; ++nt) {
      int n = nb * 128 + wn + nt * 16 + lc;
#pragma unroll
      for (int rr = 0; rr < 4; ++rr) {
        int m = mb * 128 + wm + mt * 16 + quad * 4 + rr;
        out[(size_t)m * 1024 + n] = acc[mt][nt][rr];
      }
    }
}

extern "C" void kernel_launch(void* const* d_in, const int* in_sizes, int n_in,
                              void* d_out, int out_size, void* d_ws, size_t ws_size,
                              hipStream_t stream) {
  (void)in_sizes; (void)n_in; (void)out_size; (void)ws_size;
  const float* h   = (const float*)d_in[0];
  const float* mem = (const float*)d_in[1];
  const float* r   = (const float*)d_in[2];
  const float* Wq  = (const float*)d_in[3];
  const float* Wk  = (const float*)d_in[4];
  const float* Wv  = (const float*)d_in[5];
  const float* Wr  = (const float*)d_in[6];
  const float* Wo  = (const float*)d_in[7];
  const float* rwb = (const float*)d_in[8];
  const float* rrb = (const float*)d_in[9];
  float* out = (float*)d_out;

  char* ws = (char*)d_ws;
  unsigned short* catb = (unsigned short*)(ws + 0);          // 8 MB
  unsigned short* rb   = (unsigned short*)(ws + 8388608);    // 4 MB
  unsigned short* wqt  = (unsigned short*)(ws + 12582912);   // 2 MB
  unsigned short* wkvt = (unsigned short*)(ws + 14680064);   // 4 MB
  unsigned short* wrt  = (unsigned short*)(ws + 18874368);   // 2 MB
  unsigned short* wohi = (unsigned short*)(ws + 20971520);   // 2 MB
  unsigned short* wolo = (unsigned short*)(ws + 23068672);   // 2 MB
  unsigned short* qwb  = (unsigned short*)(ws + 25165824);   // 4 MB
  unsigned short* qrb  = (unsigned short*)(ws + 29360128);   // 4 MB
  unsigned short* kbuf = (unsigned short*)(ws + 33554432);   // 8 MB
  unsigned short* vTb  = (unsigned short*)(ws + 41943040);   // 8 MB
  unsigned short* rhb  = (unsigned short*)(ws + 50331648);   // 4 MB
  unsigned short* avhi = (unsigned short*)(ws + 54525952);   // 4 MB
  unsigned short* avlo = (unsigned short*)(ws + 58720256);   // 4 MB

  build_inputs<<<6144, 256, 0, stream>>>(h, mem, r, catb, rb);
  transp_conv<<<dim3(16, 16), 256, 0, stream>>>(Wq, wqt);
  transp_conv<<<dim3(16, 16), 256, 0, stream>>>(Wk, wkvt);
  transp_conv<<<dim3(16, 16), 256, 0, stream>>>(Wv, wkvt + (size_t)1024 * 1024);
  transp_conv<<<dim3(16, 16), 256, 0, stream>>>(Wr, wrt);
  transp_conv_hilo<<<dim3(16, 16), 256, 0, stream>>>(Wo, wohi, wolo);
  gemm_all<<<768, 256, 0, stream>>>(catb, rb, wqt, wkvt, wrt, rwb, rrb,
                                    qwb, qrb, kbuf, vTb, rhb);
  attn<<<2048, 256, 0, stream>>>(qwb, qrb, kbuf, vTb, rhb, avhi, avlo);
  gemm_final<<<128, 256, 0, stream>>>(avhi, avlo, wohi, wolo, out);
}

// Round 4
// 408.493 us; speedup vs baseline: 4.2618x; 1.0076x over previous
//
#include <hip/hip_runtime.h>

#define DM 1024
#define NH 16
#define DH 64
#define QL 1024
#define KL 2048

typedef short s16x8 __attribute__((ext_vector_type(8)));
typedef float f32x4 __attribute__((ext_vector_type(4)));

__device__ __forceinline__ unsigned short f2bf(float f) {
  unsigned int u = __builtin_bit_cast(unsigned int, f);
  u += 0x7fffu + ((u >> 16) & 1u);
  return (unsigned short)(u >> 16);
}
__device__ __forceinline__ float bf2f(unsigned short b) {
  unsigned int u = ((unsigned int)b) << 16;
  return __builtin_bit_cast(float, u);
}
__device__ __forceinline__ f32x4 mfma16(s16x8 a, s16x8 b, f32x4 c) {
  return __builtin_amdgcn_mfma_f32_16x16x32_bf16(a, b, c, 0, 0, 0);
}
// async global->LDS, 16B per lane; LDS dest = wave-uniform base + lane*16
__device__ __forceinline__ void gl2lds16(const void* g, void* l) {
  __builtin_amdgcn_global_load_lds(
      (const __attribute__((address_space(1))) unsigned int*)g,
      (__attribute__((address_space(3))) unsigned int*)l, 16, 0, 0);
}

// ---------------- input conversion: catb (B*2048 x 1024 bf16), rb (2048x1024 bf16) ----
__global__ __launch_bounds__(256) void build_inputs(
    const float* __restrict__ h, const float* __restrict__ mem, const float* __restrict__ r,
    unsigned short* __restrict__ catb, unsigned short* __restrict__ rb)
{
  int idx = blockIdx.x * 256 + threadIdx.x;           // 0 .. 1.5M-1
  if (idx < 1048576) {                                // catb: 4M u16, 4 per thread
    int e = idx * 4;
    int row = e >> 10, col = e & 1023;
    int b = row >> 11, t = row & 2047;
    const float* s = (t < 1024) ? &mem[((size_t)(b * 1024 + t)) * 1024 + col]
                                : &h[((size_t)(b * 1024 + t - 1024)) * 1024 + col];
    float4 v = *(const float4*)s;
    *(ushort4*)&catb[e] = make_ushort4(f2bf(v.x), f2bf(v.y), f2bf(v.z), f2bf(v.w));
  } else {
    int e = (idx - 1048576) * 4;                      // rb: 2M elements
    float4 v = *(const float4*)&r[e];
    *(ushort4*)&rb[e] = make_ushort4(f2bf(v.x), f2bf(v.y), f2bf(v.z), f2bf(v.w));
  }
}

// ---------------- fused weight prep: 5 jobs x 256 tile-blocks -------------------------
// job 0..3: transpose+bf16 Wq->wqt, Wk->wkvt, Wv->wkvt+1M, Wr->wrt
// job 4: Wo -> transposed hi/lo split
__global__ __launch_bounds__(256) void prep_weights(
    const float* __restrict__ Wq, const float* __restrict__ Wk, const float* __restrict__ Wv,
    const float* __restrict__ Wr, const float* __restrict__ Wo,
    unsigned short* __restrict__ wqt, unsigned short* __restrict__ wkvt,
    unsigned short* __restrict__ wrt,
    unsigned short* __restrict__ wohi, unsigned short* __restrict__ wolo)
{
  __shared__ unsigned short tH[64][72];
  __shared__ unsigned short tL[64][72];
  int job = blockIdx.x >> 8;
  int tb = blockIdx.x & 255;
  int sr0 = (tb >> 4) * 64, sc0 = (tb & 15) * 64;
  const float* src = (job == 0) ? Wq : (job == 1) ? Wk : (job == 2) ? Wv : (job == 3) ? Wr : Wo;
  int tid = threadIdx.x;
  int rr = tid >> 4, c4 = (tid & 15) * 4;
#pragma unroll
  for (int i = 0; i < 4; ++i) {
    int row = rr + i * 16;
    float4 v = *(const float4*)&src[(size_t)(sr0 + row) * 1024 + sc0 + c4];
    float vv[4] = {v.x, v.y, v.z, v.w};
#pragma unroll
    for (int j = 0; j < 4; ++j) {
      unsigned short hi = f2bf(vv[j]);
      tH[c4 + j][row] = hi;
      if (job == 4) tL[c4 + j][row] = f2bf(vv[j] - bf2f(hi));
    }
  }
  __syncthreads();
  unsigned short* dst = (job == 0) ? wqt : (job == 1) ? wkvt
                      : (job == 2) ? (wkvt + (size_t)1024 * 1024)
                      : (job == 3) ? wrt : wohi;
#pragma unroll
  for (int i = 0; i < 4; ++i) {
    int row = rr + i * 16;
    size_t o = (size_t)(sc0 + row) * 1024 + sr0 + c4;
    *(ushort4*)&dst[o] = make_ushort4(tH[row][c4], tH[row][c4 + 1], tH[row][c4 + 2], tH[row][c4 + 3]);
    if (job == 4)
      *(ushort4*)&wolo[o] = make_ushort4(tL[row][c4], tL[row][c4 + 1], tL[row][c4 + 2], tL[row][c4 + 3]);
  }
}

// ---------------- projection GEMMs (bf16 MFMA, 128x128 tile, BK=32, async staging) ----
__global__ __launch_bounds__(256) void gemm_all(
    const unsigned short* __restrict__ catb, const unsigned short* __restrict__ rb,
    const unsigned short* __restrict__ wqt, const unsigned short* __restrict__ wkvt,
    const unsigned short* __restrict__ wrt,
    const float* __restrict__ rwb, const float* __restrict__ rrb,
    unsigned short* __restrict__ qwb, unsigned short* __restrict__ qrb,
    unsigned short* __restrict__ kbuf, unsigned short* __restrict__ vT,
    unsigned short* __restrict__ rhb)
{
  __shared__ __align__(16) unsigned short As[128 * 32];
  __shared__ __align__(16) unsigned short Bs[128 * 32];
  int blk = blockIdx.x, tid = threadIdx.x;
  int job, mb, nb;
  const unsigned short *A, *Bt;
  if (blk < 128)      { job = 0; A = catb; Bt = wqt;  mb = blk >> 3; nb = blk & 7; }
  else if (blk < 640) { job = 1; A = catb; Bt = wkvt; int q = blk - 128; mb = q >> 4; nb = q & 15; }
  else                { job = 2; A = rb;   Bt = wrt;  int q = blk - 640; mb = q >> 3; nb = q & 7; }

  const int w = tid >> 6;
  const int r0 = tid >> 2;                 // chunk0 row (0..63)
  const int c0u = (tid & 3) * 8;           // u16 col offset within 32-wide slab
  int ga_r0 = mb * 128 + r0, ga_r1 = mb * 128 + 64 + r0;
  if (job == 0) {
    ga_r0 = ((ga_r0 >> 10) << 11) + 1024 + (ga_r0 & 1023);
    ga_r1 = ((ga_r1 >> 10) << 11) + 1024 + (ga_r1 & 1023);
  }
  const unsigned short* gA0 = A + (size_t)ga_r0 * 1024 + c0u;
  const unsigned short* gA1 = A + (size_t)ga_r1 * 1024 + c0u;
  const unsigned short* gB0 = Bt + (size_t)(nb * 128 + r0) * 1024 + c0u;
  const unsigned short* gB1 = Bt + (size_t)(nb * 128 + 64 + r0) * 1024 + c0u;
  char* lA0 = (char*)As + w * 1024;  char* lA1 = (char*)As + 4096 + w * 1024;
  char* lB0 = (char*)Bs + w * 1024;  char* lB1 = (char*)Bs + 4096 + w * 1024;

  const int lane = tid & 63;
  const int lc = lane & 15, quad = lane >> 4;
  const int wm = (w & 1) * 64, wn = (w >> 1) * 64;

  f32x4 acc[4][4];
#pragma unroll
  for (int mt = 0; mt < 4; ++mt)
#pragma unroll
    for (int nt = 0; nt < 4; ++nt) { acc[mt][nt][0] = 0.f; acc[mt][nt][1] = 0.f; acc[mt][nt][2] = 0.f; acc[mt][nt][3] = 0.f; }

  for (int k0 = 0; k0 < 1024; k0 += 32) {
    __syncthreads();
    gl2lds16(gA0 + k0, lA0);
    gl2lds16(gA1 + k0, lA1);
    gl2lds16(gB0 + k0, lB0);
    gl2lds16(gB1 + k0, lB1);
    __syncthreads();
    s16x8 af[4], bf[4];
#pragma unroll
    for (int mt = 0; mt < 4; ++mt) af[mt] = *(const s16x8*)&As[(wm + mt * 16 + lc) * 32 + quad * 8];
#pragma unroll
    for (int nt = 0; nt < 4; ++nt) bf[nt] = *(const s16x8*)&Bs[(wn + nt * 16 + lc) * 32 + quad * 8];
#pragma unroll
    for (int mt = 0; mt < 4; ++mt)
#pragma unroll
      for (int nt = 0; nt < 4; ++nt) acc[mt][nt] = mfma16(af[mt], bf[nt], acc[mt][nt]);
  }

#pragma unroll
  for (int mt = 0; mt < 4; ++mt) {
    int t4 = mb * 128 + wm + mt * 16 + quad * 4;
#pragma unroll
    for (int nt = 0; nt < 4; ++nt) {
      int n = nb * 128 + wn + nt * 16 + lc;
      if (job == 0) {
        int hh = n >> 6, dh = n & 63;
        float bw = rwb[n], br = rrb[n];
#pragma unroll
        for (int rr = 0; rr < 4; ++rr) {
          int m = t4 + rr; int bb = m >> 10, t = m & 1023;
          size_t idx = (((size_t)bb * NH + hh) * QL + t) * DH + dh;
          qwb[idx] = f2bf(acc[mt][nt][rr] + bw);
          qrb[idx] = f2bf(acc[mt][nt][rr] + br);
        }
      } else if (job == 1) {
        int bb = t4 >> 11, t = t4 & 2047;
        if (n < 1024) {
          int hh = n >> 6, dh = n & 63;
#pragma unroll
          for (int rr = 0; rr < 4; ++rr)
            kbuf[(((size_t)bb * NH + hh) * KL + t + rr) * DH + dh] = f2bf(acc[mt][nt][rr]);
        } else {
          int n2 = n - 1024, hh = n2 >> 6, dh = n2 & 63;
          ushort4 pk = make_ushort4(f2bf(acc[mt][nt][0]), f2bf(acc[mt][nt][1]),
                                    f2bf(acc[mt][nt][2]), f2bf(acc[mt][nt][3]));
          *(ushort4*)&vT[(((size_t)bb * NH + hh) * DH + dh) * KL + t] = pk;
        }
      } else {
        int hh = n >> 6, dh = n & 63;
#pragma unroll
        for (int rr = 0; rr < 4; ++rr)
          rhb[((size_t)hh * KL + t4 + rr) * DH + dh] = f2bf(acc[mt][nt][rr]);
      }
    }
  }
}

// ---------------- fused flash attention with rel-shift (bf16 MFMA) --------------------
// block: (b, h, 16 q-rows), 512 threads / 8 waves. Phase 0: raw BD strip in LDS via MFMA.
// Main: 8-way split-K (256 keys/wave), fixed-shift softmax (no max reduction, no rescale).
// Merge: plain sum of per-wave (O, l).
#define BDSTR 2058
__global__ __launch_bounds__(512, 4) void attn(
    const unsigned short* __restrict__ qwb, const unsigned short* __restrict__ qrb,
    const unsigned short* __restrict__ kbuf, const unsigned short* __restrict__ vT,
    const unsigned short* __restrict__ rhb,
    unsigned short* __restrict__ avhi, unsigned short* __restrict__ avlo)
{
  __shared__ __align__(16) unsigned short bdS[17 * BDSTR];   // 69972 B
  __shared__ __align__(16) unsigned short pS[8 * 16 * 36];   // 9216 B
  float* oS = (float*)bdS;             // merge overlay: [8][16][64] f32
  float* lS = (float*)bdS + 8192;      // [8][16] f32

  const int tid = threadIdx.x;
  const int w = tid >> 6, lane = tid & 63;
  const int lc = lane & 15, quad = lane >> 4;
  const int is = blockIdx.x & 63, h = (blockIdx.x >> 6) & 15, b = blockIdx.x >> 10;
  const int i0 = is * 16;
  const size_t bh = (size_t)b * NH + h;

  const unsigned short* qw_p = qwb + bh * QL * DH;
  const unsigned short* qr_p = qrb + bh * QL * DH;
  const unsigned short* kb_p = kbuf + bh * KL * DH;
  const unsigned short* vT_p = vT + bh * DH * KL;
  const unsigned short* rh_p = rhb + (size_t)h * KL * DH;

  // ---- phase 0: raw BD strip rows i0..i0+16 (17), wave w covers cols [w*256,w*256+256) ----
  {
    int r0 = i0 + lc;
    int r1 = i0 + 16 + lc; if (r1 > 1023) r1 = 1023;   // clamp; clamped rows unused
    s16x8 qa00 = *(const s16x8*)(qr_p + (size_t)r0 * DH + quad * 8);
    s16x8 qa01 = *(const s16x8*)(qr_p + (size_t)r0 * DH + 32 + quad * 8);
    s16x8 qa10 = *(const s16x8*)(qr_p + (size_t)r1 * DH + quad * 8);
    s16x8 qa11 = *(const s16x8*)(qr_p + (size_t)r1 * DH + 32 + quad * 8);
    const int xt0 = w * 16;
    const unsigned short* rp = rh_p + (size_t)(xt0 * 16 + lc) * DH + quad * 8;
    s16x8 rf0 = *(const s16x8*)rp;
    s16x8 rf1 = *(const s16x8*)(rp + 32);
    for (int xt = xt0; xt < xt0 + 16; ++xt) {
      s16x8 cf0 = rf0, cf1 = rf1;
      if (xt + 1 < xt0 + 16) {
        const unsigned short* rpn = rh_p + (size_t)((xt + 1) * 16 + lc) * DH + quad * 8;
        rf0 = *(const s16x8*)rpn;
        rf1 = *(const s16x8*)(rpn + 32);
      }
      f32x4 c0; c0[0] = 0.f; c0[1] = 0.f; c0[2] = 0.f; c0[3] = 0.f;
      f32x4 c1 = c0;
      c0 = mfma16(qa00, cf0, c0); c0 = mfma16(qa01, cf1, c0);
      c1 = mfma16(qa10, cf0, c1); c1 = mfma16(qa11, cf1, c1);
      int col = xt * 16 + lc;
#pragma unroll
      for (int rr = 0; rr < 4; ++rr) bdS[(quad * 4 + rr) * BDSTR + col] = f2bf(c0[rr]);
      if (lane < 16) bdS[16 * BDSTR + col] = f2bf(c1[0]);
    }
  }
  __syncthreads();

  // ---- main split-K loop: wave w handles k in [w*256, w*256+256), 2 x 128 keys ----
  s16x8 qwf0 = *(const s16x8*)(qw_p + (size_t)(i0 + lc) * DH + quad * 8);
  s16x8 qwf1 = *(const s16x8*)(qw_p + (size_t)(i0 + lc) * DH + 32 + quad * 8);

  f32x4 O[4];
#pragma unroll
  for (int nt = 0; nt < 4; ++nt) { O[nt][0] = 0.f; O[nt][1] = 0.f; O[nt][2] = 0.f; O[nt][3] = 0.f; }
  float lsum[4] = {0.f, 0.f, 0.f, 0.f};
  unsigned short* pw = pS + w * 16 * 36;
  int ebase[4];
#pragma unroll
  for (int rr = 0; rr < 4; ++rr) ebase[rr] = lc - (quad * 4 + rr) - i0;

  for (int it = 0; it < 2; ++it) {
    const int k0 = w * 256 + it * 128;
    float p[8][4];
    // QK^T + bd gather, two 4-tile halves (limits VGPR pressure)
#pragma unroll
    for (int th = 0; th < 2; ++th) {
      s16x8 kf[4][2];
#pragma unroll
      for (int t4 = 0; t4 < 4; ++t4) {
        const unsigned short* kp = kb_p + (size_t)(k0 + (th * 4 + t4) * 16 + lc) * DH + quad * 8;
        kf[t4][0] = *(const s16x8*)kp;
        kf[t4][1] = *(const s16x8*)(kp + 32);
      }
#pragma unroll
      for (int t4 = 0; t4 < 4; ++t4) {
        const int t = th * 4 + t4;
        f32x4 c; c[0] = 0.f; c[1] = 0.f; c[2] = 0.f; c[3] = 0.f;
        c = mfma16(qwf0, kf[t4][0], c);
        c = mfma16(qwf1, kf[t4][1], c);
#pragma unroll
        for (int rr = 0; rr < 4; ++rr) {
          int row = quad * 4 + rr;
          int d = k0 + t * 16 + ebase[rr];
          int am = row * BDSTR + (d + 1023);
          int aw = (row + 1) * BDSTR + (d - 1026);
          unsigned short vb = bdS[(d <= 1024) ? am : aw];
          float bd = (d == 1025) ? 0.0f : bf2f(vb);
          p[t][rr] = c[rr] + bd;
        }
      }
    }
    // fixed-shift softmax: p = exp(s/8 - 12); shift cancels in O/l
#pragma unroll
    for (int t = 0; t < 8; ++t)
#pragma unroll
      for (int rr = 0; rr < 4; ++rr) {
        p[t][rr] = __expf(fmaf(p[t][rr], 0.125f, -12.0f));
        lsum[rr] += p[t][rr];
      }
    // PV in 32-key chunks (P via LDS round trip; per-wave region, DS ops in-order)
#pragma unroll
    for (int hb = 0; hb < 4; ++hb) {
      s16x8 vf[4];
#pragma unroll
      for (int nt = 0; nt < 4; ++nt)
        vf[nt] = *(const s16x8*)(vT_p + (size_t)(nt * 16 + lc) * KL + k0 + hb * 32 + quad * 8);
#pragma unroll
      for (int rr = 0; rr < 4; ++rr) {
        int row = quad * 4 + rr;
        pw[row * 36 + lc]      = f2bf(p[hb * 2][rr]);
        pw[row * 36 + 16 + lc] = f2bf(p[hb * 2 + 1][rr]);
      }
      asm volatile("s_waitcnt lgkmcnt(0)" ::: "memory");
      s16x8 pf = *(const s16x8*)(pw + lc * 36 + quad * 8);
#pragma unroll
      for (int nt = 0; nt < 4; ++nt) O[nt] = mfma16(pf, vf[nt], O[nt]);
    }
  }

  // per-wave row-sum of l across the 16 lc lanes (once, not per iteration)
#pragma unroll
  for (int msk = 1; msk <= 8; msk <<= 1)
#pragma unroll
    for (int rr = 0; rr < 4; ++rr) lsum[rr] += __shfl_xor(lsum[rr], msk);

  // ---- merge: plain sums over 8 waves ----
  __syncthreads();               // all waves done with bdS reads
#pragma unroll
  for (int nt = 0; nt < 4; ++nt)
#pragma unroll
    for (int rr = 0; rr < 4; ++rr)
      oS[(w * 16 + quad * 4 + rr) * 64 + nt * 16 + lc] = O[nt][rr];
  if (lc == 0) {
#pragma unroll
    for (int rr = 0; rr < 4; ++rr) lS[w * 16 + quad * 4 + rr] = lsum[rr];
  }
  __syncthreads();

  if (tid < 256) {
    int r = tid >> 4, c0 = (tid & 15) * 4;
    float L = 0.f, a0 = 0.f, a1 = 0.f, a2 = 0.f, a3 = 0.f;
#pragma unroll
    for (int wv = 0; wv < 8; ++wv) {
      L += lS[wv * 16 + r];
      const float* op = oS + (wv * 16 + r) * 64 + c0;
      a0 += op[0]; a1 += op[1]; a2 += op[2]; a3 += op[3];
    }
    float inv = 1.0f / L;
    float v[4] = {a0 * inv, a1 * inv, a2 * inv, a3 * inv};
    unsigned short hi[4], lo[4];
#pragma unroll
    for (int j = 0; j < 4; ++j) {
      hi[j] = f2bf(v[j]);
      lo[j] = f2bf(v[j] - bf2f(hi[j]));
    }
    size_t oidx = ((size_t)(b * QL + i0 + r)) * DM + h * DH + c0;
    *(ushort4*)&avhi[oidx] = make_ushort4(hi[0], hi[1], hi[2], hi[3]);
    *(ushort4*)&avlo[oidx] = make_ushort4(lo[0], lo[1], lo[2], lo[3]);
  }
}

// ---------------- final GEMM: out = av @ Wo, split bf16, 64x64 tiles (512 blocks) -----
__global__ __launch_bounds__(256) void gemm_final(
    const unsigned short* __restrict__ avhi, const unsigned short* __restrict__ avlo,
    const unsigned short* __restrict__ wohi, const unsigned short* __restrict__ wolo,
    float* __restrict__ out)
{
  __shared__ __align__(16) unsigned short As[64 * 32];
  __shared__ __align__(16) unsigned short Bs[64 * 32];
  int blk = blockIdx.x, tid = threadIdx.x;
  int mb = blk >> 4, nb = blk & 15;    // 32 x 16

  const int w = tid >> 6, lane = tid & 63;
  const int srow = w * 16 + (lane >> 2);
  const int scu = (lane & 3) * 8;
  const size_t arow = (size_t)(mb * 64 + srow) * 1024 + scu;
  const size_t brow = (size_t)(nb * 64 + srow) * 1024 + scu;
  char* lA = (char*)As + w * 1024;
  char* lB = (char*)Bs + w * 1024;

  const int lc = lane & 15, quad = lane >> 4;
  const int wm = (w & 1) * 32, wn = (w >> 1) * 32;

  f32x4 acc[2][2];
#pragma unroll
  for (int mt = 0; mt < 2; ++mt)
#pragma unroll
    for (int nt = 0; nt < 2; ++nt) { acc[mt][nt][0] = 0.f; acc[mt][nt][1] = 0.f; acc[mt][nt][2] = 0.f; acc[mt][nt][3] = 0.f; }

  for (int k0 = 0; k0 < 3072; k0 += 32) {
    int seg = k0 >> 10, kk = k0 & 1023;
    const unsigned short* Ab = ((seg < 2) ? avhi : avlo);
    const unsigned short* Bb = ((seg == 1) ? wolo : wohi);
    __syncthreads();
    gl2lds16(Ab + arow + kk, lA);
    gl2lds16(Bb + brow + kk, lB);
    __syncthreads();
    s16x8 af[2], bf[2];
#pragma unroll
    for (int mt = 0; mt < 2; ++mt) af[mt] = *(const s16x8*)&As[(wm + mt * 16 + lc) * 32 + quad * 8];
#pragma unroll
    for (int nt = 0; nt < 2; ++nt) bf[nt] = *(const s16x8*)&Bs[(wn + nt * 16 + lc) * 32 + quad * 8];
#pragma unroll
    for (int mt = 0; mt < 2; ++mt)
#pragma unroll
      for (int nt = 0; nt < 2; ++nt) acc[mt][nt] = mfma16(af[mt], bf[nt], acc[mt][nt]);
  }

#pragma unroll
  for (int mt = 0; mt < 2; ++mt)
#pragma unroll
    for (int nt = 0; nt < 2; ++nt) {
      int n = nb * 64 + wn + nt * 16 + lc;
#pragma unroll
      for (int rr = 0; rr < 4; ++rr) {
        int m = mb * 64 + wm + mt * 16 + quad * 4 + rr;
        out[(size_t)m * 1024 + n] = acc[mt][nt][rr];
      }
    }
}

extern "C" void kernel_launch(void* const* d_in, const int* in_sizes, int n_in,
                              void* d_out, int out_size, void* d_ws, size_t ws_size,
                              hipStream_t stream) {
  (void)in_sizes; (void)n_in; (void)out_size; (void)ws_size;
  const float* h   = (const float*)d_in[0];
  const float* mem = (const float*)d_in[1];
  const float* r   = (const float*)d_in[2];
  const float* Wq  = (const float*)d_in[3];
  const float* Wk  = (const float*)d_in[4];
  const float* Wv  = (const float*)d_in[5];
  const float* Wr  = (const float*)d_in[6];
  const float* Wo  = (const float*)d_in[7];
  const float* rwb = (const float*)d_in[8];
  const float* rrb = (const float*)d_in[9];
  float* out = (float*)d_out;

  char* ws = (char*)d_ws;
  unsigned short* catb = (unsigned short*)(ws + 0);          // 8 MB
  unsigned short* rb   = (unsigned short*)(ws + 8388608);    // 4 MB
  unsigned short* wqt  = (unsigned short*)(ws + 12582912);   // 2 MB
  unsigned short* wkvt = (unsigned short*)(ws + 14680064);   // 4 MB
  unsigned short* wrt  = (unsigned short*)(ws + 18874368);   // 2 MB
  unsigned short* wohi = (unsigned short*)(ws + 20971520);   // 2 MB
  unsigned short* wolo = (unsigned short*)(ws + 23068672);   // 2 MB
  unsigned short* qwb  = (unsigned short*)(ws + 25165824);   // 4 MB
  unsigned short* qrb  = (unsigned short*)(ws + 29360128);   // 4 MB
  unsigned short* kbuf = (unsigned short*)(ws + 33554432);   // 8 MB
  unsigned short* vTb  = (unsigned short*)(ws + 41943040);   // 8 MB
  unsigned short* rhb  = (unsigned short*)(ws + 50331648);   // 4 MB
  unsigned short* avhi = (unsigned short*)(ws + 54525952);   // 4 MB
  unsigned short* avlo = (unsigned short*)(ws + 58720256);   // 4 MB

  build_inputs<<<6144, 256, 0, stream>>>(h, mem, r, catb, rb);
  prep_weights<<<1280, 256, 0, stream>>>(Wq, Wk, Wv, Wr, Wo, wqt, wkvt, wrt, wohi, wolo);
  gemm_all<<<768, 256, 0, stream>>>(catb, rb, wqt, wkvt, wrt, rwb, rrb,
                                    qwb, qrb, kbuf, vTb, rhb);
  attn<<<2048, 512, 0, stream>>>(qwb, qrb, kbuf, vTb, rhb, avhi, avlo);
  gemm_final<<<512, 256, 0, stream>>>(avhi, avlo, wohi, wolo, out);
}

// Round 5
// 373.859 us; speedup vs baseline: 4.6566x; 1.0926x over previous
//
#include <hip/hip_runtime.h>

#define DM 1024
#define NH 16
#define DH 64
#define QL 1024
#define KL 2048

typedef short s16x8 __attribute__((ext_vector_type(8)));
typedef float f32x4 __attribute__((ext_vector_type(4)));

__device__ __forceinline__ unsigned short f2bf(float f) {
  unsigned int u = __builtin_bit_cast(unsigned int, f);
  u += 0x7fffu + ((u >> 16) & 1u);
  return (unsigned short)(u >> 16);
}
__device__ __forceinline__ float bf2f(unsigned short b) {
  unsigned int u = ((unsigned int)b) << 16;
  return __builtin_bit_cast(float, u);
}
__device__ __forceinline__ f32x4 mfma16(s16x8 a, s16x8 b, f32x4 c) {
  return __builtin_amdgcn_mfma_f32_16x16x32_bf16(a, b, c, 0, 0, 0);
}
// async global->LDS, 16B per lane; LDS dest = wave-uniform base + lane*16
__device__ __forceinline__ void gl2lds16(const void* g, void* l) {
  __builtin_amdgcn_global_load_lds(
      (const __attribute__((address_space(1))) unsigned int*)g,
      (__attribute__((address_space(3))) unsigned int*)l, 16, 0, 0);
}

// ---------------- input conversion: catb (B*2048 x 1024 bf16), rb (2048x1024 bf16) ----
__global__ __launch_bounds__(256) void build_inputs(
    const float* __restrict__ h, const float* __restrict__ mem, const float* __restrict__ r,
    unsigned short* __restrict__ catb, unsigned short* __restrict__ rb)
{
  int idx = blockIdx.x * 256 + threadIdx.x;           // 0 .. 1.5M-1
  if (idx < 1048576) {                                // catb: 4M u16, 4 per thread
    int e = idx * 4;
    int row = e >> 10, col = e & 1023;
    int b = row >> 11, t = row & 2047;
    const float* s = (t < 1024) ? &mem[((size_t)(b * 1024 + t)) * 1024 + col]
                                : &h[((size_t)(b * 1024 + t - 1024)) * 1024 + col];
    float4 v = *(const float4*)s;
    *(ushort4*)&catb[e] = make_ushort4(f2bf(v.x), f2bf(v.y), f2bf(v.z), f2bf(v.w));
  } else {
    int e = (idx - 1048576) * 4;                      // rb: 2M elements
    float4 v = *(const float4*)&r[e];
    *(ushort4*)&rb[e] = make_ushort4(f2bf(v.x), f2bf(v.y), f2bf(v.z), f2bf(v.w));
  }
}

// ---------------- fused weight prep: 5 jobs x 256 tile-blocks -------------------------
__global__ __launch_bounds__(256) void prep_weights(
    const float* __restrict__ Wq, const float* __restrict__ Wk, const float* __restrict__ Wv,
    const float* __restrict__ Wr, const float* __restrict__ Wo,
    unsigned short* __restrict__ wqt, unsigned short* __restrict__ wkvt,
    unsigned short* __restrict__ wrt,
    unsigned short* __restrict__ wohi, unsigned short* __restrict__ wolo)
{
  __shared__ unsigned short tH[64][72];
  __shared__ unsigned short tL[64][72];
  int job = blockIdx.x >> 8;
  int tb = blockIdx.x & 255;
  int sr0 = (tb >> 4) * 64, sc0 = (tb & 15) * 64;
  const float* src = (job == 0) ? Wq : (job == 1) ? Wk : (job == 2) ? Wv : (job == 3) ? Wr : Wo;
  int tid = threadIdx.x;
  int rr = tid >> 4, c4 = (tid & 15) * 4;
#pragma unroll
  for (int i = 0; i < 4; ++i) {
    int row = rr + i * 16;
    float4 v = *(const float4*)&src[(size_t)(sr0 + row) * 1024 + sc0 + c4];
    float vv[4] = {v.x, v.y, v.z, v.w};
#pragma unroll
    for (int j = 0; j < 4; ++j) {
      unsigned short hi = f2bf(vv[j]);
      tH[c4 + j][row] = hi;
      if (job == 4) tL[c4 + j][row] = f2bf(vv[j] - bf2f(hi));
    }
  }
  __syncthreads();
  unsigned short* dst = (job == 0) ? wqt : (job == 1) ? wkvt
                      : (job == 2) ? (wkvt + (size_t)1024 * 1024)
                      : (job == 3) ? wrt : wohi;
#pragma unroll
  for (int i = 0; i < 4; ++i) {
    int row = rr + i * 16;
    size_t o = (size_t)(sc0 + row) * 1024 + sr0 + c4;
    *(ushort4*)&dst[o] = make_ushort4(tH[row][c4], tH[row][c4 + 1], tH[row][c4 + 2], tH[row][c4 + 3]);
    if (job == 4)
      *(ushort4*)&wolo[o] = make_ushort4(tL[row][c4], tL[row][c4 + 1], tL[row][c4 + 2], tL[row][c4 + 3]);
  }
}

// ---------------- projection GEMMs (bf16 MFMA, 128x128 tile, BK=32, async staging) ----
__global__ __launch_bounds__(256) void gemm_all(
    const unsigned short* __restrict__ catb, const unsigned short* __restrict__ rb,
    const unsigned short* __restrict__ wqt, const unsigned short* __restrict__ wkvt,
    const unsigned short* __restrict__ wrt,
    const float* __restrict__ rwb, const float* __restrict__ rrb,
    unsigned short* __restrict__ qwb, unsigned short* __restrict__ qrb,
    unsigned short* __restrict__ kbuf, unsigned short* __restrict__ vT,
    unsigned short* __restrict__ rhb)
{
  __shared__ __align__(16) unsigned short As[128 * 32];
  __shared__ __align__(16) unsigned short Bs[128 * 32];
  int blk = blockIdx.x, tid = threadIdx.x;
  int job, mb, nb;
  const unsigned short *A, *Bt;
  if (blk < 128)      { job = 0; A = catb; Bt = wqt;  mb = blk >> 3; nb = blk & 7; }
  else if (blk < 640) { job = 1; A = catb; Bt = wkvt; int q = blk - 128; mb = q >> 4; nb = q & 15; }
  else                { job = 2; A = rb;   Bt = wrt;  int q = blk - 640; mb = q >> 3; nb = q & 7; }

  const int w = tid >> 6;
  const int r0 = tid >> 2;                 // chunk0 row (0..63)
  const int c0u = (tid & 3) * 8;           // u16 col offset within 32-wide slab
  int ga_r0 = mb * 128 + r0, ga_r1 = mb * 128 + 64 + r0;
  if (job == 0) {
    ga_r0 = ((ga_r0 >> 10) << 11) + 1024 + (ga_r0 & 1023);
    ga_r1 = ((ga_r1 >> 10) << 11) + 1024 + (ga_r1 & 1023);
  }
  const unsigned short* gA0 = A + (size_t)ga_r0 * 1024 + c0u;
  const unsigned short* gA1 = A + (size_t)ga_r1 * 1024 + c0u;
  const unsigned short* gB0 = Bt + (size_t)(nb * 128 + r0) * 1024 + c0u;
  const unsigned short* gB1 = Bt + (size_t)(nb * 128 + 64 + r0) * 1024 + c0u;
  char* lA0 = (char*)As + w * 1024;  char* lA1 = (char*)As + 4096 + w * 1024;
  char* lB0 = (char*)Bs + w * 1024;  char* lB1 = (char*)Bs + 4096 + w * 1024;

  const int lane = tid & 63;
  const int lc = lane & 15, quad = lane >> 4;
  const int wm = (w & 1) * 64, wn = (w >> 1) * 64;

  f32x4 acc[4][4];
#pragma unroll
  for (int mt = 0; mt < 4; ++mt)
#pragma unroll
    for (int nt = 0; nt < 4; ++nt) { acc[mt][nt][0] = 0.f; acc[mt][nt][1] = 0.f; acc[mt][nt][2] = 0.f; acc[mt][nt][3] = 0.f; }

  for (int k0 = 0; k0 < 1024; k0 += 32) {
    __syncthreads();
    gl2lds16(gA0 + k0, lA0);
    gl2lds16(gA1 + k0, lA1);
    gl2lds16(gB0 + k0, lB0);
    gl2lds16(gB1 + k0, lB1);
    __syncthreads();
    s16x8 af[4], bf[4];
#pragma unroll
    for (int mt = 0; mt < 4; ++mt) af[mt] = *(const s16x8*)&As[(wm + mt * 16 + lc) * 32 + quad * 8];
#pragma unroll
    for (int nt = 0; nt < 4; ++nt) bf[nt] = *(const s16x8*)&Bs[(wn + nt * 16 + lc) * 32 + quad * 8];
#pragma unroll
    for (int mt = 0; mt < 4; ++mt)
#pragma unroll
      for (int nt = 0; nt < 4; ++nt) acc[mt][nt] = mfma16(af[mt], bf[nt], acc[mt][nt]);
  }

#pragma unroll
  for (int mt = 0; mt < 4; ++mt) {
    int t4 = mb * 128 + wm + mt * 16 + quad * 4;
#pragma unroll
    for (int nt = 0; nt < 4; ++nt) {
      int n = nb * 128 + wn + nt * 16 + lc;
      if (job == 0) {
        int hh = n >> 6, dh = n & 63;
        float bw = rwb[n], br = rrb[n];
#pragma unroll
        for (int rr = 0; rr < 4; ++rr) {
          int m = t4 + rr; int bb = m >> 10, t = m & 1023;
          size_t idx = (((size_t)bb * NH + hh) * QL + t) * DH + dh;
          qwb[idx] = f2bf(acc[mt][nt][rr] + bw);
          qrb[idx] = f2bf(acc[mt][nt][rr] + br);
        }
      } else if (job == 1) {
        int bb = t4 >> 11, t = t4 & 2047;
        if (n < 1024) {
          int hh = n >> 6, dh = n & 63;
#pragma unroll
          for (int rr = 0; rr < 4; ++rr)
            kbuf[(((size_t)bb * NH + hh) * KL + t + rr) * DH + dh] = f2bf(acc[mt][nt][rr]);
        } else {
          int n2 = n - 1024, hh = n2 >> 6, dh = n2 & 63;
          ushort4 pk = make_ushort4(f2bf(acc[mt][nt][0]), f2bf(acc[mt][nt][1]),
                                    f2bf(acc[mt][nt][2]), f2bf(acc[mt][nt][3]));
          *(ushort4*)&vT[(((size_t)bb * NH + hh) * DH + dh) * KL + t] = pk;
        }
      } else {
        int hh = n >> 6, dh = n & 63;
#pragma unroll
        for (int rr = 0; rr < 4; ++rr)
          rhb[((size_t)hh * KL + t4 + rr) * DH + dh] = f2bf(acc[mt][nt][rr]);
      }
    }
  }
}

// ---------------- fused flash attention with rel-shift (bf16 MFMA) --------------------
// block: (b, h, 16 q-rows), 512 threads / 8 waves. Phase 0: raw BD strip in LDS via MFMA.
// Main: 8-way split-K (256 keys/wave), 32-key chunks with tight register liveness
// (r4 spilled: p[8][4]+kf[4][2] exceeded the 128-reg cap -> 143 MB scratch writes).
// Fixed-shift softmax; merge = plain sum of per-wave (O, l).
#define BDSTR 2058
__global__ __launch_bounds__(512, 4) void attn(
    const unsigned short* __restrict__ qwb, const unsigned short* __restrict__ qrb,
    const unsigned short* __restrict__ kbuf, const unsigned short* __restrict__ vT,
    const unsigned short* __restrict__ rhb,
    unsigned short* __restrict__ avhi, unsigned short* __restrict__ avlo)
{
  __shared__ __align__(16) unsigned short bdS[17 * BDSTR];   // 69972 B
  __shared__ __align__(16) unsigned short pS[8 * 16 * 36];   // 9216 B
  float* oS = (float*)bdS;             // merge overlay: [8][16][64] f32
  float* lS = (float*)bdS + 8192;      // [8][16] f32

  const int tid = threadIdx.x;
  const int w = tid >> 6, lane = tid & 63;
  const int lc = lane & 15, quad = lane >> 4;
  const int is = blockIdx.x & 63, h = (blockIdx.x >> 6) & 15, b = blockIdx.x >> 10;
  const int i0 = is * 16;
  const size_t bh = (size_t)b * NH + h;

  const unsigned short* qw_p = qwb + bh * QL * DH;
  const unsigned short* qr_p = qrb + bh * QL * DH;
  const unsigned short* kb_p = kbuf + bh * KL * DH;
  const unsigned short* vT_p = vT + bh * DH * KL;
  const unsigned short* rh_p = rhb + (size_t)h * KL * DH;

  // ---- phase 0: raw BD strip rows i0..i0+16 (17), wave w covers cols [w*256,w*256+256) ----
  {
    int r0 = i0 + lc;
    int r1 = i0 + 16 + lc; if (r1 > 1023) r1 = 1023;   // clamp; clamped rows unused
    s16x8 qa00 = *(const s16x8*)(qr_p + (size_t)r0 * DH + quad * 8);
    s16x8 qa01 = *(const s16x8*)(qr_p + (size_t)r0 * DH + 32 + quad * 8);
    s16x8 qa10 = *(const s16x8*)(qr_p + (size_t)r1 * DH + quad * 8);
    s16x8 qa11 = *(const s16x8*)(qr_p + (size_t)r1 * DH + 32 + quad * 8);
    const int xt0 = w * 16;
    const unsigned short* rp = rh_p + (size_t)(xt0 * 16 + lc) * DH + quad * 8;
    s16x8 rf0 = *(const s16x8*)rp;
    s16x8 rf1 = *(const s16x8*)(rp + 32);
    for (int xt = xt0; xt < xt0 + 16; ++xt) {
      s16x8 cf0 = rf0, cf1 = rf1;
      if (xt + 1 < xt0 + 16) {
        const unsigned short* rpn = rh_p + (size_t)((xt + 1) * 16 + lc) * DH + quad * 8;
        rf0 = *(const s16x8*)rpn;
        rf1 = *(const s16x8*)(rpn + 32);
      }
      f32x4 c0; c0[0] = 0.f; c0[1] = 0.f; c0[2] = 0.f; c0[3] = 0.f;
      f32x4 c1 = c0;
      c0 = mfma16(qa00, cf0, c0); c0 = mfma16(qa01, cf1, c0);
      c1 = mfma16(qa10, cf0, c1); c1 = mfma16(qa11, cf1, c1);
      int col = xt * 16 + lc;
#pragma unroll
      for (int rr = 0; rr < 4; ++rr) bdS[(quad * 4 + rr) * BDSTR + col] = f2bf(c0[rr]);
      if (lane < 16) bdS[16 * BDSTR + col] = f2bf(c1[0]);
    }
  }
  __syncthreads();

  // ---- main split-K loop: wave w handles k in [w*256, w*256+256), 8 x 32-key chunks ----
  s16x8 qwf0 = *(const s16x8*)(qw_p + (size_t)(i0 + lc) * DH + quad * 8);
  s16x8 qwf1 = *(const s16x8*)(qw_p + (size_t)(i0 + lc) * DH + 32 + quad * 8);

  f32x4 O[4];
#pragma unroll
  for (int nt = 0; nt < 4; ++nt) { O[nt][0] = 0.f; O[nt][1] = 0.f; O[nt][2] = 0.f; O[nt][3] = 0.f; }
  float lsum[4] = {0.f, 0.f, 0.f, 0.f};
  unsigned short* pw = pS + w * 16 * 36;
  int ebase[4];
#pragma unroll
  for (int rr = 0; rr < 4; ++rr) ebase[rr] = lc - (quad * 4 + rr) - i0;

#pragma unroll 1
  for (int it = 0; it < 8; ++it) {
    const int k0 = w * 256 + it * 32;
    // prefetch V fragments for this chunk (independent of the QK->p chain; issues early)
    s16x8 vf[4];
#pragma unroll
    for (int nt = 0; nt < 4; ++nt)
      vf[nt] = *(const s16x8*)(vT_p + (size_t)(nt * 16 + lc) * KL + k0 + quad * 8);
    // QK^T + bd gather + exp, one 16-key tile at a time (kf transient)
    float p[2][4];
#pragma unroll
    for (int tt = 0; tt < 2; ++tt) {
      const unsigned short* kp = kb_p + (size_t)(k0 + tt * 16 + lc) * DH + quad * 8;
      s16x8 kf0 = *(const s16x8*)kp;
      s16x8 kf1 = *(const s16x8*)(kp + 32);
      f32x4 c; c[0] = 0.f; c[1] = 0.f; c[2] = 0.f; c[3] = 0.f;
      c = mfma16(qwf0, kf0, c);
      c = mfma16(qwf1, kf1, c);
#pragma unroll
      for (int rr = 0; rr < 4; ++rr) {
        int row = quad * 4 + rr;
        int d = k0 + tt * 16 + ebase[rr];
        int am = row * BDSTR + (d + 1023);
        int aw = (row + 1) * BDSTR + (d - 1026);
        unsigned short vb = bdS[(d <= 1024) ? am : aw];
        float bd = (d == 1025) ? 0.0f : bf2f(vb);
        p[tt][rr] = __expf(fmaf(c[rr] + bd, 0.125f, -12.0f));
        lsum[rr] += p[tt][rr];
      }
    }
    // P -> LDS round trip (C-layout -> A-layout); same-wave DS ops are in-order
#pragma unroll
    for (int rr = 0; rr < 4; ++rr) {
      int row = quad * 4 + rr;
      pw[row * 36 + lc]      = f2bf(p[0][rr]);
      pw[row * 36 + 16 + lc] = f2bf(p[1][rr]);
    }
    asm volatile("s_waitcnt lgkmcnt(0)" ::: "memory");
    s16x8 pf = *(const s16x8*)(pw + lc * 36 + quad * 8);
#pragma unroll
    for (int nt = 0; nt < 4; ++nt) O[nt] = mfma16(pf, vf[nt], O[nt]);
  }

  // per-wave row-sum of l across the 16 lc lanes (once, not per iteration)
#pragma unroll
  for (int msk = 1; msk <= 8; msk <<= 1)
#pragma unroll
    for (int rr = 0; rr < 4; ++rr) lsum[rr] += __shfl_xor(lsum[rr], msk);

  // ---- merge: plain sums over 8 waves ----
  __syncthreads();               // all waves done with bdS reads
#pragma unroll
  for (int nt = 0; nt < 4; ++nt)
#pragma unroll
    for (int rr = 0; rr < 4; ++rr)
      oS[(w * 16 + quad * 4 + rr) * 64 + nt * 16 + lc] = O[nt][rr];
  if (lc == 0) {
#pragma unroll
    for (int rr = 0; rr < 4; ++rr) lS[w * 16 + quad * 4 + rr] = lsum[rr];
  }
  __syncthreads();

  if (tid < 256) {
    int r = tid >> 4, c0 = (tid & 15) * 4;
    float L = 0.f, a0 = 0.f, a1 = 0.f, a2 = 0.f, a3 = 0.f;
#pragma unroll
    for (int wv = 0; wv < 8; ++wv) {
      L += lS[wv * 16 + r];
      const float* op = oS + (wv * 16 + r) * 64 + c0;
      a0 += op[0]; a1 += op[1]; a2 += op[2]; a3 += op[3];
    }
    float inv = 1.0f / L;
    float v[4] = {a0 * inv, a1 * inv, a2 * inv, a3 * inv};
    unsigned short hi[4], lo[4];
#pragma unroll
    for (int j = 0; j < 4; ++j) {
      hi[j] = f2bf(v[j]);
      lo[j] = f2bf(v[j] - bf2f(hi[j]));
    }
    size_t oidx = ((size_t)(b * QL + i0 + r)) * DM + h * DH + c0;
    *(ushort4*)&avhi[oidx] = make_ushort4(hi[0], hi[1], hi[2], hi[3]);
    *(ushort4*)&avlo[oidx] = make_ushort4(lo[0], lo[1], lo[2], lo[3]);
  }
}

// ---------------- final GEMM: out = av @ Wo, split bf16, 64x64 tiles (512 blocks) -----
__global__ __launch_bounds__(256) void gemm_final(
    const unsigned short* __restrict__ avhi, const unsigned short* __restrict__ avlo,
    const unsigned short* __restrict__ wohi, const unsigned short* __restrict__ wolo,
    float* __restrict__ out)
{
  __shared__ __align__(16) unsigned short As[64 * 32];
  __shared__ __align__(16) unsigned short Bs[64 * 32];
  int blk = blockIdx.x, tid = threadIdx.x;
  int mb = blk >> 4, nb = blk & 15;    // 32 x 16

  const int w = tid >> 6, lane = tid & 63;
  const int srow = w * 16 + (lane >> 2);
  const int scu = (lane & 3) * 8;
  const size_t arow = (size_t)(mb * 64 + srow) * 1024 + scu;
  const size_t brow = (size_t)(nb * 64 + srow) * 1024 + scu;
  char* lA = (char*)As + w * 1024;
  char* lB = (char*)Bs + w * 1024;

  const int lc = lane & 15, quad = lane >> 4;
  const int wm = (w & 1) * 32, wn = (w >> 1) * 32;

  f32x4 acc[2][2];
#pragma unroll
  for (int mt = 0; mt < 2; ++mt)
#pragma unroll
    for (int nt = 0; nt < 2; ++nt) { acc[mt][nt][0] = 0.f; acc[mt][nt][1] = 0.f; acc[mt][nt][2] = 0.f; acc[mt][nt][3] = 0.f; }

  for (int k0 = 0; k0 < 3072; k0 += 32) {
    int seg = k0 >> 10, kk = k0 & 1023;
    const unsigned short* Ab = ((seg < 2) ? avhi : avlo);
    const unsigned short* Bb = ((seg == 1) ? wolo : wohi);
    __syncthreads();
    gl2lds16(Ab + arow + kk, lA);
    gl2lds16(Bb + brow + kk, lB);
    __syncthreads();
    s16x8 af[2], bf[2];
#pragma unroll
    for (int mt = 0; mt < 2; ++mt) af[mt] = *(const s16x8*)&As[(wm + mt * 16 + lc) * 32 + quad * 8];
#pragma unroll
    for (int nt = 0; nt < 2; ++nt) bf[nt] = *(const s16x8*)&Bs[(wn + nt * 16 + lc) * 32 + quad * 8];
#pragma unroll
    for (int mt = 0; mt < 2; ++mt)
#pragma unroll
      for (int nt = 0; nt < 2; ++nt) acc[mt][nt] = mfma16(af[mt], bf[nt], acc[mt][nt]);
  }

#pragma unroll
  for (int mt = 0; mt < 2; ++mt)
#pragma unroll
    for (int nt = 0; nt < 2; ++nt) {
      int n = nb * 64 + wn + nt * 16 + lc;
#pragma unroll
      for (int rr = 0; rr < 4; ++rr) {
        int m = mb * 64 + wm + mt * 16 + quad * 4 + rr;
        out[(size_t)m * 1024 + n] = acc[mt][nt][rr];
      }
    }
}

extern "C" void kernel_launch(void* const* d_in, const int* in_sizes, int n_in,
                              void* d_out, int out_size, void* d_ws, size_t ws_size,
                              hipStream_t stream) {
  (void)in_sizes; (void)n_in; (void)out_size; (void)ws_size;
  const float* h   = (const float*)d_in[0];
  const float* mem = (const float*)d_in[1];
  const float* r   = (const float*)d_in[2];
  const float* Wq  = (const float*)d_in[3];
  const float* Wk  = (const float*)d_in[4];
  const float* Wv  = (const float*)d_in[5];
  const float* Wr  = (const float*)d_in[6];
  const float* Wo  = (const float*)d_in[7];
  const float* rwb = (const float*)d_in[8];
  const float* rrb = (const float*)d_in[9];
  float* out = (float*)d_out;

  char* ws = (char*)d_ws;
  unsigned short* catb = (unsigned short*)(ws + 0);          // 8 MB
  unsigned short* rb   = (unsigned short*)(ws + 8388608);    // 4 MB
  unsigned short* wqt  = (unsigned short*)(ws + 12582912);   // 2 MB
  unsigned short* wkvt = (unsigned short*)(ws + 14680064);   // 4 MB
  unsigned short* wrt  = (unsigned short*)(ws + 18874368);   // 2 MB
  unsigned short* wohi = (unsigned short*)(ws + 20971520);   // 2 MB
  unsigned short* wolo = (unsigned short*)(ws + 23068672);   // 2 MB
  unsigned short* qwb  = (unsigned short*)(ws + 25165824);   // 4 MB
  unsigned short* qrb  = (unsigned short*)(ws + 29360128);   // 4 MB
  unsigned short* kbuf = (unsigned short*)(ws + 33554432);   // 8 MB
  unsigned short* vTb  = (unsigned short*)(ws + 41943040);   // 8 MB
  unsigned short* rhb  = (unsigned short*)(ws + 50331648);   // 4 MB
  unsigned short* avhi = (unsigned short*)(ws + 54525952);   // 4 MB
  unsigned short* avlo = (unsigned short*)(ws + 58720256);   // 4 MB

  build_inputs<<<6144, 256, 0, stream>>>(h, mem, r, catb, rb);
  prep_weights<<<1280, 256, 0, stream>>>(Wq, Wk, Wv, Wr, Wo, wqt, wkvt, wrt, wohi, wolo);
  gemm_all<<<768, 256, 0, stream>>>(catb, rb, wqt, wkvt, wrt, rwb, rrb,
                                    qwb, qrb, kbuf, vTb, rhb);
  attn<<<2048, 512, 0, stream>>>(qwb, qrb, kbuf, vTb, rhb, avhi, avlo);
  gemm_final<<<512, 256, 0, stream>>>(avhi, avlo, wohi, wolo, out);
}

// Round 6
// 372.655 us; speedup vs baseline: 4.6716x; 1.0032x over previous
//
#include <hip/hip_runtime.h>

#define DM 1024
#define NH 16
#define DH 64
#define QL 1024
#define KL 2048

typedef short s16x8 __attribute__((ext_vector_type(8)));
typedef float f32x4 __attribute__((ext_vector_type(4)));

__device__ __forceinline__ unsigned short f2bf(float f) {
  unsigned int u = __builtin_bit_cast(unsigned int, f);
  u += 0x7fffu + ((u >> 16) & 1u);
  return (unsigned short)(u >> 16);
}
__device__ __forceinline__ float bf2f(unsigned short b) {
  unsigned int u = ((unsigned int)b) << 16;
  return __builtin_bit_cast(float, u);
}
__device__ __forceinline__ f32x4 mfma16(s16x8 a, s16x8 b, f32x4 c) {
  return __builtin_amdgcn_mfma_f32_16x16x32_bf16(a, b, c, 0, 0, 0);
}
// async global->LDS, 16B per lane; LDS dest = wave-uniform base + lane*16
__device__ __forceinline__ void gl2lds16(const void* g, void* l) {
  __builtin_amdgcn_global_load_lds(
      (const __attribute__((address_space(1))) unsigned int*)g,
      (__attribute__((address_space(3))) unsigned int*)l, 16, 0, 0);
}

// ---------------- fused prep: blocks 0..6143 input conversion, 6144..7423 weights ------
__global__ __launch_bounds__(256) void prep_all(
    const float* __restrict__ h, const float* __restrict__ mem, const float* __restrict__ r,
    const float* __restrict__ Wq, const float* __restrict__ Wk, const float* __restrict__ Wv,
    const float* __restrict__ Wr, const float* __restrict__ Wo,
    unsigned short* __restrict__ catb, unsigned short* __restrict__ rb,
    unsigned short* __restrict__ wqt, unsigned short* __restrict__ wkvt,
    unsigned short* __restrict__ wrt,
    unsigned short* __restrict__ wohi, unsigned short* __restrict__ wolo)
{
  __shared__ unsigned short tH[64][72];
  __shared__ unsigned short tL[64][72];
  if (blockIdx.x < 6144) {
    int idx = blockIdx.x * 256 + threadIdx.x;           // 0 .. 1.5M-1
    if (idx < 1048576) {                                // catb: 4M u16, 4 per thread
      int e = idx * 4;
      int row = e >> 10, col = e & 1023;
      int b = row >> 11, t = row & 2047;
      const float* s = (t < 1024) ? &mem[((size_t)(b * 1024 + t)) * 1024 + col]
                                  : &h[((size_t)(b * 1024 + t - 1024)) * 1024 + col];
      float4 v = *(const float4*)s;
      *(ushort4*)&catb[e] = make_ushort4(f2bf(v.x), f2bf(v.y), f2bf(v.z), f2bf(v.w));
    } else {
      int e = (idx - 1048576) * 4;                      // rb: 2M elements
      float4 v = *(const float4*)&r[e];
      *(ushort4*)&rb[e] = make_ushort4(f2bf(v.x), f2bf(v.y), f2bf(v.z), f2bf(v.w));
    }
    return;
  }
  int q = blockIdx.x - 6144;
  int job = q >> 8;
  int tb = q & 255;
  int sr0 = (tb >> 4) * 64, sc0 = (tb & 15) * 64;
  const float* src = (job == 0) ? Wq : (job == 1) ? Wk : (job == 2) ? Wv : (job == 3) ? Wr : Wo;
  int tid = threadIdx.x;
  int rr = tid >> 4, c4 = (tid & 15) * 4;
#pragma unroll
  for (int i = 0; i < 4; ++i) {
    int row = rr + i * 16;
    float4 v = *(const float4*)&src[(size_t)(sr0 + row) * 1024 + sc0 + c4];
    float vv[4] = {v.x, v.y, v.z, v.w};
#pragma unroll
    for (int j = 0; j < 4; ++j) {
      unsigned short hi = f2bf(vv[j]);
      tH[c4 + j][row] = hi;
      if (job == 4) tL[c4 + j][row] = f2bf(vv[j] - bf2f(hi));
    }
  }
  __syncthreads();
  unsigned short* dst = (job == 0) ? wqt : (job == 1) ? wkvt
                      : (job == 2) ? (wkvt + (size_t)1024 * 1024)
                      : (job == 3) ? wrt : wohi;
#pragma unroll
  for (int i = 0; i < 4; ++i) {
    int row = rr + i * 16;
    size_t o = (size_t)(sc0 + row) * 1024 + sr0 + c4;
    *(ushort4*)&dst[o] = make_ushort4(tH[row][c4], tH[row][c4 + 1], tH[row][c4 + 2], tH[row][c4 + 3]);
    if (job == 4)
      *(ushort4*)&wolo[o] = make_ushort4(tL[row][c4], tL[row][c4 + 1], tL[row][c4 + 2], tL[row][c4 + 3]);
  }
}

// ---------------- projection GEMMs (bf16 MFMA, 128x128 tile, BK=32, async staging) ----
__global__ __launch_bounds__(256) void gemm_all(
    const unsigned short* __restrict__ catb, const unsigned short* __restrict__ rb,
    const unsigned short* __restrict__ wqt, const unsigned short* __restrict__ wkvt,
    const unsigned short* __restrict__ wrt,
    const float* __restrict__ rwb, const float* __restrict__ rrb,
    unsigned short* __restrict__ qwb, unsigned short* __restrict__ qrb,
    unsigned short* __restrict__ kbuf, unsigned short* __restrict__ vT,
    unsigned short* __restrict__ rhb)
{
  __shared__ __align__(16) unsigned short As[128 * 32];
  __shared__ __align__(16) unsigned short Bs[128 * 32];
  int blk = blockIdx.x, tid = threadIdx.x;
  int job, mb, nb;
  const unsigned short *A, *Bt;
  if (blk < 128)      { job = 0; A = catb; Bt = wqt;  mb = blk >> 3; nb = blk & 7; }
  else if (blk < 640) { job = 1; A = catb; Bt = wkvt; int q = blk - 128; mb = q >> 4; nb = q & 15; }
  else                { job = 2; A = rb;   Bt = wrt;  int q = blk - 640; mb = q >> 3; nb = q & 7; }

  const int w = tid >> 6;
  const int r0 = tid >> 2;                 // chunk0 row (0..63)
  const int c0u = (tid & 3) * 8;           // u16 col offset within 32-wide slab
  int ga_r0 = mb * 128 + r0, ga_r1 = mb * 128 + 64 + r0;
  if (job == 0) {
    ga_r0 = ((ga_r0 >> 10) << 11) + 1024 + (ga_r0 & 1023);
    ga_r1 = ((ga_r1 >> 10) << 11) + 1024 + (ga_r1 & 1023);
  }
  const unsigned short* gA0 = A + (size_t)ga_r0 * 1024 + c0u;
  const unsigned short* gA1 = A + (size_t)ga_r1 * 1024 + c0u;
  const unsigned short* gB0 = Bt + (size_t)(nb * 128 + r0) * 1024 + c0u;
  const unsigned short* gB1 = Bt + (size_t)(nb * 128 + 64 + r0) * 1024 + c0u;
  char* lA0 = (char*)As + w * 1024;  char* lA1 = (char*)As + 4096 + w * 1024;
  char* lB0 = (char*)Bs + w * 1024;  char* lB1 = (char*)Bs + 4096 + w * 1024;

  const int lane = tid & 63;
  const int lc = lane & 15, quad = lane >> 4;
  const int wm = (w & 1) * 64, wn = (w >> 1) * 64;

  f32x4 acc[4][4];
#pragma unroll
  for (int mt = 0; mt < 4; ++mt)
#pragma unroll
    for (int nt = 0; nt < 4; ++nt) { acc[mt][nt][0] = 0.f; acc[mt][nt][1] = 0.f; acc[mt][nt][2] = 0.f; acc[mt][nt][3] = 0.f; }

  for (int k0 = 0; k0 < 1024; k0 += 32) {
    __syncthreads();
    gl2lds16(gA0 + k0, lA0);
    gl2lds16(gA1 + k0, lA1);
    gl2lds16(gB0 + k0, lB0);
    gl2lds16(gB1 + k0, lB1);
    __syncthreads();
    s16x8 af[4], bf[4];
#pragma unroll
    for (int mt = 0; mt < 4; ++mt) af[mt] = *(const s16x8*)&As[(wm + mt * 16 + lc) * 32 + quad * 8];
#pragma unroll
    for (int nt = 0; nt < 4; ++nt) bf[nt] = *(const s16x8*)&Bs[(wn + nt * 16 + lc) * 32 + quad * 8];
#pragma unroll
    for (int mt = 0; mt < 4; ++mt)
#pragma unroll
      for (int nt = 0; nt < 4; ++nt) acc[mt][nt] = mfma16(af[mt], bf[nt], acc[mt][nt]);
  }

#pragma unroll
  for (int mt = 0; mt < 4; ++mt) {
    int t4 = mb * 128 + wm + mt * 16 + quad * 4;
#pragma unroll
    for (int nt = 0; nt < 4; ++nt) {
      int n = nb * 128 + wn + nt * 16 + lc;
      if (job == 0) {
        int hh = n >> 6, dh = n & 63;
        float bw = rwb[n], br = rrb[n];
#pragma unroll
        for (int rr = 0; rr < 4; ++rr) {
          int m = t4 + rr; int bb = m >> 10, t = m & 1023;
          size_t idx = (((size_t)bb * NH + hh) * QL + t) * DH + dh;
          qwb[idx] = f2bf(acc[mt][nt][rr] + bw);
          qrb[idx] = f2bf(acc[mt][nt][rr] + br);
        }
      } else if (job == 1) {
        int bb = t4 >> 11, t = t4 & 2047;
        if (n < 1024) {
          int hh = n >> 6, dh = n & 63;
#pragma unroll
          for (int rr = 0; rr < 4; ++rr)
            kbuf[(((size_t)bb * NH + hh) * KL + t + rr) * DH + dh] = f2bf(acc[mt][nt][rr]);
        } else {
          int n2 = n - 1024, hh = n2 >> 6, dh = n2 & 63;
          ushort4 pk = make_ushort4(f2bf(acc[mt][nt][0]), f2bf(acc[mt][nt][1]),
                                    f2bf(acc[mt][nt][2]), f2bf(acc[mt][nt][3]));
          *(ushort4*)&vT[(((size_t)bb * NH + hh) * DH + dh) * KL + t] = pk;
        }
      } else {
        int hh = n >> 6, dh = n & 63;
#pragma unroll
        for (int rr = 0; rr < 4; ++rr)
          rhb[((size_t)hh * KL + t4 + rr) * DH + dh] = f2bf(acc[mt][nt][rr]);
      }
    }
  }
}

// ---------------- fused flash attention with rel-shift (bf16 MFMA) --------------------
// block: (b, h, 16 q-rows), 512 threads / 8 waves. Phase 0: raw BD strip in LDS via MFMA.
// Main: 8-way split-K (256 keys/wave), 32-key chunks, PV pipelined one chunk behind the
// score phase so the P LDS round-trip and the V global load both get a full iteration
// of latency cover. Single P buffer (read-old-then-write-new, same-wave ordering).
// Fixed-shift softmax; merge = plain sum of per-wave (O, l).
#define BDSTR 2058
__global__ __launch_bounds__(512, 4) void attn(
    const unsigned short* __restrict__ qwb, const unsigned short* __restrict__ qrb,
    const unsigned short* __restrict__ kbuf, const unsigned short* __restrict__ vT,
    const unsigned short* __restrict__ rhb,
    unsigned short* __restrict__ avhi, unsigned short* __restrict__ avlo)
{
  __shared__ __align__(16) unsigned short bdS[17 * BDSTR];   // 69972 B
  __shared__ __align__(16) unsigned short pS[8 * 16 * 36];   // 9216 B
  float* oS = (float*)bdS;             // merge overlay: [8][16][64] f32
  float* lS = (float*)bdS + 8192;      // [8][16] f32

  const int tid = threadIdx.x;
  const int w = tid >> 6, lane = tid & 63;
  const int lc = lane & 15, quad = lane >> 4;
  const int is = blockIdx.x & 63, h = (blockIdx.x >> 6) & 15, b = blockIdx.x >> 10;
  const int i0 = is * 16;
  const size_t bh = (size_t)b * NH + h;

  const unsigned short* qw_p = qwb + bh * QL * DH;
  const unsigned short* qr_p = qrb + bh * QL * DH;
  const unsigned short* kb_p = kbuf + bh * KL * DH;
  const unsigned short* vT_p = vT + bh * DH * KL;
  const unsigned short* rh_p = rhb + (size_t)h * KL * DH;

  // ---- phase 0: raw BD strip rows i0..i0+16 (17), wave w covers cols [w*256,w*256+256) ----
  {
    int r0 = i0 + lc;
    int r1 = i0 + 16 + lc; if (r1 > 1023) r1 = 1023;   // clamp; clamped rows unused
    s16x8 qa00 = *(const s16x8*)(qr_p + (size_t)r0 * DH + quad * 8);
    s16x8 qa01 = *(const s16x8*)(qr_p + (size_t)r0 * DH + 32 + quad * 8);
    s16x8 qa10 = *(const s16x8*)(qr_p + (size_t)r1 * DH + quad * 8);
    s16x8 qa11 = *(const s16x8*)(qr_p + (size_t)r1 * DH + 32 + quad * 8);
    const int xt0 = w * 16;
    const unsigned short* rp = rh_p + (size_t)(xt0 * 16 + lc) * DH + quad * 8;
    s16x8 rf0 = *(const s16x8*)rp;
    s16x8 rf1 = *(const s16x8*)(rp + 32);
    for (int xt = xt0; xt < xt0 + 16; ++xt) {
      s16x8 cf0 = rf0, cf1 = rf1;
      if (xt + 1 < xt0 + 16) {
        const unsigned short* rpn = rh_p + (size_t)((xt + 1) * 16 + lc) * DH + quad * 8;
        rf0 = *(const s16x8*)rpn;
        rf1 = *(const s16x8*)(rpn + 32);
      }
      f32x4 c0; c0[0] = 0.f; c0[1] = 0.f; c0[2] = 0.f; c0[3] = 0.f;
      f32x4 c1 = c0;
      c0 = mfma16(qa00, cf0, c0); c0 = mfma16(qa01, cf1, c0);
      c1 = mfma16(qa10, cf0, c1); c1 = mfma16(qa11, cf1, c1);
      int col = xt * 16 + lc;
#pragma unroll
      for (int rr = 0; rr < 4; ++rr) bdS[(quad * 4 + rr) * BDSTR + col] = f2bf(c0[rr]);
      if (lane < 16) bdS[16 * BDSTR + col] = f2bf(c1[0]);
    }
  }
  __syncthreads();

  // ---- main split-K loop: wave w handles k in [w*256, w*256+256), 8 x 32-key chunks ----
  s16x8 qwf0 = *(const s16x8*)(qw_p + (size_t)(i0 + lc) * DH + quad * 8);
  s16x8 qwf1 = *(const s16x8*)(qw_p + (size_t)(i0 + lc) * DH + 32 + quad * 8);

  f32x4 O[4];
#pragma unroll
  for (int nt = 0; nt < 4; ++nt) { O[nt][0] = 0.f; O[nt][1] = 0.f; O[nt][2] = 0.f; O[nt][3] = 0.f; }
  float lsum[4] = {0.f, 0.f, 0.f, 0.f};
  unsigned short* pw = pS + w * 16 * 36;
  int ebase[4];
#pragma unroll
  for (int rr = 0; rr < 4; ++rr) ebase[rr] = lc - (quad * 4 + rr) - i0;

  // score phase for one 32-key chunk: bd gathers (issued first), QK MFMA, exp -> p
  auto score = [&](int k0, float p[2][4]) {
    float bd[2][4];
#pragma unroll
    for (int tt = 0; tt < 2; ++tt)
#pragma unroll
      for (int rr = 0; rr < 4; ++rr) {
        int row = quad * 4 + rr;
        int d = k0 + tt * 16 + ebase[rr];
        int am = row * BDSTR + (d + 1023);
        int aw = (row + 1) * BDSTR + (d - 1026);
        unsigned short vb = bdS[(d <= 1024) ? am : aw];
        bd[tt][rr] = (d == 1025) ? 0.0f : bf2f(vb);
      }
#pragma unroll
    for (int tt = 0; tt < 2; ++tt) {
      const unsigned short* kp = kb_p + (size_t)(k0 + tt * 16 + lc) * DH + quad * 8;
      s16x8 kf0 = *(const s16x8*)kp;
      s16x8 kf1 = *(const s16x8*)(kp + 32);
      f32x4 c; c[0] = 0.f; c[1] = 0.f; c[2] = 0.f; c[3] = 0.f;
      c = mfma16(qwf0, kf0, c);
      c = mfma16(qwf1, kf1, c);
#pragma unroll
      for (int rr = 0; rr < 4; ++rr) {
        p[tt][rr] = __expf(fmaf(c[rr] + bd[tt][rr], 0.125f, -12.0f));
        lsum[rr] += p[tt][rr];
      }
    }
  };
  auto storeP = [&](float p[2][4]) {
#pragma unroll
    for (int rr = 0; rr < 4; ++rr) {
      int row = quad * 4 + rr;
      pw[row * 36 + lc]      = f2bf(p[0][rr]);
      pw[row * 36 + 16 + lc] = f2bf(p[1][rr]);
    }
  };
  auto loadV = [&](int k0, s16x8 vf[4]) {
#pragma unroll
    for (int nt = 0; nt < 4; ++nt)
      vf[nt] = *(const s16x8*)(vT_p + (size_t)(nt * 16 + lc) * KL + k0 + quad * 8);
  };

  s16x8 vfPrev[4];
  {
    float p[2][4];
    score(w * 256, p);
    storeP(p);
    loadV(w * 256, vfPrev);
  }
#pragma unroll 1
  for (int it = 1; it < 8; ++it) {
    const int k0 = w * 256 + it * 32;
    float p[2][4];
    score(k0, p);                       // gathers + QK + exp for chunk it
    __builtin_amdgcn_s_waitcnt(0xC07F); // lgkmcnt(0): P(it-1) writes landed long ago
    s16x8 pf = *(const s16x8*)(pw + lc * 36 + quad * 8);
#pragma unroll
    for (int nt = 0; nt < 4; ++nt) O[nt] = mfma16(pf, vfPrev[nt], O[nt]);  // PV chunk it-1
    loadV(k0, vfPrev);                  // V(it), consumed next iteration
    storeP(p);                          // safe: pf read completed before MFMA consumed it
  }
  {
    __builtin_amdgcn_s_waitcnt(0xC07F);
    s16x8 pf = *(const s16x8*)(pw + lc * 36 + quad * 8);
#pragma unroll
    for (int nt = 0; nt < 4; ++nt) O[nt] = mfma16(pf, vfPrev[nt], O[nt]);  // PV chunk 7
  }

  // per-wave row-sum of l across the 16 lc lanes (once, not per iteration)
#pragma unroll
  for (int msk = 1; msk <= 8; msk <<= 1)
#pragma unroll
    for (int rr = 0; rr < 4; ++rr) lsum[rr] += __shfl_xor(lsum[rr], msk);

  // ---- merge: plain sums over 8 waves ----
  __syncthreads();               // all waves done with bdS reads
#pragma unroll
  for (int nt = 0; nt < 4; ++nt)
#pragma unroll
    for (int rr = 0; rr < 4; ++rr)
      oS[(w * 16 + quad * 4 + rr) * 64 + nt * 16 + lc] = O[nt][rr];
  if (lc == 0) {
#pragma unroll
    for (int rr = 0; rr < 4; ++rr) lS[w * 16 + quad * 4 + rr] = lsum[rr];
  }
  __syncthreads();

  if (tid < 256) {
    int r = tid >> 4, c0 = (tid & 15) * 4;
    float L = 0.f, a0 = 0.f, a1 = 0.f, a2 = 0.f, a3 = 0.f;
#pragma unroll
    for (int wv = 0; wv < 8; ++wv) {
      L += lS[wv * 16 + r];
      const float* op = oS + (wv * 16 + r) * 64 + c0;
      a0 += op[0]; a1 += op[1]; a2 += op[2]; a3 += op[3];
    }
    float inv = 1.0f / L;
    float v[4] = {a0 * inv, a1 * inv, a2 * inv, a3 * inv};
    unsigned short hi[4], lo[4];
#pragma unroll
    for (int j = 0; j < 4; ++j) {
      hi[j] = f2bf(v[j]);
      lo[j] = f2bf(v[j] - bf2f(hi[j]));
    }
    size_t oidx = ((size_t)(b * QL + i0 + r)) * DM + h * DH + c0;
    *(ushort4*)&avhi[oidx] = make_ushort4(hi[0], hi[1], hi[2], hi[3]);
    *(ushort4*)&avlo[oidx] = make_ushort4(lo[0], lo[1], lo[2], lo[3]);
  }
}

// ---------------- final GEMM: out = av @ Wo, split bf16, 64x64 tiles (512 blocks) -----
__global__ __launch_bounds__(256) void gemm_final(
    const unsigned short* __restrict__ avhi, const unsigned short* __restrict__ avlo,
    const unsigned short* __restrict__ wohi, const unsigned short* __restrict__ wolo,
    float* __restrict__ out)
{
  __shared__ __align__(16) unsigned short As[64 * 32];
  __shared__ __align__(16) unsigned short Bs[64 * 32];
  int blk = blockIdx.x, tid = threadIdx.x;
  int mb = blk >> 4, nb = blk & 15;    // 32 x 16

  const int w = tid >> 6, lane = tid & 63;
  const int srow = w * 16 + (lane >> 2);
  const int scu = (lane & 3) * 8;
  const size_t arow = (size_t)(mb * 64 + srow) * 1024 + scu;
  const size_t brow = (size_t)(nb * 64 + srow) * 1024 + scu;
  char* lA = (char*)As + w * 1024;
  char* lB = (char*)Bs + w * 1024;

  const int lc = lane & 15, quad = lane >> 4;
  const int wm = (w & 1) * 32, wn = (w >> 1) * 32;

  f32x4 acc[2][2];
#pragma unroll
  for (int mt = 0; mt < 2; ++mt)
#pragma unroll
    for (int nt = 0; nt < 2; ++nt) { acc[mt][nt][0] = 0.f; acc[mt][nt][1] = 0.f; acc[mt][nt][2] = 0.f; acc[mt][nt][3] = 0.f; }

  for (int k0 = 0; k0 < 3072; k0 += 32) {
    int seg = k0 >> 10, kk = k0 & 1023;
    const unsigned short* Ab = ((seg < 2) ? avhi : avlo);
    const unsigned short* Bb = ((seg == 1) ? wolo : wohi);
    __syncthreads();
    gl2lds16(Ab + arow + kk, lA);
    gl2lds16(Bb + brow + kk, lB);
    __syncthreads();
    s16x8 af[2], bf[2];
#pragma unroll
    for (int mt = 0; mt < 2; ++mt) af[mt] = *(const s16x8*)&As[(wm + mt * 16 + lc) * 32 + quad * 8];
#pragma unroll
    for (int nt = 0; nt < 2; ++nt) bf[nt] = *(const s16x8*)&Bs[(wn + nt * 16 + lc) * 32 + quad * 8];
#pragma unroll
    for (int mt = 0; mt < 2; ++mt)
#pragma unroll
      for (int nt = 0; nt < 2; ++nt) acc[mt][nt] = mfma16(af[mt], bf[nt], acc[mt][nt]);
  }

#pragma unroll
  for (int mt = 0; mt < 2; ++mt)
#pragma unroll
    for (int nt = 0; nt < 2; ++nt) {
      int n = nb * 64 + wn + nt * 16 + lc;
#pragma unroll
      for (int rr = 0; rr < 4; ++rr) {
        int m = mb * 64 + wm + mt * 16 + quad * 4 + rr;
        out[(size_t)m * 1024 + n] = acc[mt][nt][rr];
      }
    }
}

extern "C" void kernel_launch(void* const* d_in, const int* in_sizes, int n_in,
                              void* d_out, int out_size, void* d_ws, size_t ws_size,
                              hipStream_t stream) {
  (void)in_sizes; (void)n_in; (void)out_size; (void)ws_size;
  const float* h   = (const float*)d_in[0];
  const float* mem = (const float*)d_in[1];
  const float* r   = (const float*)d_in[2];
  const float* Wq  = (const float*)d_in[3];
  const float* Wk  = (const float*)d_in[4];
  const float* Wv  = (const float*)d_in[5];
  const float* Wr  = (const float*)d_in[6];
  const float* Wo  = (const float*)d_in[7];
  const float* rwb = (const float*)d_in[8];
  const float* rrb = (const float*)d_in[9];
  float* out = (float*)d_out;

  char* ws = (char*)d_ws;
  unsigned short* catb = (unsigned short*)(ws + 0);          // 8 MB
  unsigned short* rb   = (unsigned short*)(ws + 8388608);    // 4 MB
  unsigned short* wqt  = (unsigned short*)(ws + 12582912);   // 2 MB
  unsigned short* wkvt = (unsigned short*)(ws + 14680064);   // 4 MB
  unsigned short* wrt  = (unsigned short*)(ws + 18874368);   // 2 MB
  unsigned short* wohi = (unsigned short*)(ws + 20971520);   // 2 MB
  unsigned short* wolo = (unsigned short*)(ws + 23068672);   // 2 MB
  unsigned short* qwb  = (unsigned short*)(ws + 25165824);   // 4 MB
  unsigned short* qrb  = (unsigned short*)(ws + 29360128);   // 4 MB
  unsigned short* kbuf = (unsigned short*)(ws + 33554432);   // 8 MB
  unsigned short* vTb  = (unsigned short*)(ws + 41943040);   // 8 MB
  unsigned short* rhb  = (unsigned short*)(ws + 50331648);   // 4 MB
  unsigned short* avhi = (unsigned short*)(ws + 54525952);   // 4 MB
  unsigned short* avlo = (unsigned short*)(ws + 58720256);   // 4 MB

  prep_all<<<7424, 256, 0, stream>>>(h, mem, r, Wq, Wk, Wv, Wr, Wo,
                                     catb, rb, wqt, wkvt, wrt, wohi, wolo);
  gemm_all<<<768, 256, 0, stream>>>(catb, rb, wqt, wkvt, wrt, rwb, rrb,
                                    qwb, qrb, kbuf, vTb, rhb);
  attn<<<2048, 512, 0, stream>>>(qwb, qrb, kbuf, vTb, rhb, avhi, avlo);
  gemm_final<<<512, 256, 0, stream>>>(avhi, avlo, wohi, wolo, out);
}

// Round 7
// 330.280 us; speedup vs baseline: 5.2710x; 1.1283x over previous
//
#include <hip/hip_runtime.h>

#define DM 1024
#define NH 16
#define DH 64
#define QL 1024
#define KL 2048

typedef short s16x8 __attribute__((ext_vector_type(8)));
typedef float f32x4 __attribute__((ext_vector_type(4)));

__device__ __forceinline__ unsigned short f2bf(float f) {
  unsigned int u = __builtin_bit_cast(unsigned int, f);
  u += 0x7fffu + ((u >> 16) & 1u);
  return (unsigned short)(u >> 16);
}
__device__ __forceinline__ float bf2f(unsigned short b) {
  unsigned int u = ((unsigned int)b) << 16;
  return __builtin_bit_cast(float, u);
}
__device__ __forceinline__ f32x4 mfma16(s16x8 a, s16x8 b, f32x4 c) {
  return __builtin_amdgcn_mfma_f32_16x16x32_bf16(a, b, c, 0, 0, 0);
}
// async global->LDS, 16B per lane; LDS dest = wave-uniform base + lane*16
__device__ __forceinline__ void gl2lds16(const void* g, void* l) {
  __builtin_amdgcn_global_load_lds(
      (const __attribute__((address_space(1))) unsigned int*)g,
      (__attribute__((address_space(3))) unsigned int*)l, 16, 0, 0);
}

// ---------------- fused prep: blocks 0..6143 input conversion, 6144..7423 weights ------
__global__ __launch_bounds__(256) void prep_all(
    const float* __restrict__ h, const float* __restrict__ mem, const float* __restrict__ r,
    const float* __restrict__ Wq, const float* __restrict__ Wk, const float* __restrict__ Wv,
    const float* __restrict__ Wr, const float* __restrict__ Wo,
    unsigned short* __restrict__ catb, unsigned short* __restrict__ rb,
    unsigned short* __restrict__ wqt, unsigned short* __restrict__ wkvt,
    unsigned short* __restrict__ wrt,
    unsigned short* __restrict__ wohi, unsigned short* __restrict__ wolo)
{
  __shared__ unsigned short tH[64][72];
  __shared__ unsigned short tL[64][72];
  if (blockIdx.x < 6144) {
    int idx = blockIdx.x * 256 + threadIdx.x;           // 0 .. 1.5M-1
    if (idx < 1048576) {                                // catb: 4M u16, 4 per thread
      int e = idx * 4;
      int row = e >> 10, col = e & 1023;
      int b = row >> 11, t = row & 2047;
      const float* s = (t < 1024) ? &mem[((size_t)(b * 1024 + t)) * 1024 + col]
                                  : &h[((size_t)(b * 1024 + t - 1024)) * 1024 + col];
      float4 v = *(const float4*)s;
      *(ushort4*)&catb[e] = make_ushort4(f2bf(v.x), f2bf(v.y), f2bf(v.z), f2bf(v.w));
    } else {
      int e = (idx - 1048576) * 4;                      // rb: 2M elements
      float4 v = *(const float4*)&r[e];
      *(ushort4*)&rb[e] = make_ushort4(f2bf(v.x), f2bf(v.y), f2bf(v.z), f2bf(v.w));
    }
    return;
  }
  int q = blockIdx.x - 6144;
  int job = q >> 8;
  int tb = q & 255;
  int sr0 = (tb >> 4) * 64, sc0 = (tb & 15) * 64;
  const float* src = (job == 0) ? Wq : (job == 1) ? Wk : (job == 2) ? Wv : (job == 3) ? Wr : Wo;
  int tid = threadIdx.x;
  int rr = tid >> 4, c4 = (tid & 15) * 4;
#pragma unroll
  for (int i = 0; i < 4; ++i) {
    int row = rr + i * 16;
    float4 v = *(const float4*)&src[(size_t)(sr0 + row) * 1024 + sc0 + c4];
    float vv[4] = {v.x, v.y, v.z, v.w};
#pragma unroll
    for (int j = 0; j < 4; ++j) {
      unsigned short hi = f2bf(vv[j]);
      tH[c4 + j][row] = hi;
      if (job == 4) tL[c4 + j][row] = f2bf(vv[j] - bf2f(hi));
    }
  }
  __syncthreads();
  unsigned short* dst = (job == 0) ? wqt : (job == 1) ? wkvt
                      : (job == 2) ? (wkvt + (size_t)1024 * 1024)
                      : (job == 3) ? wrt : wohi;
#pragma unroll
  for (int i = 0; i < 4; ++i) {
    int row = rr + i * 16;
    size_t o = (size_t)(sc0 + row) * 1024 + sr0 + c4;
    *(ushort4*)&dst[o] = make_ushort4(tH[row][c4], tH[row][c4 + 1], tH[row][c4 + 2], tH[row][c4 + 3]);
    if (job == 4)
      *(ushort4*)&wolo[o] = make_ushort4(tL[row][c4], tL[row][c4 + 1], tL[row][c4 + 2], tL[row][c4 + 3]);
  }
}

// ---------------- projection GEMMs (bf16 MFMA, 128x128 tile, BK=32, async staging) ----
// V output is packed in MFMA B-fragment order:
//   vP[bh][kt=key/32][nt=dim/16][lane=((key>>3)&3)*16+(dim&15)][j=key&7]
// so the attn PV fragment load is lane-contiguous (16 lines/wave-load instead of 64).
__global__ __launch_bounds__(256) void gemm_all(
    const unsigned short* __restrict__ catb, const unsigned short* __restrict__ rb,
    const unsigned short* __restrict__ wqt, const unsigned short* __restrict__ wkvt,
    const unsigned short* __restrict__ wrt,
    const float* __restrict__ rwb, const float* __restrict__ rrb,
    unsigned short* __restrict__ qwb, unsigned short* __restrict__ qrb,
    unsigned short* __restrict__ kbuf, unsigned short* __restrict__ vP,
    unsigned short* __restrict__ rhb)
{
  __shared__ __align__(16) unsigned short As[128 * 32];
  __shared__ __align__(16) unsigned short Bs[128 * 32];
  int blk = blockIdx.x, tid = threadIdx.x;
  int job, mb, nb;
  const unsigned short *A, *Bt;
  if (blk < 128)      { job = 0; A = catb; Bt = wqt;  mb = blk >> 3; nb = blk & 7; }
  else if (blk < 640) { job = 1; A = catb; Bt = wkvt; int q = blk - 128; mb = q >> 4; nb = q & 15; }
  else                { job = 2; A = rb;   Bt = wrt;  int q = blk - 640; mb = q >> 3; nb = q & 7; }

  const int w = tid >> 6;
  const int r0 = tid >> 2;                 // chunk0 row (0..63)
  const int c0u = (tid & 3) * 8;           // u16 col offset within 32-wide slab
  int ga_r0 = mb * 128 + r0, ga_r1 = mb * 128 + 64 + r0;
  if (job == 0) {
    ga_r0 = ((ga_r0 >> 10) << 11) + 1024 + (ga_r0 & 1023);
    ga_r1 = ((ga_r1 >> 10) << 11) + 1024 + (ga_r1 & 1023);
  }
  const unsigned short* gA0 = A + (size_t)ga_r0 * 1024 + c0u;
  const unsigned short* gA1 = A + (size_t)ga_r1 * 1024 + c0u;
  const unsigned short* gB0 = Bt + (size_t)(nb * 128 + r0) * 1024 + c0u;
  const unsigned short* gB1 = Bt + (size_t)(nb * 128 + 64 + r0) * 1024 + c0u;
  char* lA0 = (char*)As + w * 1024;  char* lA1 = (char*)As + 4096 + w * 1024;
  char* lB0 = (char*)Bs + w * 1024;  char* lB1 = (char*)Bs + 4096 + w * 1024;

  const int lane = tid & 63;
  const int lc = lane & 15, quad = lane >> 4;
  const int wm = (w & 1) * 64, wn = (w >> 1) * 64;

  f32x4 acc[4][4];
#pragma unroll
  for (int mt = 0; mt < 4; ++mt)
#pragma unroll
    for (int nt = 0; nt < 4; ++nt) { acc[mt][nt][0] = 0.f; acc[mt][nt][1] = 0.f; acc[mt][nt][2] = 0.f; acc[mt][nt][3] = 0.f; }

  for (int k0 = 0; k0 < 1024; k0 += 32) {
    __syncthreads();
    gl2lds16(gA0 + k0, lA0);
    gl2lds16(gA1 + k0, lA1);
    gl2lds16(gB0 + k0, lB0);
    gl2lds16(gB1 + k0, lB1);
    __syncthreads();
    s16x8 af[4], bf[4];
#pragma unroll
    for (int mt = 0; mt < 4; ++mt) af[mt] = *(const s16x8*)&As[(wm + mt * 16 + lc) * 32 + quad * 8];
#pragma unroll
    for (int nt = 0; nt < 4; ++nt) bf[nt] = *(const s16x8*)&Bs[(wn + nt * 16 + lc) * 32 + quad * 8];
#pragma unroll
    for (int mt = 0; mt < 4; ++mt)
#pragma unroll
      for (int nt = 0; nt < 4; ++nt) acc[mt][nt] = mfma16(af[mt], bf[nt], acc[mt][nt]);
  }

#pragma unroll
  for (int mt = 0; mt < 4; ++mt) {
    int t4 = mb * 128 + wm + mt * 16 + quad * 4;
#pragma unroll
    for (int nt = 0; nt < 4; ++nt) {
      int n = nb * 128 + wn + nt * 16 + lc;
      if (job == 0) {
        int hh = n >> 6, dh = n & 63;
        float bw = rwb[n], br = rrb[n];
#pragma unroll
        for (int rr = 0; rr < 4; ++rr) {
          int m = t4 + rr; int bb = m >> 10, t = m & 1023;
          size_t idx = (((size_t)bb * NH + hh) * QL + t) * DH + dh;
          qwb[idx] = f2bf(acc[mt][nt][rr] + bw);
          qrb[idx] = f2bf(acc[mt][nt][rr] + br);
        }
      } else if (job == 1) {
        int bb = t4 >> 11, t = t4 & 2047;
        if (n < 1024) {
          int hh = n >> 6, dh = n & 63;
#pragma unroll
          for (int rr = 0; rr < 4; ++rr)
            kbuf[(((size_t)bb * NH + hh) * KL + t + rr) * DH + dh] = f2bf(acc[mt][nt][rr]);
        } else {
          int n2 = n - 1024, hh = n2 >> 6, dh = n2 & 63;
          int bhv = bb * NH + hh;
          int kt = t >> 5;
          int ntv = dh >> 4;
          int lanev = (((t >> 3) & 3) << 4) + (dh & 15);
          ushort4 pk = make_ushort4(f2bf(acc[mt][nt][0]), f2bf(acc[mt][nt][1]),
                                    f2bf(acc[mt][nt][2]), f2bf(acc[mt][nt][3]));
          *(ushort4*)&vP[(((size_t)bhv * 64 + kt) * 4 + ntv) * 512 + lanev * 8 + (t & 7)] = pk;
        }
      } else {
        int hh = n >> 6, dh = n & 63;
#pragma unroll
        for (int rr = 0; rr < 4; ++rr)
          rhb[((size_t)hh * KL + t4 + rr) * DH + dh] = f2bf(acc[mt][nt][rr]);
      }
    }
  }
}

// ---------------- fused flash attention with rel-shift (bf16 MFMA) --------------------
// block: (b, h, 16 q-rows), 512 threads / 8 waves. Phase 0: raw BD strip in LDS via MFMA.
// Main: 8-way split-K (256 keys/wave), 32-key chunks, PV pipelined one chunk behind;
// V loads hit the fragment-packed vP layout (lane-contiguous, 16 lines/wave-load).
// Fixed-shift softmax; merge = plain sum of per-wave (O, l).
#define BDSTR 2058
__global__ __launch_bounds__(512, 4) void attn(
    const unsigned short* __restrict__ qwb, const unsigned short* __restrict__ qrb,
    const unsigned short* __restrict__ kbuf, const unsigned short* __restrict__ vP,
    const unsigned short* __restrict__ rhb,
    unsigned short* __restrict__ avhi, unsigned short* __restrict__ avlo)
{
  __shared__ __align__(16) unsigned short bdS[17 * BDSTR];   // 69972 B
  __shared__ __align__(16) unsigned short pS[8 * 16 * 36];   // 9216 B
  float* oS = (float*)bdS;             // merge overlay: [8][16][64] f32
  float* lS = (float*)bdS + 8192;      // [8][16] f32

  const int tid = threadIdx.x;
  const int w = tid >> 6, lane = tid & 63;
  const int lc = lane & 15, quad = lane >> 4;
  const int is = blockIdx.x & 63, h = (blockIdx.x >> 6) & 15, b = blockIdx.x >> 10;
  const int i0 = is * 16;
  const size_t bh = (size_t)b * NH + h;

  const unsigned short* qw_p = qwb + bh * QL * DH;
  const unsigned short* qr_p = qrb + bh * QL * DH;
  const unsigned short* kb_p = kbuf + bh * KL * DH;
  const unsigned short* vP_p = vP + bh * KL * DH + lane * 8;   // lane-contiguous base
  const unsigned short* rh_p = rhb + (size_t)h * KL * DH;

  // ---- phase 0: raw BD strip rows i0..i0+16 (17), wave w covers cols [w*256,w*256+256) ----
  {
    int r0 = i0 + lc;
    int r1 = i0 + 16 + lc; if (r1 > 1023) r1 = 1023;   // clamp; clamped rows unused
    s16x8 qa00 = *(const s16x8*)(qr_p + (size_t)r0 * DH + quad * 8);
    s16x8 qa01 = *(const s16x8*)(qr_p + (size_t)r0 * DH + 32 + quad * 8);
    s16x8 qa10 = *(const s16x8*)(qr_p + (size_t)r1 * DH + quad * 8);
    s16x8 qa11 = *(const s16x8*)(qr_p + (size_t)r1 * DH + 32 + quad * 8);
    const int xt0 = w * 16;
    const unsigned short* rp = rh_p + (size_t)(xt0 * 16 + lc) * DH + quad * 8;
    s16x8 rf0 = *(const s16x8*)rp;
    s16x8 rf1 = *(const s16x8*)(rp + 32);
    for (int xt = xt0; xt < xt0 + 16; ++xt) {
      s16x8 cf0 = rf0, cf1 = rf1;
      if (xt + 1 < xt0 + 16) {
        const unsigned short* rpn = rh_p + (size_t)((xt + 1) * 16 + lc) * DH + quad * 8;
        rf0 = *(const s16x8*)rpn;
        rf1 = *(const s16x8*)(rpn + 32);
      }
      f32x4 c0; c0[0] = 0.f; c0[1] = 0.f; c0[2] = 0.f; c0[3] = 0.f;
      f32x4 c1 = c0;
      c0 = mfma16(qa00, cf0, c0); c0 = mfma16(qa01, cf1, c0);
      c1 = mfma16(qa10, cf0, c1); c1 = mfma16(qa11, cf1, c1);
      int col = xt * 16 + lc;
#pragma unroll
      for (int rr = 0; rr < 4; ++rr) bdS[(quad * 4 + rr) * BDSTR + col] = f2bf(c0[rr]);
      if (lane < 16) bdS[16 * BDSTR + col] = f2bf(c1[0]);
    }
  }
  __syncthreads();

  // ---- main split-K loop: wave w handles k in [w*256, w*256+256), 8 x 32-key chunks ----
  s16x8 qwf0 = *(const s16x8*)(qw_p + (size_t)(i0 + lc) * DH + quad * 8);
  s16x8 qwf1 = *(const s16x8*)(qw_p + (size_t)(i0 + lc) * DH + 32 + quad * 8);

  f32x4 O[4];
#pragma unroll
  for (int nt = 0; nt < 4; ++nt) { O[nt][0] = 0.f; O[nt][1] = 0.f; O[nt][2] = 0.f; O[nt][3] = 0.f; }
  float lsum[4] = {0.f, 0.f, 0.f, 0.f};
  unsigned short* pw = pS + w * 16 * 36;
  int ebase[4];
#pragma unroll
  for (int rr = 0; rr < 4; ++rr) ebase[rr] = lc - (quad * 4 + rr) - i0;

  // score phase for one 32-key chunk: bd gathers (issued first), QK MFMA, exp -> p
  auto score = [&](int k0, float p[2][4]) {
    float bd[2][4];
#pragma unroll
    for (int tt = 0; tt < 2; ++tt)
#pragma unroll
      for (int rr = 0; rr < 4; ++rr) {
        int row = quad * 4 + rr;
        int d = k0 + tt * 16 + ebase[rr];
        int am = row * BDSTR + (d + 1023);
        int aw = (row + 1) * BDSTR + (d - 1026);
        unsigned short vb = bdS[(d <= 1024) ? am : aw];
        bd[tt][rr] = (d == 1025) ? 0.0f : bf2f(vb);
      }
#pragma unroll
    for (int tt = 0; tt < 2; ++tt) {
      const unsigned short* kp = kb_p + (size_t)(k0 + tt * 16 + lc) * DH + quad * 8;
      s16x8 kf0 = *(const s16x8*)kp;
      s16x8 kf1 = *(const s16x8*)(kp + 32);
      f32x4 c; c[0] = 0.f; c[1] = 0.f; c[2] = 0.f; c[3] = 0.f;
      c = mfma16(qwf0, kf0, c);
      c = mfma16(qwf1, kf1, c);
#pragma unroll
      for (int rr = 0; rr < 4; ++rr) {
        p[tt][rr] = __expf(fmaf(c[rr] + bd[tt][rr], 0.125f, -12.0f));
        lsum[rr] += p[tt][rr];
      }
    }
  };
  auto storeP = [&](float p[2][4]) {
#pragma unroll
    for (int rr = 0; rr < 4; ++rr) {
      int row = quad * 4 + rr;
      pw[row * 36 + lc]      = f2bf(p[0][rr]);
      pw[row * 36 + 16 + lc] = f2bf(p[1][rr]);
    }
  };
  auto loadV = [&](int k0, s16x8 vf[4]) {
    const unsigned short* base = vP_p + (size_t)(k0 >> 5) * 2048;   // 4*512 per key-tile
#pragma unroll
    for (int nt = 0; nt < 4; ++nt)
      vf[nt] = *(const s16x8*)(base + nt * 512);
  };

  s16x8 vfPrev[4];
  {
    float p[2][4];
    score(w * 256, p);
    storeP(p);
    loadV(w * 256, vfPrev);
  }
#pragma unroll 1
  for (int it = 1; it < 8; ++it) {
    const int k0 = w * 256 + it * 32;
    float p[2][4];
    score(k0, p);                       // gathers + QK + exp for chunk it
    __builtin_amdgcn_s_waitcnt(0xC07F); // lgkmcnt(0): P(it-1) writes landed long ago
    s16x8 pf = *(const s16x8*)(pw + lc * 36 + quad * 8);
#pragma unroll
    for (int nt = 0; nt < 4; ++nt) O[nt] = mfma16(pf, vfPrev[nt], O[nt]);  // PV chunk it-1
    loadV(k0, vfPrev);                  // V(it), consumed next iteration
    storeP(p);                          // safe: pf read completed before MFMA consumed it
  }
  {
    __builtin_amdgcn_s_waitcnt(0xC07F);
    s16x8 pf = *(const s16x8*)(pw + lc * 36 + quad * 8);
#pragma unroll
    for (int nt = 0; nt < 4; ++nt) O[nt] = mfma16(pf, vfPrev[nt], O[nt]);  // PV chunk 7
  }

  // per-wave row-sum of l across the 16 lc lanes (once, not per iteration)
#pragma unroll
  for (int msk = 1; msk <= 8; msk <<= 1)
#pragma unroll
    for (int rr = 0; rr < 4; ++rr) lsum[rr] += __shfl_xor(lsum[rr], msk);

  // ---- merge: plain sums over 8 waves ----
  __syncthreads();               // all waves done with bdS reads
#pragma unroll
  for (int nt = 0; nt < 4; ++nt)
#pragma unroll
    for (int rr = 0; rr < 4; ++rr)
      oS[(w * 16 + quad * 4 + rr) * 64 + nt * 16 + lc] = O[nt][rr];
  if (lc == 0) {
#pragma unroll
    for (int rr = 0; rr < 4; ++rr) lS[w * 16 + quad * 4 + rr] = lsum[rr];
  }
  __syncthreads();

  if (tid < 256) {
    int r = tid >> 4, c0 = (tid & 15) * 4;
    float L = 0.f, a0 = 0.f, a1 = 0.f, a2 = 0.f, a3 = 0.f;
#pragma unroll
    for (int wv = 0; wv < 8; ++wv) {
      L += lS[wv * 16 + r];
      const float* op = oS + (wv * 16 + r) * 64 + c0;
      a0 += op[0]; a1 += op[1]; a2 += op[2]; a3 += op[3];
    }
    float inv = 1.0f / L;
    float v[4] = {a0 * inv, a1 * inv, a2 * inv, a3 * inv};
    unsigned short hi[4], lo[4];
#pragma unroll
    for (int j = 0; j < 4; ++j) {
      hi[j] = f2bf(v[j]);
      lo[j] = f2bf(v[j] - bf2f(hi[j]));
    }
    size_t oidx = ((size_t)(b * QL + i0 + r)) * DM + h * DH + c0;
    *(ushort4*)&avhi[oidx] = make_ushort4(hi[0], hi[1], hi[2], hi[3]);
    *(ushort4*)&avlo[oidx] = make_ushort4(lo[0], lo[1], lo[2], lo[3]);
  }
}

// ---------------- final GEMM: out = av @ Wo, split bf16, 64x64 tiles (512 blocks) -----
__global__ __launch_bounds__(256) void gemm_final(
    const unsigned short* __restrict__ avhi, const unsigned short* __restrict__ avlo,
    const unsigned short* __restrict__ wohi, const unsigned short* __restrict__ wolo,
    float* __restrict__ out)
{
  __shared__ __align__(16) unsigned short As[64 * 32];
  __shared__ __align__(16) unsigned short Bs[64 * 32];
  int blk = blockIdx.x, tid = threadIdx.x;
  int mb = blk >> 4, nb = blk & 15;    // 32 x 16

  const int w = tid >> 6, lane = tid & 63;
  const int srow = w * 16 + (lane >> 2);
  const int scu = (lane & 3) * 8;
  const size_t arow = (size_t)(mb * 64 + srow) * 1024 + scu;
  const size_t brow = (size_t)(nb * 64 + srow) * 1024 + scu;
  char* lA = (char*)As + w * 1024;
  char* lB = (char*)Bs + w * 1024;

  const int lc = lane & 15, quad = lane >> 4;
  const int wm = (w & 1) * 32, wn = (w >> 1) * 32;

  f32x4 acc[2][2];
#pragma unroll
  for (int mt = 0; mt < 2; ++mt)
#pragma unroll
    for (int nt = 0; nt < 2; ++nt) { acc[mt][nt][0] = 0.f; acc[mt][nt][1] = 0.f; acc[mt][nt][2] = 0.f; acc[mt][nt][3] = 0.f; }

  for (int k0 = 0; k0 < 3072; k0 += 32) {
    int seg = k0 >> 10, kk = k0 & 1023;
    const unsigned short* Ab = ((seg < 2) ? avhi : avlo);
    const unsigned short* Bb = ((seg == 1) ? wolo : wohi);
    __syncthreads();
    gl2lds16(Ab + arow + kk, lA);
    gl2lds16(Bb + brow + kk, lB);
    __syncthreads();
    s16x8 af[2], bf[2];
#pragma unroll
    for (int mt = 0; mt < 2; ++mt) af[mt] = *(const s16x8*)&As[(wm + mt * 16 + lc) * 32 + quad * 8];
#pragma unroll
    for (int nt = 0; nt < 2; ++nt) bf[nt] = *(const s16x8*)&Bs[(wn + nt * 16 + lc) * 32 + quad * 8];
#pragma unroll
    for (int mt = 0; mt < 2; ++mt)
#pragma unroll
      for (int nt = 0; nt < 2; ++nt) acc[mt][nt] = mfma16(af[mt], bf[nt], acc[mt][nt]);
  }

#pragma unroll
  for (int mt = 0; mt < 2; ++mt)
#pragma unroll
    for (int nt = 0; nt < 2; ++nt) {
      int n = nb * 64 + wn + nt * 16 + lc;
#pragma unroll
      for (int rr = 0; rr < 4; ++rr) {
        int m = mb * 64 + wm + mt * 16 + quad * 4 + rr;
        out[(size_t)m * 1024 + n] = acc[mt][nt][rr];
      }
    }
}

extern "C" void kernel_launch(void* const* d_in, const int* in_sizes, int n_in,
                              void* d_out, int out_size, void* d_ws, size_t ws_size,
                              hipStream_t stream) {
  (void)in_sizes; (void)n_in; (void)out_size; (void)ws_size;
  const float* h   = (const float*)d_in[0];
  const float* mem = (const float*)d_in[1];
  const float* r   = (const float*)d_in[2];
  const float* Wq  = (const float*)d_in[3];
  const float* Wk  = (const float*)d_in[4];
  const float* Wv  = (const float*)d_in[5];
  const float* Wr  = (const float*)d_in[6];
  const float* Wo  = (const float*)d_in[7];
  const float* rwb = (const float*)d_in[8];
  const float* rrb = (const float*)d_in[9];
  float* out = (float*)d_out;

  char* ws = (char*)d_ws;
  unsigned short* catb = (unsigned short*)(ws + 0);          // 8 MB
  unsigned short* rb   = (unsigned short*)(ws + 8388608);    // 4 MB
  unsigned short* wqt  = (unsigned short*)(ws + 12582912);   // 2 MB
  unsigned short* wkvt = (unsigned short*)(ws + 14680064);   // 4 MB
  unsigned short* wrt  = (unsigned short*)(ws + 18874368);   // 2 MB
  unsigned short* wohi = (unsigned short*)(ws + 20971520);   // 2 MB
  unsigned short* wolo = (unsigned short*)(ws + 23068672);   // 2 MB
  unsigned short* qwb  = (unsigned short*)(ws + 25165824);   // 4 MB
  unsigned short* qrb  = (unsigned short*)(ws + 29360128);   // 4 MB
  unsigned short* kbuf = (unsigned short*)(ws + 33554432);   // 8 MB
  unsigned short* vPb  = (unsigned short*)(ws + 41943040);   // 8 MB (fragment-packed V)
  unsigned short* rhb  = (unsigned short*)(ws + 50331648);   // 4 MB
  unsigned short* avhi = (unsigned short*)(ws + 54525952);   // 4 MB
  unsigned short* avlo = (unsigned short*)(ws + 58720256);   // 4 MB

  prep_all<<<7424, 256, 0, stream>>>(h, mem, r, Wq, Wk, Wv, Wr, Wo,
                                     catb, rb, wqt, wkvt, wrt, wohi, wolo);
  gemm_all<<<768, 256, 0, stream>>>(catb, rb, wqt, wkvt, wrt, rwb, rrb,
                                    qwb, qrb, kbuf, vPb, rhb);
  attn<<<2048, 512, 0, stream>>>(qwb, qrb, kbuf, vPb, rhb, avhi, avlo);
  gemm_final<<<512, 256, 0, stream>>>(avhi, avlo, wohi, wolo, out);
}

// Round 8
// 251.589 us; speedup vs baseline: 6.9196x; 1.3128x over previous
//
#include <hip/hip_runtime.h>

#define DM 1024
#define NH 16
#define DH 64
#define QL 1024
#define KL 2048

typedef short s16x8 __attribute__((ext_vector_type(8)));
typedef float f32x4 __attribute__((ext_vector_type(4)));

__device__ __forceinline__ unsigned short f2bf(float f) {
  unsigned int u = __builtin_bit_cast(unsigned int, f);
  u += 0x7fffu + ((u >> 16) & 1u);
  return (unsigned short)(u >> 16);
}
__device__ __forceinline__ float bf2f(unsigned short b) {
  unsigned int u = ((unsigned int)b) << 16;
  return __builtin_bit_cast(float, u);
}
__device__ __forceinline__ f32x4 mfma16(s16x8 a, s16x8 b, f32x4 c) {
  return __builtin_amdgcn_mfma_f32_16x16x32_bf16(a, b, c, 0, 0, 0);
}
// async global->LDS, 16B per lane; LDS dest = wave-uniform base + lane*16
__device__ __forceinline__ void gl2lds16(const void* g, void* l) {
  __builtin_amdgcn_global_load_lds(
      (const __attribute__((address_space(1))) unsigned int*)g,
      (__attribute__((address_space(3))) unsigned int*)l, 16, 0, 0);
}

// Fragment-packed layouts (all bf16):
//  qP/qrP: [bh][qt=row/16][f=dim/32][lane=((dim>>3)&3)*16+(row&15)][j=dim&7]   (A-frag)
//  kP:     [bh][kt=key/16][f][lane][j]  (B-frag; lane=((dim>>3)&3)*16+(key&15))
//  rP:     [h][xt=row/16][f][lane][j]   (B-frag)
//  vP:     [bh][kt=key/32][nt=dim/16][lane=((key>>3)&3)*16+(dim&15)][j=key&7]  (B-frag of PV)
// Every attn fragment load is then base + lane*8 (contiguous 1KB/wave-load).

// ---------------- fused prep: blocks 0..6143 input conversion, 6144..7423 weights ------
__global__ __launch_bounds__(256) void prep_all(
    const float* __restrict__ h, const float* __restrict__ mem, const float* __restrict__ r,
    const float* __restrict__ Wq, const float* __restrict__ Wk, const float* __restrict__ Wv,
    const float* __restrict__ Wr, const float* __restrict__ Wo,
    unsigned short* __restrict__ catb, unsigned short* __restrict__ rb,
    unsigned short* __restrict__ wqt, unsigned short* __restrict__ wkvt,
    unsigned short* __restrict__ wrt,
    unsigned short* __restrict__ wohi, unsigned short* __restrict__ wolo)
{
  __shared__ unsigned short tH[64][72];
  __shared__ unsigned short tL[64][72];
  if (blockIdx.x < 6144) {
    int idx = blockIdx.x * 256 + threadIdx.x;           // 0 .. 1.5M-1
    if (idx < 1048576) {                                // catb: 4M u16, 4 per thread
      int e = idx * 4;
      int row = e >> 10, col = e & 1023;
      int b = row >> 11, t = row & 2047;
      const float* s = (t < 1024) ? &mem[((size_t)(b * 1024 + t)) * 1024 + col]
                                  : &h[((size_t)(b * 1024 + t - 1024)) * 1024 + col];
      float4 v = *(const float4*)s;
      *(ushort4*)&catb[e] = make_ushort4(f2bf(v.x), f2bf(v.y), f2bf(v.z), f2bf(v.w));
    } else {
      int e = (idx - 1048576) * 4;                      // rb: 2M elements
      float4 v = *(const float4*)&r[e];
      *(ushort4*)&rb[e] = make_ushort4(f2bf(v.x), f2bf(v.y), f2bf(v.z), f2bf(v.w));
    }
    return;
  }
  int q = blockIdx.x - 6144;
  int job = q >> 8;
  int tb = q & 255;
  int sr0 = (tb >> 4) * 64, sc0 = (tb & 15) * 64;
  const float* src = (job == 0) ? Wq : (job == 1) ? Wk : (job == 2) ? Wv : (job == 3) ? Wr : Wo;
  int tid = threadIdx.x;
  int rr = tid >> 4, c4 = (tid & 15) * 4;
#pragma unroll
  for (int i = 0; i < 4; ++i) {
    int row = rr + i * 16;
    float4 v = *(const float4*)&src[(size_t)(sr0 + row) * 1024 + sc0 + c4];
    float vv[4] = {v.x, v.y, v.z, v.w};
#pragma unroll
    for (int j = 0; j < 4; ++j) {
      unsigned short hi = f2bf(vv[j]);
      tH[c4 + j][row] = hi;
      if (job == 4) tL[c4 + j][row] = f2bf(vv[j] - bf2f(hi));
    }
  }
  __syncthreads();
  unsigned short* dst = (job == 0) ? wqt : (job == 1) ? wkvt
                      : (job == 2) ? (wkvt + (size_t)1024 * 1024)
                      : (job == 3) ? wrt : wohi;
#pragma unroll
  for (int i = 0; i < 4; ++i) {
    int row = rr + i * 16;
    size_t o = (size_t)(sc0 + row) * 1024 + sr0 + c4;
    *(ushort4*)&dst[o] = make_ushort4(tH[row][c4], tH[row][c4 + 1], tH[row][c4 + 2], tH[row][c4 + 3]);
    if (job == 4)
      *(ushort4*)&wolo[o] = make_ushort4(tL[row][c4], tL[row][c4 + 1], tL[row][c4 + 2], tL[row][c4 + 3]);
  }
}

// ---------------- projection GEMMs (bf16 MFMA, 128x128 tile, BK=32, async staging) ----
// All outputs written in fragment-packed layouts (line-local epilogue stores).
__global__ __launch_bounds__(256) void gemm_all(
    const unsigned short* __restrict__ catb, const unsigned short* __restrict__ rb,
    const unsigned short* __restrict__ wqt, const unsigned short* __restrict__ wkvt,
    const unsigned short* __restrict__ wrt,
    const float* __restrict__ rwb, const float* __restrict__ rrb,
    unsigned short* __restrict__ qwP, unsigned short* __restrict__ qrP,
    unsigned short* __restrict__ kP, unsigned short* __restrict__ vP,
    unsigned short* __restrict__ rP)
{
  __shared__ __align__(16) unsigned short As[128 * 32];
  __shared__ __align__(16) unsigned short Bs[128 * 32];
  int blk = blockIdx.x, tid = threadIdx.x;
  int job, mb, nb;
  const unsigned short *A, *Bt;
  if (blk < 128)      { job = 0; A = catb; Bt = wqt;  mb = blk >> 3; nb = blk & 7; }
  else if (blk < 640) { job = 1; A = catb; Bt = wkvt; int q = blk - 128; mb = q >> 4; nb = q & 15; }
  else                { job = 2; A = rb;   Bt = wrt;  int q = blk - 640; mb = q >> 3; nb = q & 7; }

  const int w = tid >> 6;
  const int r0 = tid >> 2;                 // chunk0 row (0..63)
  const int c0u = (tid & 3) * 8;           // u16 col offset within 32-wide slab
  int ga_r0 = mb * 128 + r0, ga_r1 = mb * 128 + 64 + r0;
  if (job == 0) {
    ga_r0 = ((ga_r0 >> 10) << 11) + 1024 + (ga_r0 & 1023);
    ga_r1 = ((ga_r1 >> 10) << 11) + 1024 + (ga_r1 & 1023);
  }
  const unsigned short* gA0 = A + (size_t)ga_r0 * 1024 + c0u;
  const unsigned short* gA1 = A + (size_t)ga_r1 * 1024 + c0u;
  const unsigned short* gB0 = Bt + (size_t)(nb * 128 + r0) * 1024 + c0u;
  const unsigned short* gB1 = Bt + (size_t)(nb * 128 + 64 + r0) * 1024 + c0u;
  char* lA0 = (char*)As + w * 1024;  char* lA1 = (char*)As + 4096 + w * 1024;
  char* lB0 = (char*)Bs + w * 1024;  char* lB1 = (char*)Bs + 4096 + w * 1024;

  const int lane = tid & 63;
  const int lc = lane & 15, quad = lane >> 4;
  const int wm = (w & 1) * 64, wn = (w >> 1) * 64;

  f32x4 acc[4][4];
#pragma unroll
  for (int mt = 0; mt < 4; ++mt)
#pragma unroll
    for (int nt = 0; nt < 4; ++nt) { acc[mt][nt][0] = 0.f; acc[mt][nt][1] = 0.f; acc[mt][nt][2] = 0.f; acc[mt][nt][3] = 0.f; }

  for (int k0 = 0; k0 < 1024; k0 += 32) {
    __syncthreads();
    gl2lds16(gA0 + k0, lA0);
    gl2lds16(gA1 + k0, lA1);
    gl2lds16(gB0 + k0, lB0);
    gl2lds16(gB1 + k0, lB1);
    __syncthreads();
    s16x8 af[4], bf[4];
#pragma unroll
    for (int mt = 0; mt < 4; ++mt) af[mt] = *(const s16x8*)&As[(wm + mt * 16 + lc) * 32 + quad * 8];
#pragma unroll
    for (int nt = 0; nt < 4; ++nt) bf[nt] = *(const s16x8*)&Bs[(wn + nt * 16 + lc) * 32 + quad * 8];
#pragma unroll
    for (int mt = 0; mt < 4; ++mt)
#pragma unroll
      for (int nt = 0; nt < 4; ++nt) acc[mt][nt] = mfma16(af[mt], bf[nt], acc[mt][nt]);
  }

#pragma unroll
  for (int mt = 0; mt < 4; ++mt) {
    int t4 = mb * 128 + wm + mt * 16 + quad * 4;
#pragma unroll
    for (int nt = 0; nt < 4; ++nt) {
      int n = nb * 128 + wn + nt * 16 + lc;
      if (job == 0) {
        int hh = n >> 6, dh = n & 63;
        int f = dh >> 5, qd = (dh >> 3) & 3, j = dh & 7;
        float bw = rwb[n], br = rrb[n];
        int bb = t4 >> 10, trow = t4 & 1023;
        size_t tbb = ((((size_t)(bb * NH + hh) * 64 + (trow >> 4)) * 2 + f) * 512) + qd * 128 + j;
        int l0 = trow & 15;
#pragma unroll
        for (int rr = 0; rr < 4; ++rr) {
          qwP[tbb + (l0 + rr) * 8] = f2bf(acc[mt][nt][rr] + bw);
          qrP[tbb + (l0 + rr) * 8] = f2bf(acc[mt][nt][rr] + br);
        }
      } else if (job == 1) {
        int bb = t4 >> 11, t = t4 & 2047;
        if (n < 1024) {
          int hh = n >> 6, dh = n & 63;
          int f = dh >> 5, qd = (dh >> 3) & 3, j = dh & 7;
          size_t tbb = ((((size_t)(bb * NH + hh) * 128 + (t >> 4)) * 2 + f) * 512) + qd * 128 + j;
          int l0 = t & 15;
#pragma unroll
          for (int rr = 0; rr < 4; ++rr)
            kP[tbb + (l0 + rr) * 8] = f2bf(acc[mt][nt][rr]);
        } else {
          int n2 = n - 1024, hh = n2 >> 6, dh = n2 & 63;
          int bhv = bb * NH + hh;
          int kt = t >> 5;
          int ntv = dh >> 4;
          int lanev = (((t >> 3) & 3) << 4) + (dh & 15);
          ushort4 pk = make_ushort4(f2bf(acc[mt][nt][0]), f2bf(acc[mt][nt][1]),
                                    f2bf(acc[mt][nt][2]), f2bf(acc[mt][nt][3]));
          *(ushort4*)&vP[(((size_t)bhv * 64 + kt) * 4 + ntv) * 512 + lanev * 8 + (t & 7)] = pk;
        }
      } else {
        int hh = n >> 6, dh = n & 63;
        int f = dh >> 5, qd = (dh >> 3) & 3, j = dh & 7;
        size_t tbb = (((size_t)hh * 128 + (t4 >> 4)) * 2 + f) * 512 + qd * 128 + j;
        int l0 = t4 & 15;
#pragma unroll
        for (int rr = 0; rr < 4; ++rr)
          rP[tbb + (l0 + rr) * 8] = f2bf(acc[mt][nt][rr]);
      }
    }
  }
}

// ---------------- fused flash attention with rel-shift (bf16 MFMA) --------------------
// block: (b, h, 16 q-rows), 512 threads / 8 waves. Phase 0: raw BD strip in LDS via MFMA.
// Main: 8-way split-K (256 keys/wave), 32-key chunks, PV pipelined one chunk behind.
// All Q/K/R/V global loads hit fragment-packed layouts (base + lane*8, contiguous).
#define BDSTR 2058
__global__ __launch_bounds__(512, 4) void attn(
    const unsigned short* __restrict__ qwP, const unsigned short* __restrict__ qrP,
    const unsigned short* __restrict__ kP, const unsigned short* __restrict__ vP,
    const unsigned short* __restrict__ rP,
    unsigned short* __restrict__ avhi, unsigned short* __restrict__ avlo)
{
  __shared__ __align__(16) unsigned short bdS[17 * BDSTR];   // 69972 B
  __shared__ __align__(16) unsigned short pS[8 * 16 * 36];   // 9216 B
  float* oS = (float*)bdS;             // merge overlay: [8][16][64] f32
  float* lS = (float*)bdS + 8192;      // [8][16] f32

  const int tid = threadIdx.x;
  const int w = tid >> 6, lane = tid & 63;
  const int lc = lane & 15, quad = lane >> 4;
  const int is = blockIdx.x & 63, h = (blockIdx.x >> 6) & 15, b = blockIdx.x >> 10;
  const int i0 = is * 16;
  const size_t bh = (size_t)b * NH + h;

  const unsigned short* qwP_p = qwP + bh * 65536;
  const unsigned short* qrP_p = qrP + bh * 65536;
  const unsigned short* kP_p  = kP + bh * 131072;
  const unsigned short* vP_p  = vP + bh * (size_t)KL * DH + lane * 8;
  const unsigned short* rP_p  = rP + (size_t)h * 131072;

  // ---- phase 0: raw BD strip rows i0..i0+16 (17), wave w covers cols [w*256,w*256+256) ----
  {
    s16x8 qa00 = *(const s16x8*)(qrP_p + is * 1024 + lane * 8);
    s16x8 qa01 = *(const s16x8*)(qrP_p + is * 1024 + 512 + lane * 8);
    int r1 = i0 + 16 + lc; if (r1 > 1023) r1 = 1023;   // clamp; clamped rows unused
    int off1 = (r1 >> 4) * 1024 + (quad * 16 + (r1 & 15)) * 8;
    s16x8 qa10 = *(const s16x8*)(qrP_p + off1);
    s16x8 qa11 = *(const s16x8*)(qrP_p + off1 + 512);
    const int xt0 = w * 16;
    const unsigned short* rp = rP_p + xt0 * 1024 + lane * 8;
    s16x8 rf0 = *(const s16x8*)rp;
    s16x8 rf1 = *(const s16x8*)(rp + 512);
    for (int xt = xt0; xt < xt0 + 16; ++xt) {
      s16x8 cf0 = rf0, cf1 = rf1;
      if (xt + 1 < xt0 + 16) {
        const unsigned short* rpn = rP_p + (xt + 1) * 1024 + lane * 8;
        rf0 = *(const s16x8*)rpn;
        rf1 = *(const s16x8*)(rpn + 512);
      }
      f32x4 c0; c0[0] = 0.f; c0[1] = 0.f; c0[2] = 0.f; c0[3] = 0.f;
      f32x4 c1 = c0;
      c0 = mfma16(qa00, cf0, c0); c0 = mfma16(qa01, cf1, c0);
      c1 = mfma16(qa10, cf0, c1); c1 = mfma16(qa11, cf1, c1);
      int col = xt * 16 + lc;
#pragma unroll
      for (int rr = 0; rr < 4; ++rr) bdS[(quad * 4 + rr) * BDSTR + col] = f2bf(c0[rr]);
      if (lane < 16) bdS[16 * BDSTR + col] = f2bf(c1[0]);
    }
  }
  __syncthreads();

  // ---- main split-K loop: wave w handles k in [w*256, w*256+256), 8 x 32-key chunks ----
  s16x8 qwf0 = *(const s16x8*)(qwP_p + is * 1024 + lane * 8);
  s16x8 qwf1 = *(const s16x8*)(qwP_p + is * 1024 + 512 + lane * 8);

  f32x4 O[4];
#pragma unroll
  for (int nt = 0; nt < 4; ++nt) { O[nt][0] = 0.f; O[nt][1] = 0.f; O[nt][2] = 0.f; O[nt][3] = 0.f; }
  float lsum[4] = {0.f, 0.f, 0.f, 0.f};
  unsigned short* pw = pS + w * 16 * 36;
  int ebase[4];
#pragma unroll
  for (int rr = 0; rr < 4; ++rr) ebase[rr] = lc - (quad * 4 + rr) - i0;

  // score phase for one 32-key chunk: bd gathers (issued first), QK MFMA, exp -> p
  auto score = [&](int k0, float p[2][4]) {
    float bd[2][4];
#pragma unroll
    for (int tt = 0; tt < 2; ++tt)
#pragma unroll
      for (int rr = 0; rr < 4; ++rr) {
        int row = quad * 4 + rr;
        int d = k0 + tt * 16 + ebase[rr];
        int am = row * BDSTR + (d + 1023);
        int aw = (row + 1) * BDSTR + (d - 1026);
        unsigned short vb = bdS[(d <= 1024) ? am : aw];
        bd[tt][rr] = (d == 1025) ? 0.0f : bf2f(vb);
      }
#pragma unroll
    for (int tt = 0; tt < 2; ++tt) {
      const unsigned short* kp = kP_p + (size_t)((k0 >> 4) + tt) * 1024 + lane * 8;
      s16x8 kf0 = *(const s16x8*)kp;
      s16x8 kf1 = *(const s16x8*)(kp + 512);
      f32x4 c; c[0] = 0.f; c[1] = 0.f; c[2] = 0.f; c[3] = 0.f;
      c = mfma16(qwf0, kf0, c);
      c = mfma16(qwf1, kf1, c);
#pragma unroll
      for (int rr = 0; rr < 4; ++rr) {
        p[tt][rr] = __expf(fmaf(c[rr] + bd[tt][rr], 0.125f, -12.0f));
        lsum[rr] += p[tt][rr];
      }
    }
  };
  auto storeP = [&](float p[2][4]) {
#pragma unroll
    for (int rr = 0; rr < 4; ++rr) {
      int row = quad * 4 + rr;
      pw[row * 36 + lc]      = f2bf(p[0][rr]);
      pw[row * 36 + 16 + lc] = f2bf(p[1][rr]);
    }
  };
  auto loadV = [&](int k0, s16x8 vf[4]) {
    const unsigned short* base = vP_p + (size_t)(k0 >> 5) * 2048;   // 4*512 per key-tile
#pragma unroll
    for (int nt = 0; nt < 4; ++nt)
      vf[nt] = *(const s16x8*)(base + nt * 512);
  };

  s16x8 vfPrev[4];
  {
    float p[2][4];
    score(w * 256, p);
    storeP(p);
    loadV(w * 256, vfPrev);
  }
#pragma unroll 1
  for (int it = 1; it < 8; ++it) {
    const int k0 = w * 256 + it * 32;
    float p[2][4];
    score(k0, p);                       // gathers + QK + exp for chunk it
    __builtin_amdgcn_s_waitcnt(0xC07F); // lgkmcnt(0): P(it-1) writes landed long ago
    s16x8 pf = *(const s16x8*)(pw + lc * 36 + quad * 8);
#pragma unroll
    for (int nt = 0; nt < 4; ++nt) O[nt] = mfma16(pf, vfPrev[nt], O[nt]);  // PV chunk it-1
    loadV(k0, vfPrev);                  // V(it), consumed next iteration
    storeP(p);                          // safe: pf read completed before MFMA consumed it
  }
  {
    __builtin_amdgcn_s_waitcnt(0xC07F);
    s16x8 pf = *(const s16x8*)(pw + lc * 36 + quad * 8);
#pragma unroll
    for (int nt = 0; nt < 4; ++nt) O[nt] = mfma16(pf, vfPrev[nt], O[nt]);  // PV chunk 7
  }

  // per-wave row-sum of l across the 16 lc lanes (once, not per iteration)
#pragma unroll
  for (int msk = 1; msk <= 8; msk <<= 1)
#pragma unroll
    for (int rr = 0; rr < 4; ++rr) lsum[rr] += __shfl_xor(lsum[rr], msk);

  // ---- merge: plain sums over 8 waves ----
  __syncthreads();               // all waves done with bdS reads
#pragma unroll
  for (int nt = 0; nt < 4; ++nt)
#pragma unroll
    for (int rr = 0; rr < 4; ++rr)
      oS[(w * 16 + quad * 4 + rr) * 64 + nt * 16 + lc] = O[nt][rr];
  if (lc == 0) {
#pragma unroll
    for (int rr = 0; rr < 4; ++rr) lS[w * 16 + quad * 4 + rr] = lsum[rr];
  }
  __syncthreads();

  if (tid < 256) {
    int r = tid >> 4, c0 = (tid & 15) * 4;
    float L = 0.f, a0 = 0.f, a1 = 0.f, a2 = 0.f, a3 = 0.f;
#pragma unroll
    for (int wv = 0; wv < 8; ++wv) {
      L += lS[wv * 16 + r];
      const float* op = oS + (wv * 16 + r) * 64 + c0;
      a0 += op[0]; a1 += op[1]; a2 += op[2]; a3 += op[3];
    }
    float inv = 1.0f / L;
    float v[4] = {a0 * inv, a1 * inv, a2 * inv, a3 * inv};
    unsigned short hi[4], lo[4];
#pragma unroll
    for (int j = 0; j < 4; ++j) {
      hi[j] = f2bf(v[j]);
      lo[j] = f2bf(v[j] - bf2f(hi[j]));
    }
    size_t oidx = ((size_t)(b * QL + i0 + r)) * DM + h * DH + c0;
    *(ushort4*)&avhi[oidx] = make_ushort4(hi[0], hi[1], hi[2], hi[3]);
    *(ushort4*)&avlo[oidx] = make_ushort4(lo[0], lo[1], lo[2], lo[3]);
  }
}

// ---------------- final GEMM: out = av @ Wo, fused 3-segment split-bf16 ----------------
// Per 32-wide k-slab stage all four operands (avhi/avlo/wohi/wolo, 16 KB) and run
// hi*hi + hi*lo + lo*hi in one pass: k-loop 32 slabs (was 96), 1/3 the barriers.
__global__ __launch_bounds__(256) void gemm_final(
    const unsigned short* __restrict__ avhi, const unsigned short* __restrict__ avlo,
    const unsigned short* __restrict__ wohi, const unsigned short* __restrict__ wolo,
    float* __restrict__ out)
{
  __shared__ __align__(16) unsigned short S[4][64 * 32];   // avhi, avlo, wohi, wolo
  int blk = blockIdx.x, tid = threadIdx.x;
  int mb = blk >> 4, nb = blk & 15;    // 32 x 16

  const int w = tid >> 6, lane = tid & 63;
  const int srow = w * 16 + (lane >> 2);
  const int scu = (lane & 3) * 8;
  const size_t arow = (size_t)(mb * 64 + srow) * 1024 + scu;
  const size_t brow = (size_t)(nb * 64 + srow) * 1024 + scu;
  char* l0 = (char*)S[0] + w * 1024;
  char* l1 = (char*)S[1] + w * 1024;
  char* l2 = (char*)S[2] + w * 1024;
  char* l3 = (char*)S[3] + w * 1024;

  const int lc = lane & 15, quad = lane >> 4;
  const int wm = (w & 1) * 32, wn = (w >> 1) * 32;

  f32x4 acc[2][2];
#pragma unroll
  for (int mt = 0; mt < 2; ++mt)
#pragma unroll
    for (int nt = 0; nt < 2; ++nt) { acc[mt][nt][0] = 0.f; acc[mt][nt][1] = 0.f; acc[mt][nt][2] = 0.f; acc[mt][nt][3] = 0.f; }

  for (int k0 = 0; k0 < 1024; k0 += 32) {
    __syncthreads();
    gl2lds16(avhi + arow + k0, l0);
    gl2lds16(avlo + arow + k0, l1);
    gl2lds16(wohi + brow + k0, l2);
    gl2lds16(wolo + brow + k0, l3);
    __syncthreads();
    s16x8 ah[2], al[2], bh[2], bl[2];
#pragma unroll
    for (int mt = 0; mt < 2; ++mt) {
      int off = (wm + mt * 16 + lc) * 32 + quad * 8;
      ah[mt] = *(const s16x8*)&S[0][off];
      al[mt] = *(const s16x8*)&S[1][off];
    }
#pragma unroll
    for (int nt = 0; nt < 2; ++nt) {
      int off = (wn + nt * 16 + lc) * 32 + quad * 8;
      bh[nt] = *(const s16x8*)&S[2][off];
      bl[nt] = *(const s16x8*)&S[3][off];
    }
#pragma unroll
    for (int mt = 0; mt < 2; ++mt)
#pragma unroll
      for (int nt = 0; nt < 2; ++nt) {
        acc[mt][nt] = mfma16(ah[mt], bh[nt], acc[mt][nt]);
        acc[mt][nt] = mfma16(ah[mt], bl[nt], acc[mt][nt]);
        acc[mt][nt] = mfma16(al[mt], bh[nt], acc[mt][nt]);
      }
  }

#pragma unroll
  for (int mt = 0; mt < 2; ++mt)
#pragma unroll
    for (int nt = 0; nt < 2; ++nt) {
      int n = nb * 64 + wn + nt * 16 + lc;
#pragma unroll
      for (int rr = 0; rr < 4; ++rr) {
        int m = mb * 64 + wm + mt * 16 + quad * 4 + rr;
        out[(size_t)m * 1024 + n] = acc[mt][nt][rr];
      }
    }
}

extern "C" void kernel_launch(void* const* d_in, const int* in_sizes, int n_in,
                              void* d_out, int out_size, void* d_ws, size_t ws_size,
                              hipStream_t stream) {
  (void)in_sizes; (void)n_in; (void)out_size; (void)ws_size;
  const float* h   = (const float*)d_in[0];
  const float* mem = (const float*)d_in[1];
  const float* r   = (const float*)d_in[2];
  const float* Wq  = (const float*)d_in[3];
  const float* Wk  = (const float*)d_in[4];
  const float* Wv  = (const float*)d_in[5];
  const float* Wr  = (const float*)d_in[6];
  const float* Wo  = (const float*)d_in[7];
  const float* rwb = (const float*)d_in[8];
  const float* rrb = (const float*)d_in[9];
  float* out = (float*)d_out;

  char* ws = (char*)d_ws;
  unsigned short* catb = (unsigned short*)(ws + 0);          // 8 MB
  unsigned short* rb   = (unsigned short*)(ws + 8388608);    // 4 MB
  unsigned short* wqt  = (unsigned short*)(ws + 12582912);   // 2 MB
  unsigned short* wkvt = (unsigned short*)(ws + 14680064);   // 4 MB
  unsigned short* wrt  = (unsigned short*)(ws + 18874368);   // 2 MB
  unsigned short* wohi = (unsigned short*)(ws + 20971520);   // 2 MB
  unsigned short* wolo = (unsigned short*)(ws + 23068672);   // 2 MB
  unsigned short* qwP  = (unsigned short*)(ws + 25165824);   // 4 MB (A-frag packed)
  unsigned short* qrP  = (unsigned short*)(ws + 29360128);   // 4 MB (A-frag packed)
  unsigned short* kPb  = (unsigned short*)(ws + 33554432);   // 8 MB (B-frag packed)
  unsigned short* vPb  = (unsigned short*)(ws + 41943040);   // 8 MB (B-frag packed)
  unsigned short* rPb  = (unsigned short*)(ws + 50331648);   // 4 MB (B-frag packed)
  unsigned short* avhi = (unsigned short*)(ws + 54525952);   // 4 MB
  unsigned short* avlo = (unsigned short*)(ws + 58720256);   // 4 MB

  prep_all<<<7424, 256, 0, stream>>>(h, mem, r, Wq, Wk, Wv, Wr, Wo,
                                     catb, rb, wqt, wkvt, wrt, wohi, wolo);
  gemm_all<<<768, 256, 0, stream>>>(catb, rb, wqt, wkvt, wrt, rwb, rrb,
                                    qwP, qrP, kPb, vPb, rPb);
  attn<<<2048, 512, 0, stream>>>(qwP, qrP, kPb, vPb, rPb, avhi, avlo);
  gemm_final<<<512, 256, 0, stream>>>(avhi, avlo, wohi, wolo, out);
}